// Round 1
// baseline (982.367 us; speedup 1.0000x reference)
//
#include <hip/hip_runtime.h>

// ---------------------------------------------------------------------------
// SConv pipeline, fp32 baseline.
// Shapes: B=8, Cin=256, Cout=256, H=W=64. h channels = 64. K = 9 taps.
// ws layout (floats):
//   xT    [8][64][64][256]   x transposed to NHWC
//   Si    [8][64][64][3]     resized S, NHWC
//   A,B,C [8][64][64][64]    ping-pong activations (h1,h2,h3/feat)
//   offs  [8*4096][36]       fused offset(0:18) + dc_off(18:36), NHWC
//   maskb [8*4096][9]        sigmoid mask
//   wT    [9*256][256]       big weight, [k*256+c][o]
//   wsp1[9][3][64] bsp1[64] wsp2[9][64][64] bsp2[64] wsp3 bsp3
//   woff[9][64][64] (o>=36 zero-padded) boff[64]  wdc[576][64] ([k*64+c][o])
// ---------------------------------------------------------------------------

#define OXT   0
#define OSI   (OXT + 8388608)
#define OA    (OSI + 98304)
#define OB    (OA + 2097152)
#define OC    (OB + 2097152)
#define OOFFS (OC + 2097152)
#define OMSK  (OOFFS + 1179648)
#define OWT   (OMSK + 294912)
#define OWSP1 (OWT + 589824)
#define OBSP1 (OWSP1 + 1728)
#define OWSP2 (OBSP1 + 64)
#define OBSP2 (OWSP2 + 36864)
#define OWSP3 (OBSP2 + 64)
#define OBSP3 (OWSP3 + 36864)
#define OWOFF (OBSP3 + 64)
#define OBOFF (OWOFF + 36864)
#define OWDC  (OBOFF + 64)

__global__ __launch_bounds__(256) void prep_k(
    const float* __restrict__ weight,
    const float* __restrict__ sp_w1, const float* __restrict__ sp_s1,
    const float* __restrict__ sp_w2, const float* __restrict__ sp_s2,
    const float* __restrict__ sp_w3, const float* __restrict__ sp_s3,
    const float* __restrict__ off_w, const float* __restrict__ dc_off_w,
    const float* __restrict__ dc_w,
    const float* __restrict__ sp_b1, const float* __restrict__ sp_o1,
    const float* __restrict__ sp_b2, const float* __restrict__ sp_o2,
    const float* __restrict__ sp_b3, const float* __restrict__ sp_o3,
    const float* __restrict__ off_b, const float* __restrict__ dc_off_b,
    float* __restrict__ ws)
{
    int i = blockIdx.x * 256 + threadIdx.x;
    // wT: [j=k*256+c][o]  <- weight[o][c][k]
    if (i < 589824) {
        int o = i & 255; int j = i >> 8; int k = j >> 8; int c = j & 255;
        ws[OWT + i] = weight[o * 2304 + c * 9 + k];
        return;
    }
    i -= 589824;
    // wsp1 [9][3][64]
    if (i < 1728) {
        int o = i & 63; int kc = i >> 6; int c = kc % 3; int k = kc / 3;
        ws[OWSP1 + i] = sp_w1[(o * 3 + c) * 9 + k] * sp_s1[o];
        return;
    }
    i -= 1728;
    if (i < 36864) {
        int o = i & 63; int c = (i >> 6) & 63; int k = i >> 12;
        ws[OWSP2 + i] = sp_w2[(o * 64 + c) * 9 + k] * sp_s2[o];
        return;
    }
    i -= 36864;
    if (i < 36864) {
        int o = i & 63; int c = (i >> 6) & 63; int k = i >> 12;
        ws[OWSP3 + i] = sp_w3[(o * 64 + c) * 9 + k] * sp_s3[o];
        return;
    }
    i -= 36864;
    if (i < 36864) {
        int o = i & 63; int c = (i >> 6) & 63; int k = i >> 12;
        float v = 0.f;
        if (o < 18) v = off_w[(o * 64 + c) * 9 + k];
        else if (o < 36) v = dc_off_w[((o - 18) * 64 + c) * 9 + k];
        ws[OWOFF + i] = v;
        return;
    }
    i -= 36864;
    // wdc [j=k*64+c][o]
    if (i < 36864) {
        int o = i & 63; int j = i >> 6; int k = j >> 6; int c = j & 63;
        ws[OWDC + i] = dc_w[(o * 64 + c) * 9 + k];
        return;
    }
    i -= 36864;
    if (i < 64) { ws[OBSP1 + i] = sp_b1[i] * sp_s1[i] + sp_o1[i]; return; }
    i -= 64;
    if (i < 64) { ws[OBSP2 + i] = sp_b2[i] * sp_s2[i] + sp_o2[i]; return; }
    i -= 64;
    if (i < 64) { ws[OBSP3 + i] = sp_b3[i] * sp_s3[i] + sp_o3[i]; return; }
    i -= 64;
    if (i < 64) { ws[OBOFF + i] = (i < 18) ? off_b[i] : (i < 36 ? dc_off_b[i - 18] : 0.f); return; }
}

// x NCHW [8,256,64,64] -> xT NHWC [8,64,64,256]
__global__ __launch_bounds__(256) void transpose_x_k(const float* __restrict__ x,
                                                     float* __restrict__ xT)
{
    __shared__ float tile[64][65];
    int blk = blockIdx.x;                 // ((b*64+y)*4 + chunk)
    int chunk = blk & 3; int by = blk >> 2;
    int b = by >> 6; int y = by & 63;
    int c0 = chunk * 64;
    int t = threadIdx.x;
    for (int i = t; i < 4096; i += 256) {
        int ci = i >> 6, xi = i & 63;
        tile[ci][xi] = x[((b * 256 + c0 + ci) * 64 + y) * 64 + xi];
    }
    __syncthreads();
    for (int i = t; i < 4096; i += 256) {
        int xi = i >> 6, ci = i & 63;
        xT[((b * 64 + y) * 64 + xi) * 256 + c0 + ci] = tile[ci][xi];
    }
}

// S [8,3,128,128] -> Si NHWC [8,64,64,3], bilinear align_corners=True
__global__ __launch_bounds__(256) void resize_k(const float* __restrict__ S,
                                                float* __restrict__ Si)
{
    int i = blockIdx.x * 256 + threadIdx.x;
    if (i >= 8 * 64 * 64 * 3) return;
    int c = i % 3; int x = (i / 3) & 63; int y = (i / 192) & 63; int b = i / 12288;
    const float sc = 127.0f / 63.0f;
    float sy = y * sc, sx = x * sc;
    float fy = floorf(sy), fx = floorf(sx);
    int y0 = (int)fy, x0 = (int)fx;
    int y1 = min(y0 + 1, 127), x1 = min(x0 + 1, 127);
    float wy = sy - fy, wx = sx - fx;
    const float* Sb = S + (size_t)(b * 3 + c) * 16384;
    float v00 = Sb[y0 * 128 + x0], v01 = Sb[y0 * 128 + x1];
    float v10 = Sb[y1 * 128 + x0], v11 = Sb[y1 * 128 + x1];
    Si[i] = (v00 * (1.f - wy) + v10 * wy) * (1.f - wx)
          + (v01 * (1.f - wy) + v11 * wy) * wx;
}

// Generic 3x3 conv, NHWC in/out, pad=1, COUT=64 internal (store first out_ch).
// wt: [9][CIN][64], bias: [64]. One block per (b,y) row.
template <int CIN, bool RELU>
__global__ __launch_bounds__(256) void conv3x3_k(const float* __restrict__ in,
                                                 const float* __restrict__ wt,
                                                 const float* __restrict__ bias,
                                                 float* __restrict__ out,
                                                 int out_ch, int out_stride)
{
    __shared__ float rows[3][66][CIN];
    int by = blockIdx.x; int b = by >> 6; int y = by & 63;
    int t = threadIdx.x;
    if constexpr (CIN % 4 == 0) {
        const int total = 3 * 66 * (CIN / 4);
        for (int i = t; i < total; i += 256) {
            int r = i / (66 * (CIN / 4)); int rem = i - r * (66 * (CIN / 4));
            int xi = rem / (CIN / 4); int cq = rem - xi * (CIN / 4);
            int yy = y - 1 + r, xx = xi - 1;
            float4 v = make_float4(0.f, 0.f, 0.f, 0.f);
            if (yy >= 0 && yy < 64 && xx >= 0 && xx < 64)
                v = *reinterpret_cast<const float4*>(&in[(((b * 64 + yy) * 64 + xx) * CIN) + cq * 4]);
            *reinterpret_cast<float4*>(&rows[r][xi][cq * 4]) = v;
        }
    } else {
        const int total = 3 * 66 * CIN;
        for (int i = t; i < total; i += 256) {
            int r = i / (66 * CIN); int rem = i - r * (66 * CIN);
            int xi = rem / CIN; int c = rem - xi * CIN;
            int yy = y - 1 + r, xx = xi - 1;
            float v = 0.f;
            if (yy >= 0 && yy < 64 && xx >= 0 && xx < 64)
                v = in[(((b * 64 + yy) * 64 + xx) * CIN) + c];
            rows[r][xi][c] = v;
        }
    }
    __syncthreads();

    int o4 = (t & 15) * 4; int xg = t >> 4;   // 16 x-groups of 4
    float acc[4][4];
    #pragma unroll
    for (int oi = 0; oi < 4; oi++) {
        float bv = bias[o4 + oi];
        #pragma unroll
        for (int xi = 0; xi < 4; xi++) acc[oi][xi] = bv;
    }
    for (int k = 0; k < 9; k++) {
        int dy = k / 3, dx = k - 3 * (k / 3);
        for (int c = 0; c < CIN; c++) {
            float4 w = *reinterpret_cast<const float4*>(&wt[(k * CIN + c) * 64 + o4]);
            float iv[4];
            #pragma unroll
            for (int xi = 0; xi < 4; xi++) iv[xi] = rows[dy][xg * 4 + xi + dx][c];
            #pragma unroll
            for (int xi = 0; xi < 4; xi++) {
                acc[0][xi] = fmaf(w.x, iv[xi], acc[0][xi]);
                acc[1][xi] = fmaf(w.y, iv[xi], acc[1][xi]);
                acc[2][xi] = fmaf(w.z, iv[xi], acc[2][xi]);
                acc[3][xi] = fmaf(w.w, iv[xi], acc[3][xi]);
            }
        }
    }
    if (o4 + 3 < out_ch) {
        #pragma unroll
        for (int xi = 0; xi < 4; xi++) {
            int x = xg * 4 + xi;
            float4 v;
            v.x = RELU ? fmaxf(acc[0][xi], 0.f) : acc[0][xi];
            v.y = RELU ? fmaxf(acc[1][xi], 0.f) : acc[1][xi];
            v.z = RELU ? fmaxf(acc[2][xi], 0.f) : acc[2][xi];
            v.w = RELU ? fmaxf(acc[3][xi], 0.f) : acc[3][xi];
            *reinterpret_cast<float4*>(&out[((size_t)(by * 64 + x)) * out_stride + o4]) = v;
        }
    }
}

// DCNv1 on h (C=64): block = 16 pixels. offs channels 18..35. wdc [576=k*64+c][64].
__global__ __launch_bounds__(256) void dconv_small_k(const float* __restrict__ h,
                                                     const float* __restrict__ offs,
                                                     const float* __restrict__ wdc,
                                                     float* __restrict__ feat)
{
    __shared__ float s[16][580];       // pad to break bank alias across p
    __shared__ float cw[144][4];
    __shared__ int   ca[144][4];
    int t = threadIdx.x;
    int pix0 = blockIdx.x * 16;
    int b = pix0 >> 12;
    if (t < 144) {
        int pl = t / 9, k = t - 9 * (t / 9);
        int pix = pix0 + pl;
        int pib = pix & 4095; int y = pib >> 6, x = pib & 63;
        float offy = offs[(size_t)pix * 36 + 18 + k * 2];
        float offx = offs[(size_t)pix * 36 + 18 + k * 2 + 1];
        float py = (float)(y - 1 + k / 3) + offy;
        float px = (float)(x - 1 + (k - 3 * (k / 3))) + offx;
        float fy = floorf(py), fx = floorf(px);
        int y0 = (int)fy, x0 = (int)fx;
        float dy = py - fy, dx = px - fx;
        float wts[4] = { (1.f - dy) * (1.f - dx), (1.f - dy) * dx,
                         dy * (1.f - dx), dy * dx };
        #pragma unroll
        for (int j = 0; j < 4; j++) {
            int yy = y0 + (j >> 1), xx = x0 + (j & 1);
            bool valid = (yy >= 0 && yy < 64 && xx >= 0 && xx < 64);
            int yc = min(max(yy, 0), 63), xc = min(max(xx, 0), 63);
            ca[t][j] = (b * 4096 + yc * 64 + xc) * 64;
            cw[t][j] = valid ? wts[j] : 0.f;
        }
    }
    __syncthreads();
    for (int i = t; i < 2304; i += 256) {   // 16p * 9k * 16cq
        int cq = i & 15; int pk = i >> 4;
        float4 a = make_float4(0.f, 0.f, 0.f, 0.f);
        #pragma unroll
        for (int j = 0; j < 4; j++) {
            float w = cw[pk][j];
            float4 v = *reinterpret_cast<const float4*>(&h[ca[pk][j] + cq * 4]);
            a.x = fmaf(w, v.x, a.x); a.y = fmaf(w, v.y, a.y);
            a.z = fmaf(w, v.z, a.z); a.w = fmaf(w, v.w, a.w);
        }
        int p = pk / 9; int k = pk - 9 * p;
        *reinterpret_cast<float4*>(&s[p][k * 64 + cq * 4]) = a;
    }
    __syncthreads();
    int o4 = (t & 15) * 4; int p = t >> 4;
    float acc[4] = {0.f, 0.f, 0.f, 0.f};
    for (int j = 0; j < 576; j += 4) {
        float sv[4];
        *reinterpret_cast<float4*>(sv) = *reinterpret_cast<const float4*>(&s[p][j]);
        #pragma unroll
        for (int jj = 0; jj < 4; jj++) {
            float4 w = *reinterpret_cast<const float4*>(&wdc[(j + jj) * 64 + o4]);
            acc[0] = fmaf(w.x, sv[jj], acc[0]);
            acc[1] = fmaf(w.y, sv[jj], acc[1]);
            acc[2] = fmaf(w.z, sv[jj], acc[2]);
            acc[3] = fmaf(w.w, sv[jj], acc[3]);
        }
    }
    int pix = pix0 + p;
    *reinterpret_cast<float4*>(&feat[(size_t)pix * 64 + o4]) =
        make_float4(acc[0], acc[1], acc[2], acc[3]);
}

// mask = sigmoid(conv1x1(feat, m_w) + m_b), thread per pixel
__global__ __launch_bounds__(256) void mask_k(const float* __restrict__ feat,
                                              const float* __restrict__ m_w,
                                              const float* __restrict__ m_b,
                                              float* __restrict__ maskb)
{
    int pix = blockIdx.x * 256 + threadIdx.x;
    float f[64];
    const float* fr = feat + (size_t)pix * 64;
    #pragma unroll
    for (int q = 0; q < 16; q++) {
        float4 v = *reinterpret_cast<const float4*>(&fr[q * 4]);
        f[q * 4] = v.x; f[q * 4 + 1] = v.y; f[q * 4 + 2] = v.z; f[q * 4 + 3] = v.w;
    }
    for (int j = 0; j < 9; j++) {
        float a = m_b[j];
        #pragma unroll 8
        for (int c = 0; c < 64; c++) a = fmaf(f[c], m_w[j * 64 + c], a);
        maskb[(size_t)pix * 9 + j] = 1.f / (1.f + expf(-a));
    }
}

// Modulated DCNv2 on x (C=256 -> O=256). Block = 16 pixels, 4 chunks of 64 cin.
__global__ __launch_bounds__(256) void dconv_big_k(const float* __restrict__ xT,
                                                   const float* __restrict__ offs,
                                                   const float* __restrict__ maskb,
                                                   const float* __restrict__ wT,
                                                   const float* __restrict__ bias,
                                                   float* __restrict__ out)
{
    __shared__ float s[16][576];
    __shared__ float cw[144][4];
    __shared__ int   ca[144][4];
    int t = threadIdx.x;
    int pix0 = blockIdx.x * 16;
    int b = pix0 >> 12;
    if (t < 144) {
        int pl = t / 9, k = t - 9 * (t / 9);
        int pix = pix0 + pl;
        int pib = pix & 4095; int y = pib >> 6, x = pib & 63;
        float offy = offs[(size_t)pix * 36 + k * 2];
        float offx = offs[(size_t)pix * 36 + k * 2 + 1];
        float m = maskb[(size_t)pix * 9 + k];
        float py = (float)(y - 1 + k / 3) + offy;
        float px = (float)(x - 1 + (k - 3 * (k / 3))) + offx;
        float fy = floorf(py), fx = floorf(px);
        int y0 = (int)fy, x0 = (int)fx;
        float dy = py - fy, dx = px - fx;
        float wts[4] = { (1.f - dy) * (1.f - dx), (1.f - dy) * dx,
                         dy * (1.f - dx), dy * dx };
        #pragma unroll
        for (int j = 0; j < 4; j++) {
            int yy = y0 + (j >> 1), xx = x0 + (j & 1);
            bool valid = (yy >= 0 && yy < 64 && xx >= 0 && xx < 64);
            int yc = min(max(yy, 0), 63), xc = min(max(xx, 0), 63);
            ca[t][j] = (b * 4096 + yc * 64 + xc) * 256;
            cw[t][j] = valid ? wts[j] * m : 0.f;
        }
    }
    __syncthreads();

    int o4 = (t & 63) * 4; int wv = t >> 6;   // wave handles pixels wv*4..wv*4+3
    float acc[4][4];                           // [oi][pi]
    #pragma unroll
    for (int oi = 0; oi < 4; oi++)
        #pragma unroll
        for (int pi = 0; pi < 4; pi++) acc[oi][pi] = 0.f;

    for (int chunk = 0; chunk < 4; chunk++) {
        int cbase = chunk << 6;
        // fill s for this cin chunk
        for (int i = t; i < 2304; i += 256) {
            int cq = i & 15; int pk = i >> 4;
            float4 a = make_float4(0.f, 0.f, 0.f, 0.f);
            #pragma unroll
            for (int j = 0; j < 4; j++) {
                float w = cw[pk][j];
                float4 v = *reinterpret_cast<const float4*>(&xT[ca[pk][j] + cbase + cq * 4]);
                a.x = fmaf(w, v.x, a.x); a.y = fmaf(w, v.y, a.y);
                a.z = fmaf(w, v.z, a.z); a.w = fmaf(w, v.w, a.w);
            }
            int p = pk / 9; int k = pk - 9 * p;
            *reinterpret_cast<float4*>(&s[p][(k << 6) + cq * 4]) = a;
        }
        __syncthreads();
        // GEMM chunk
        for (int k = 0; k < 9; k++) {
            for (int cc = 0; cc < 64; cc += 4) {
                float sv[4][4];
                #pragma unroll
                for (int pi = 0; pi < 4; pi++)
                    *reinterpret_cast<float4*>(sv[pi]) =
                        *reinterpret_cast<const float4*>(&s[(wv << 2) + pi][(k << 6) + cc]);
                const float* wrow = &wT[((k << 8) + cbase + cc) * 256 + o4];
                #pragma unroll
                for (int jj = 0; jj < 4; jj++) {
                    float4 w = *reinterpret_cast<const float4*>(wrow + jj * 256);
                    #pragma unroll
                    for (int pi = 0; pi < 4; pi++) {
                        float sx = sv[pi][jj];
                        acc[0][pi] = fmaf(w.x, sx, acc[0][pi]);
                        acc[1][pi] = fmaf(w.y, sx, acc[1][pi]);
                        acc[2][pi] = fmaf(w.z, sx, acc[2][pi]);
                        acc[3][pi] = fmaf(w.w, sx, acc[3][pi]);
                    }
                }
            }
        }
        __syncthreads();
    }
    // epilogue: bias + store NCHW
    int pb = (pix0 & 4095) + wv * 4;
    #pragma unroll
    for (int oi = 0; oi < 4; oi++) {
        float bb = bias[o4 + oi];
        float4 v = make_float4(acc[oi][0] + bb, acc[oi][1] + bb,
                               acc[oi][2] + bb, acc[oi][3] + bb);
        *reinterpret_cast<float4*>(&out[((size_t)(b * 256 + o4 + oi)) * 4096 + pb]) = v;
    }
}

extern "C" void kernel_launch(void* const* d_in, const int* in_sizes, int n_in,
                              void* d_out, int out_size, void* d_ws, size_t ws_size,
                              hipStream_t stream)
{
    const float* x        = (const float*)d_in[0];
    const float* S        = (const float*)d_in[1];
    const float* sp_w1    = (const float*)d_in[2];
    const float* sp_b1    = (const float*)d_in[3];
    const float* sp_s1    = (const float*)d_in[4];
    const float* sp_o1    = (const float*)d_in[5];
    const float* sp_w2    = (const float*)d_in[6];
    const float* sp_b2    = (const float*)d_in[7];
    const float* sp_s2    = (const float*)d_in[8];
    const float* sp_o2    = (const float*)d_in[9];
    const float* sp_w3    = (const float*)d_in[10];
    const float* sp_b3    = (const float*)d_in[11];
    const float* sp_s3    = (const float*)d_in[12];
    const float* sp_o3    = (const float*)d_in[13];
    const float* off_w    = (const float*)d_in[14];
    const float* off_b    = (const float*)d_in[15];
    const float* dc_off_w = (const float*)d_in[16];
    const float* dc_off_b = (const float*)d_in[17];
    const float* dc_w     = (const float*)d_in[18];
    const float* m_w      = (const float*)d_in[19];
    const float* m_b      = (const float*)d_in[20];
    const float* weight   = (const float*)d_in[21];
    const float* bias     = (const float*)d_in[22];
    float* out = (float*)d_out;
    float* ws  = (float*)d_ws;

    float* xT    = ws + OXT;
    float* Si    = ws + OSI;
    float* hA    = ws + OA;
    float* hB    = ws + OB;
    float* hC    = ws + OC;
    float* offsb = ws + OOFFS;
    float* maskb = ws + OMSK;

    // weight prep (739264 elements)
    prep_k<<<2888, 256, 0, stream>>>(weight, sp_w1, sp_s1, sp_w2, sp_s2, sp_w3, sp_s3,
                                     off_w, dc_off_w, dc_w,
                                     sp_b1, sp_o1, sp_b2, sp_o2, sp_b3, sp_o3,
                                     off_b, dc_off_b, ws);
    transpose_x_k<<<2048, 256, 0, stream>>>(x, xT);
    resize_k<<<384, 256, 0, stream>>>(S, Si);
    conv3x3_k<3, true><<<512, 256, 0, stream>>>(Si, ws + OWSP1, ws + OBSP1, hA, 64, 64);
    conv3x3_k<64, true><<<512, 256, 0, stream>>>(hA, ws + OWSP2, ws + OBSP2, hB, 64, 64);
    conv3x3_k<64, true><<<512, 256, 0, stream>>>(hB, ws + OWSP3, ws + OBSP3, hC, 64, 64);
    conv3x3_k<64, false><<<512, 256, 0, stream>>>(hC, ws + OWOFF, ws + OBOFF, offsb, 36, 36);
    dconv_small_k<<<2048, 256, 0, stream>>>(hC, offsb, ws + OWDC, hA);   // hA = feat
    mask_k<<<128, 256, 0, stream>>>(hA, m_w, m_b, maskb);
    dconv_big_k<<<2048, 256, 0, stream>>>(xT, offsb, maskb, ws + OWT, bias, out);
}

// Round 2
// 536.423 us; speedup vs baseline: 1.8313x; 1.8313x over previous
//
#include <hip/hip_runtime.h>
#include <hip/hip_bf16.h>

typedef unsigned short u16;
typedef __attribute__((ext_vector_type(8))) short short8;
typedef __attribute__((ext_vector_type(16))) float f32x16;

// ---------------------------------------------------------------------------
// SConv pipeline. Big deformable conv now bf16 MFMA implicit GEMM.
// ws layout (floats):
//   xT    [8][64][64][256]   x transposed to NHWC
//   Si    [8][64][64][3]     resized S, NHWC
//   A,B,C [8][64][64][64]    ping-pong activations
//   offs  [8*4096][36]       fused offset(0:18) + dc_off(18:36)
//   maskb [8*4096][9]
//   wKg   bf16 [288 kg][256 o][8]  (u16, occupies OWT region)
//   wsp1[9][3][64] bsp1[64] wsp2[9][64][64] bsp2 wsp3 bsp3 woff boff wdc[576][64]
// ---------------------------------------------------------------------------

#define OXT   0
#define OSI   (OXT + 8388608)
#define OA    (OSI + 98304)
#define OB    (OA + 2097152)
#define OC    (OB + 2097152)
#define OOFFS (OC + 2097152)
#define OMSK  (OOFFS + 1179648)
#define OWT   (OMSK + 294912)
#define OWSP1 (OWT + 589824)
#define OBSP1 (OWSP1 + 1728)
#define OWSP2 (OBSP1 + 64)
#define OBSP2 (OWSP2 + 36864)
#define OWSP3 (OBSP2 + 64)
#define OBSP3 (OWSP3 + 36864)
#define OWOFF (OBSP3 + 64)
#define OBOFF (OWOFF + 36864)
#define OWDC  (OBOFF + 64)

__device__ __forceinline__ u16 f2bf(float f) {
    __hip_bfloat16 hb = __float2bfloat16(f);
    return __builtin_bit_cast(u16, hb);
}

__global__ __launch_bounds__(256) void prep_k(
    const float* __restrict__ weight,
    const float* __restrict__ sp_w1, const float* __restrict__ sp_s1,
    const float* __restrict__ sp_w2, const float* __restrict__ sp_s2,
    const float* __restrict__ sp_w3, const float* __restrict__ sp_s3,
    const float* __restrict__ off_w, const float* __restrict__ dc_off_w,
    const float* __restrict__ dc_w,
    const float* __restrict__ sp_b1, const float* __restrict__ sp_o1,
    const float* __restrict__ sp_b2, const float* __restrict__ sp_o2,
    const float* __restrict__ sp_b3, const float* __restrict__ sp_o3,
    const float* __restrict__ off_b, const float* __restrict__ dc_off_b,
    float* __restrict__ ws)
{
    int i = blockIdx.x * 256 + threadIdx.x;
    // wKg bf16: [kg][o][j], K = kg*8+j = k*256+c
    if (i < 589824) {
        int j = i & 7; int o = (i >> 3) & 255; int kg = i >> 11;
        int K = kg * 8 + j; int k = K >> 8; int c = K & 255;
        ((u16*)(ws + OWT))[i] = f2bf(weight[o * 2304 + c * 9 + k]);
        return;
    }
    i -= 589824;
    if (i < 1728) {
        int o = i & 63; int kc = i >> 6; int c = kc % 3; int k = kc / 3;
        ws[OWSP1 + i] = sp_w1[(o * 3 + c) * 9 + k] * sp_s1[o];
        return;
    }
    i -= 1728;
    if (i < 36864) {
        int o = i & 63; int c = (i >> 6) & 63; int k = i >> 12;
        ws[OWSP2 + i] = sp_w2[(o * 64 + c) * 9 + k] * sp_s2[o];
        return;
    }
    i -= 36864;
    if (i < 36864) {
        int o = i & 63; int c = (i >> 6) & 63; int k = i >> 12;
        ws[OWSP3 + i] = sp_w3[(o * 64 + c) * 9 + k] * sp_s3[o];
        return;
    }
    i -= 36864;
    if (i < 36864) {
        int o = i & 63; int c = (i >> 6) & 63; int k = i >> 12;
        float v = 0.f;
        if (o < 18) v = off_w[(o * 64 + c) * 9 + k];
        else if (o < 36) v = dc_off_w[((o - 18) * 64 + c) * 9 + k];
        ws[OWOFF + i] = v;
        return;
    }
    i -= 36864;
    if (i < 36864) {
        int o = i & 63; int j = i >> 6; int k = j >> 6; int c = j & 63;
        ws[OWDC + i] = dc_w[(o * 64 + c) * 9 + k];
        return;
    }
    i -= 36864;
    if (i < 64) { ws[OBSP1 + i] = sp_b1[i] * sp_s1[i] + sp_o1[i]; return; }
    i -= 64;
    if (i < 64) { ws[OBSP2 + i] = sp_b2[i] * sp_s2[i] + sp_o2[i]; return; }
    i -= 64;
    if (i < 64) { ws[OBSP3 + i] = sp_b3[i] * sp_s3[i] + sp_o3[i]; return; }
    i -= 64;
    if (i < 64) { ws[OBOFF + i] = (i < 18) ? off_b[i] : (i < 36 ? dc_off_b[i - 18] : 0.f); return; }
}

__global__ __launch_bounds__(256) void transpose_x_k(const float* __restrict__ x,
                                                     float* __restrict__ xT)
{
    __shared__ float tile[64][65];
    int blk = blockIdx.x;
    int chunk = blk & 3; int by = blk >> 2;
    int b = by >> 6; int y = by & 63;
    int c0 = chunk * 64;
    int t = threadIdx.x;
    for (int i = t; i < 4096; i += 256) {
        int ci = i >> 6, xi = i & 63;
        tile[ci][xi] = x[((b * 256 + c0 + ci) * 64 + y) * 64 + xi];
    }
    __syncthreads();
    for (int i = t; i < 4096; i += 256) {
        int xi = i >> 6, ci = i & 63;
        xT[((b * 64 + y) * 64 + xi) * 256 + c0 + ci] = tile[ci][xi];
    }
}

__global__ __launch_bounds__(256) void resize_k(const float* __restrict__ S,
                                                float* __restrict__ Si)
{
    int i = blockIdx.x * 256 + threadIdx.x;
    if (i >= 8 * 64 * 64 * 3) return;
    int c = i % 3; int x = (i / 3) & 63; int y = (i / 192) & 63; int b = i / 12288;
    const float sc = 127.0f / 63.0f;
    float sy = y * sc, sx = x * sc;
    float fy = floorf(sy), fx = floorf(sx);
    int y0 = (int)fy, x0 = (int)fx;
    int y1 = min(y0 + 1, 127), x1 = min(x0 + 1, 127);
    float wy = sy - fy, wx = sx - fx;
    const float* Sb = S + (size_t)(b * 3 + c) * 16384;
    float v00 = Sb[y0 * 128 + x0], v01 = Sb[y0 * 128 + x1];
    float v10 = Sb[y1 * 128 + x0], v11 = Sb[y1 * 128 + x1];
    Si[i] = (v00 * (1.f - wy) + v10 * wy) * (1.f - wx)
          + (v01 * (1.f - wy) + v11 * wy) * wx;
}

template <int CIN, bool RELU>
__global__ __launch_bounds__(256) void conv3x3_k(const float* __restrict__ in,
                                                 const float* __restrict__ wt,
                                                 const float* __restrict__ bias,
                                                 float* __restrict__ out,
                                                 int out_ch, int out_stride)
{
    __shared__ float rows[3][66][CIN];
    int by = blockIdx.x; int b = by >> 6; int y = by & 63;
    int t = threadIdx.x;
    if constexpr (CIN % 4 == 0) {
        const int total = 3 * 66 * (CIN / 4);
        for (int i = t; i < total; i += 256) {
            int r = i / (66 * (CIN / 4)); int rem = i - r * (66 * (CIN / 4));
            int xi = rem / (CIN / 4); int cq = rem - xi * (CIN / 4);
            int yy = y - 1 + r, xx = xi - 1;
            float4 v = make_float4(0.f, 0.f, 0.f, 0.f);
            if (yy >= 0 && yy < 64 && xx >= 0 && xx < 64)
                v = *reinterpret_cast<const float4*>(&in[(((b * 64 + yy) * 64 + xx) * CIN) + cq * 4]);
            *reinterpret_cast<float4*>(&rows[r][xi][cq * 4]) = v;
        }
    } else {
        const int total = 3 * 66 * CIN;
        for (int i = t; i < total; i += 256) {
            int r = i / (66 * CIN); int rem = i - r * (66 * CIN);
            int xi = rem / CIN; int c = rem - xi * CIN;
            int yy = y - 1 + r, xx = xi - 1;
            float v = 0.f;
            if (yy >= 0 && yy < 64 && xx >= 0 && xx < 64)
                v = in[(((b * 64 + yy) * 64 + xx) * CIN) + c];
            rows[r][xi][c] = v;
        }
    }
    __syncthreads();

    int o4 = (t & 15) * 4; int xg = t >> 4;
    float acc[4][4];
    #pragma unroll
    for (int oi = 0; oi < 4; oi++) {
        float bv = bias[o4 + oi];
        #pragma unroll
        for (int xi = 0; xi < 4; xi++) acc[oi][xi] = bv;
    }
    for (int k = 0; k < 9; k++) {
        int dy = k / 3, dx = k - 3 * (k / 3);
        for (int c = 0; c < CIN; c++) {
            float4 w = *reinterpret_cast<const float4*>(&wt[(k * CIN + c) * 64 + o4]);
            float iv[4];
            #pragma unroll
            for (int xi = 0; xi < 4; xi++) iv[xi] = rows[dy][xg * 4 + xi + dx][c];
            #pragma unroll
            for (int xi = 0; xi < 4; xi++) {
                acc[0][xi] = fmaf(w.x, iv[xi], acc[0][xi]);
                acc[1][xi] = fmaf(w.y, iv[xi], acc[1][xi]);
                acc[2][xi] = fmaf(w.z, iv[xi], acc[2][xi]);
                acc[3][xi] = fmaf(w.w, iv[xi], acc[3][xi]);
            }
        }
    }
    if (o4 + 3 < out_ch) {
        #pragma unroll
        for (int xi = 0; xi < 4; xi++) {
            int x = xg * 4 + xi;
            float4 v;
            v.x = RELU ? fmaxf(acc[0][xi], 0.f) : acc[0][xi];
            v.y = RELU ? fmaxf(acc[1][xi], 0.f) : acc[1][xi];
            v.z = RELU ? fmaxf(acc[2][xi], 0.f) : acc[2][xi];
            v.w = RELU ? fmaxf(acc[3][xi], 0.f) : acc[3][xi];
            *reinterpret_cast<float4*>(&out[((size_t)(by * 64 + x)) * out_stride + o4]) = v;
        }
    }
}

__global__ __launch_bounds__(256) void dconv_small_k(const float* __restrict__ h,
                                                     const float* __restrict__ offs,
                                                     const float* __restrict__ wdc,
                                                     float* __restrict__ feat)
{
    __shared__ float s[16][580];
    __shared__ float cw[144][4];
    __shared__ int   ca[144][4];
    int t = threadIdx.x;
    int pix0 = blockIdx.x * 16;
    int b = pix0 >> 12;
    if (t < 144) {
        int pl = t / 9, k = t - 9 * (t / 9);
        int pix = pix0 + pl;
        int pib = pix & 4095; int y = pib >> 6, x = pib & 63;
        float offy = offs[(size_t)pix * 36 + 18 + k * 2];
        float offx = offs[(size_t)pix * 36 + 18 + k * 2 + 1];
        float py = (float)(y - 1 + k / 3) + offy;
        float px = (float)(x - 1 + (k - 3 * (k / 3))) + offx;
        float fy = floorf(py), fx = floorf(px);
        int y0 = (int)fy, x0 = (int)fx;
        float dy = py - fy, dx = px - fx;
        float wts[4] = { (1.f - dy) * (1.f - dx), (1.f - dy) * dx,
                         dy * (1.f - dx), dy * dx };
        #pragma unroll
        for (int j = 0; j < 4; j++) {
            int yy = y0 + (j >> 1), xx = x0 + (j & 1);
            bool valid = (yy >= 0 && yy < 64 && xx >= 0 && xx < 64);
            int yc = min(max(yy, 0), 63), xc = min(max(xx, 0), 63);
            ca[t][j] = (b * 4096 + yc * 64 + xc) * 64;
            cw[t][j] = valid ? wts[j] : 0.f;
        }
    }
    __syncthreads();
    for (int i = t; i < 2304; i += 256) {
        int cq = i & 15; int pk = i >> 4;
        float4 a = make_float4(0.f, 0.f, 0.f, 0.f);
        #pragma unroll
        for (int j = 0; j < 4; j++) {
            float w = cw[pk][j];
            float4 v = *reinterpret_cast<const float4*>(&h[ca[pk][j] + cq * 4]);
            a.x = fmaf(w, v.x, a.x); a.y = fmaf(w, v.y, a.y);
            a.z = fmaf(w, v.z, a.z); a.w = fmaf(w, v.w, a.w);
        }
        int p = pk / 9; int k = pk - 9 * p;
        *reinterpret_cast<float4*>(&s[p][k * 64 + cq * 4]) = a;
    }
    __syncthreads();
    int o4 = (t & 15) * 4; int p = t >> 4;
    float acc[4] = {0.f, 0.f, 0.f, 0.f};
    for (int j = 0; j < 576; j += 4) {
        float sv[4];
        *reinterpret_cast<float4*>(sv) = *reinterpret_cast<const float4*>(&s[p][j]);
        #pragma unroll
        for (int jj = 0; jj < 4; jj++) {
            float4 w = *reinterpret_cast<const float4*>(&wdc[(j + jj) * 64 + o4]);
            acc[0] = fmaf(w.x, sv[jj], acc[0]);
            acc[1] = fmaf(w.y, sv[jj], acc[1]);
            acc[2] = fmaf(w.z, sv[jj], acc[2]);
            acc[3] = fmaf(w.w, sv[jj], acc[3]);
        }
    }
    int pix = pix0 + p;
    *reinterpret_cast<float4*>(&feat[(size_t)pix * 64 + o4]) =
        make_float4(acc[0], acc[1], acc[2], acc[3]);
}

__global__ __launch_bounds__(256) void mask_k(const float* __restrict__ feat,
                                              const float* __restrict__ m_w,
                                              const float* __restrict__ m_b,
                                              float* __restrict__ maskb)
{
    int pix = blockIdx.x * 256 + threadIdx.x;
    float f[64];
    const float* fr = feat + (size_t)pix * 64;
    #pragma unroll
    for (int q = 0; q < 16; q++) {
        float4 v = *reinterpret_cast<const float4*>(&fr[q * 4]);
        f[q * 4] = v.x; f[q * 4 + 1] = v.y; f[q * 4 + 2] = v.z; f[q * 4 + 3] = v.w;
    }
    for (int j = 0; j < 9; j++) {
        float a = m_b[j];
        #pragma unroll 8
        for (int c = 0; c < 64; c++) a = fmaf(f[c], m_w[j * 64 + c], a);
        maskb[(size_t)pix * 9 + j] = 1.f / (1.f + expf(-a));
    }
}

// ---------------------------------------------------------------------------
// Modulated DCNv2 (256->256), bf16 MFMA implicit GEMM.
// Block: 64 pixels x 256 outch, 4 waves (each 64o x 64px, 2x2 mfma 32x32x16).
// K = 2304 = 9 taps x 256 c; BK = 64 (one tap x 64 channels), 36 K-steps.
// wKg: bf16 [288 kg][256 o][8]  (kg = K/8, linear 32KB per K-step)
// ---------------------------------------------------------------------------
__global__ __launch_bounds__(256) void dconv_big_mfma(
    const float* __restrict__ xT, const float* __restrict__ offs,
    const float* __restrict__ maskb, const u16* __restrict__ wKg,
    const float* __restrict__ bias, float* __restrict__ out)
{
    __shared__ __attribute__((aligned(16))) u16 wtile[8][256][8];  // 32 KB
    __shared__ __attribute__((aligned(16))) u16 stile[8][64][8];   // 8 KB
    __shared__ int   ca[64][5];
    __shared__ float cw[64][5];

    int t = threadIdx.x;
    int pix0 = blockIdx.x * 64;
    int b = pix0 >> 12, pib0 = pix0 & 4095;
    int wid = t >> 6, lane = t & 63;
    int px = lane;           // gather pixel
    int kslot = wid;         // gather kgroup slot
    int lrow = lane & 31, lhi = lane >> 5;
    int o0 = wid << 6;

    f32x16 acc[2][2];
    #pragma unroll
    for (int fo = 0; fo < 2; fo++)
        #pragma unroll
        for (int fp = 0; fp < 2; fp++)
            #pragma unroll
            for (int r = 0; r < 16; r++) acc[fo][fp][r] = 0.f;

    float cwr[4]; int car[4];

    for (int kt = 0; kt < 36; ++kt) {
        int k = kt >> 2;
        if ((kt & 3) == 0) {
            // per-tap corner table: thread (pxc, j)
            int pxc = t >> 2, j = t & 3;
            int pix = pix0 + pxc; int pib = pix & 4095;
            int yy0 = pib >> 6, xx0 = pib & 63;
            float offy = offs[(size_t)pix * 36 + k * 2];
            float offx = offs[(size_t)pix * 36 + k * 2 + 1];
            float m = maskb[(size_t)pix * 9 + k];
            float py = (float)(yy0 - 1 + k / 3) + offy;
            float pxf = (float)(xx0 - 1 + (k % 3)) + offx;
            float fy = floorf(py), fx = floorf(pxf);
            int y0 = (int)fy, x0 = (int)fx;
            float dy = py - fy, dx = pxf - fx;
            float wj = ((j >> 1) ? dy : 1.f - dy) * ((j & 1) ? dx : 1.f - dx);
            int yy = y0 + (j >> 1), xx = x0 + (j & 1);
            bool valid = (yy >= 0 && yy < 64 && xx >= 0 && xx < 64);
            int yc = min(max(yy, 0), 63), xc = min(max(xx, 0), 63);
            ca[pxc][j] = (b * 4096 + yc * 64 + xc) << 8;
            cw[pxc][j] = valid ? wj * m : 0.f;
            __syncthreads();
            #pragma unroll
            for (int jj = 0; jj < 4; jj++) { car[jj] = ca[px][jj]; cwr[jj] = cw[px][jj]; }
        }

        // stage weights: linear 32KB, global_load_lds width 16
        {
            const char* gbase = (const char*)(wKg + (size_t)kt * 16384);
            char* lbase = (char*)&wtile[0][0][0];
            #pragma unroll
            for (int i = 0; i < 8; i++) {
                int off = i * 4096 + wid * 1024;
                __builtin_amdgcn_global_load_lds(
                    (const __attribute__((address_space(1))) void*)(gbase + off + lane * 16),
                    (__attribute__((address_space(3))) void*)(lbase + off), 16, 0, 0);
            }
        }

        // gather s: 64 px x 64 ch (8 kgroups); thread does kg = kslot, kslot+4
        int c0 = (kt & 3) << 6;
        #pragma unroll
        for (int h = 0; h < 2; h++) {
            int kg = kslot + h * 4;
            int c = c0 + (kg << 3);
            float va[8];
            #pragma unroll
            for (int e = 0; e < 8; e++) va[e] = 0.f;
            #pragma unroll
            for (int j = 0; j < 4; j++) {
                float w = cwr[j];
                const float* p = xT + car[j] + c;
                float4 v0 = *reinterpret_cast<const float4*>(p);
                float4 v1 = *reinterpret_cast<const float4*>(p + 4);
                va[0] = fmaf(w, v0.x, va[0]); va[1] = fmaf(w, v0.y, va[1]);
                va[2] = fmaf(w, v0.z, va[2]); va[3] = fmaf(w, v0.w, va[3]);
                va[4] = fmaf(w, v1.x, va[4]); va[5] = fmaf(w, v1.y, va[5]);
                va[6] = fmaf(w, v1.z, va[6]); va[7] = fmaf(w, v1.w, va[7]);
            }
            short8 sv;
            #pragma unroll
            for (int e = 0; e < 8; e++) sv[e] = (short)f2bf(va[e]);
            *reinterpret_cast<short8*>(&stile[kg][px][0]) = sv;
        }
        __syncthreads();   // drains vmcnt (weights) + lgkmcnt (s writes)

        // compute: 4 K16 slices, 2x2 frags of 32x32x16
        #pragma unroll
        for (int ks = 0; ks < 4; ks++) {
            int kg = ks * 2 + lhi;
            short8 a0 = *reinterpret_cast<const short8*>(&wtile[kg][o0 + lrow][0]);
            short8 a1 = *reinterpret_cast<const short8*>(&wtile[kg][o0 + 32 + lrow][0]);
            short8 b0 = *reinterpret_cast<const short8*>(&stile[kg][lrow][0]);
            short8 b1 = *reinterpret_cast<const short8*>(&stile[kg][32 + lrow][0]);
            acc[0][0] = __builtin_amdgcn_mfma_f32_32x32x16_bf16(a0, b0, acc[0][0], 0, 0, 0);
            acc[0][1] = __builtin_amdgcn_mfma_f32_32x32x16_bf16(a0, b1, acc[0][1], 0, 0, 0);
            acc[1][0] = __builtin_amdgcn_mfma_f32_32x32x16_bf16(a1, b0, acc[1][0], 0, 0, 0);
            acc[1][1] = __builtin_amdgcn_mfma_f32_32x32x16_bf16(a1, b1, acc[1][1], 0, 0, 0);
        }
        __syncthreads();
    }

    // epilogue: bias + store NCHW
    #pragma unroll
    for (int fo = 0; fo < 2; fo++) {
        #pragma unroll
        for (int r = 0; r < 16; r++) {
            int o = o0 + fo * 32 + (r & 3) + ((r >> 2) << 3) + (lhi << 2);
            float bv = bias[o];
            size_t rowoff = ((size_t)(b * 256 + o) << 12) + pib0;
            out[rowoff + lrow] = acc[fo][0][r] + bv;
            out[rowoff + 32 + lrow] = acc[fo][1][r] + bv;
        }
    }
}

extern "C" void kernel_launch(void* const* d_in, const int* in_sizes, int n_in,
                              void* d_out, int out_size, void* d_ws, size_t ws_size,
                              hipStream_t stream)
{
    const float* x        = (const float*)d_in[0];
    const float* S        = (const float*)d_in[1];
    const float* sp_w1    = (const float*)d_in[2];
    const float* sp_b1    = (const float*)d_in[3];
    const float* sp_s1    = (const float*)d_in[4];
    const float* sp_o1    = (const float*)d_in[5];
    const float* sp_w2    = (const float*)d_in[6];
    const float* sp_b2    = (const float*)d_in[7];
    const float* sp_s2    = (const float*)d_in[8];
    const float* sp_o2    = (const float*)d_in[9];
    const float* sp_w3    = (const float*)d_in[10];
    const float* sp_b3    = (const float*)d_in[11];
    const float* sp_s3    = (const float*)d_in[12];
    const float* sp_o3    = (const float*)d_in[13];
    const float* off_w    = (const float*)d_in[14];
    const float* off_b    = (const float*)d_in[15];
    const float* dc_off_w = (const float*)d_in[16];
    const float* dc_off_b = (const float*)d_in[17];
    const float* dc_w     = (const float*)d_in[18];
    const float* m_w      = (const float*)d_in[19];
    const float* m_b      = (const float*)d_in[20];
    const float* weight   = (const float*)d_in[21];
    const float* bias     = (const float*)d_in[22];
    float* out = (float*)d_out;
    float* ws  = (float*)d_ws;

    float* xT    = ws + OXT;
    float* Si    = ws + OSI;
    float* hA    = ws + OA;
    float* hB    = ws + OB;
    float* hC    = ws + OC;
    float* offsb = ws + OOFFS;
    float* maskb = ws + OMSK;

    prep_k<<<2888, 256, 0, stream>>>(weight, sp_w1, sp_s1, sp_w2, sp_s2, sp_w3, sp_s3,
                                     off_w, dc_off_w, dc_w,
                                     sp_b1, sp_o1, sp_b2, sp_o2, sp_b3, sp_o3,
                                     off_b, dc_off_b, ws);
    transpose_x_k<<<2048, 256, 0, stream>>>(x, xT);
    resize_k<<<384, 256, 0, stream>>>(S, Si);
    conv3x3_k<3, true><<<512, 256, 0, stream>>>(Si, ws + OWSP1, ws + OBSP1, hA, 64, 64);
    conv3x3_k<64, true><<<512, 256, 0, stream>>>(hA, ws + OWSP2, ws + OBSP2, hB, 64, 64);
    conv3x3_k<64, true><<<512, 256, 0, stream>>>(hB, ws + OWSP3, ws + OBSP3, hC, 64, 64);
    conv3x3_k<64, false><<<512, 256, 0, stream>>>(hC, ws + OWOFF, ws + OBOFF, offsb, 36, 36);
    dconv_small_k<<<2048, 256, 0, stream>>>(hC, offsb, ws + OWDC, hA);   // hA = feat
    mask_k<<<128, 256, 0, stream>>>(hA, m_w, m_b, maskb);
    dconv_big_mfma<<<512, 256, 0, stream>>>(xT, offsb, maskb,
                                            (const u16*)(ws + OWT), bias, out);
}

// Round 3
// 337.206 us; speedup vs baseline: 2.9133x; 1.5908x over previous
//
#include <hip/hip_runtime.h>
#include <hip/hip_bf16.h>

typedef unsigned short u16;
typedef unsigned int u32;
typedef __attribute__((ext_vector_type(8))) short short8;
typedef __attribute__((ext_vector_type(4))) unsigned short ush4;
typedef __attribute__((ext_vector_type(16))) float f32x16;

// ---------------------------------------------------------------------------
// ws layout (float units):
//   OXT   xT bf16 [8][64][64][256]      (u16 in float-sized region)
//   OSI   Si f32  [8][64][64][3]
//   OA    h1 bf16 [32768][64]
//   OB    h2 bf16 -> later feat f32 [32768][64]
//   OC    h3 bf16 [32768][64]
//   OOFFS offs f32 [32768][36]
//   OMSK  mask f32 [32768][9]
//   OWT   wKg bf16 [288][256][8]
//   OWSP1 f32 [9][3][64];  OWSP2/OWSP3/OWOFF bf16 [9][8][64][8];  OWDC f32 [576][64]
// ---------------------------------------------------------------------------
#define OXT   0
#define OSI   (OXT + 8388608)
#define OA    (OSI + 98304)
#define OB    (OA + 2097152)
#define OC    (OB + 2097152)
#define OOFFS (OC + 2097152)
#define OMSK  (OOFFS + 1179648)
#define OWT   (OMSK + 294912)
#define OWSP1 (OWT + 589824)
#define OBSP1 (OWSP1 + 1728)
#define OWSP2 (OBSP1 + 64)
#define OBSP2 (OWSP2 + 36864)
#define OWSP3 (OBSP2 + 64)
#define OBSP3 (OWSP3 + 36864)
#define OWOFF (OBSP3 + 64)
#define OBOFF (OWOFF + 36864)
#define OWDC  (OBOFF + 64)

__device__ __forceinline__ u16 f2bf(float f) {
    __hip_bfloat16 hb = __float2bfloat16(f);
    return __builtin_bit_cast(u16, hb);
}
__device__ __forceinline__ float bf2f(u16 v) {
    return __builtin_bit_cast(float, (u32)v << 16);
}

// ---------------------------------------------------------------------------
__global__ __launch_bounds__(256) void prep_k(
    const float* __restrict__ weight,
    const float* __restrict__ sp_w1, const float* __restrict__ sp_s1,
    const float* __restrict__ sp_w2, const float* __restrict__ sp_s2,
    const float* __restrict__ sp_w3, const float* __restrict__ sp_s3,
    const float* __restrict__ off_w, const float* __restrict__ dc_off_w,
    const float* __restrict__ dc_w,
    const float* __restrict__ sp_b1, const float* __restrict__ sp_o1,
    const float* __restrict__ sp_b2, const float* __restrict__ sp_o2,
    const float* __restrict__ sp_b3, const float* __restrict__ sp_o3,
    const float* __restrict__ off_b, const float* __restrict__ dc_off_b,
    float* __restrict__ ws)
{
    int i = blockIdx.x * 256 + threadIdx.x;
    if (i < 589824) {   // wKg bf16 [kg][o][j], K=kg*8+j = k*256+c
        int j = i & 7; int o = (i >> 3) & 255; int kg = i >> 11;
        int K = kg * 8 + j; int k = K >> 8; int c = K & 255;
        ((u16*)(ws + OWT))[i] = f2bf(weight[o * 2304 + c * 9 + k]);
        return;
    }
    i -= 589824;
    if (i < 1728) {     // wsp1 f32 [9][3][64]
        int o = i & 63; int kc = i >> 6; int c = kc % 3; int k = kc / 3;
        ws[OWSP1 + i] = sp_w1[(o * 3 + c) * 9 + k] * sp_s1[o];
        return;
    }
    i -= 1728;
    if (i < 36864) {    // wm2 bf16 [t][kg][o][e]
        int e = i & 7; int o = (i >> 3) & 63; int kg = (i >> 9) & 7; int tp = i >> 12;
        ((u16*)(ws + OWSP2))[i] = f2bf(sp_w2[(o * 64 + kg * 8 + e) * 9 + tp] * sp_s2[o]);
        return;
    }
    i -= 36864;
    if (i < 36864) {
        int e = i & 7; int o = (i >> 3) & 63; int kg = (i >> 9) & 7; int tp = i >> 12;
        ((u16*)(ws + OWSP3))[i] = f2bf(sp_w3[(o * 64 + kg * 8 + e) * 9 + tp] * sp_s3[o]);
        return;
    }
    i -= 36864;
    if (i < 36864) {    // woff bf16, o<18 off_w, 18..35 dc_off_w, else 0
        int e = i & 7; int o = (i >> 3) & 63; int kg = (i >> 9) & 7; int tp = i >> 12;
        int c = kg * 8 + e;
        float v = 0.f;
        if (o < 18) v = off_w[(o * 64 + c) * 9 + tp];
        else if (o < 36) v = dc_off_w[((o - 18) * 64 + c) * 9 + tp];
        ((u16*)(ws + OWOFF))[i] = f2bf(v);
        return;
    }
    i -= 36864;
    if (i < 36864) {    // wdc f32 [j=k*64+c][o]
        int o = i & 63; int j = i >> 6; int k = j >> 6; int c = j & 63;
        ws[OWDC + i] = dc_w[(o * 64 + c) * 9 + k];
        return;
    }
    i -= 36864;
    if (i < 64) { ws[OBSP1 + i] = sp_b1[i] * sp_s1[i] + sp_o1[i]; return; }
    i -= 64;
    if (i < 64) { ws[OBSP2 + i] = sp_b2[i] * sp_s2[i] + sp_o2[i]; return; }
    i -= 64;
    if (i < 64) { ws[OBSP3 + i] = sp_b3[i] * sp_s3[i] + sp_o3[i]; return; }
    i -= 64;
    if (i < 64) { ws[OBOFF + i] = (i < 18) ? off_b[i] : (i < 36 ? dc_off_b[i - 18] : 0.f); return; }
}

// x NCHW f32 -> xT NHWC bf16
__global__ __launch_bounds__(256) void transpose_x_k(const float* __restrict__ x,
                                                     u16* __restrict__ xT)
{
    __shared__ float tile[64][65];
    int blk = blockIdx.x;
    int chunk = blk & 3; int by = blk >> 2;
    int b = by >> 6; int y = by & 63;
    int c0 = chunk * 64;
    int t = threadIdx.x;
    for (int i = t; i < 4096; i += 256) {
        int ci = i >> 6, xi = i & 63;
        tile[ci][xi] = x[((b * 256 + c0 + ci) * 64 + y) * 64 + xi];
    }
    __syncthreads();
    for (int i = t; i < 4096; i += 256) {
        int xi = i >> 6, ci = i & 63;
        xT[((b * 64 + y) * 64 + xi) * 256 + c0 + ci] = f2bf(tile[ci][xi]);
    }
}

__global__ __launch_bounds__(256) void resize_k(const float* __restrict__ S,
                                                float* __restrict__ Si)
{
    int i = blockIdx.x * 256 + threadIdx.x;
    if (i >= 8 * 64 * 64 * 3) return;
    int c = i % 3; int x = (i / 3) & 63; int y = (i / 192) & 63; int b = i / 12288;
    const float sc = 127.0f / 63.0f;
    float sy = y * sc, sx = x * sc;
    float fy = floorf(sy), fx = floorf(sx);
    int y0 = (int)fy, x0 = (int)fx;
    int y1 = min(y0 + 1, 127), x1 = min(x0 + 1, 127);
    float wy = sy - fy, wx = sx - fx;
    const float* Sb = S + (size_t)(b * 3 + c) * 16384;
    float v00 = Sb[y0 * 128 + x0], v01 = Sb[y0 * 128 + x1];
    float v10 = Sb[y1 * 128 + x0], v11 = Sb[y1 * 128 + x1];
    Si[i] = (v00 * (1.f - wy) + v10 * wy) * (1.f - wx)
          + (v01 * (1.f - wy) + v11 * wy) * wx;
}

// conv1: 3->64, fp32 VALU, bf16 NHWC output. One block per (b,y) row.
__global__ __launch_bounds__(256) void conv_in_k(const float* __restrict__ in,
                                                 const float* __restrict__ wt,
                                                 const float* __restrict__ bias,
                                                 u16* __restrict__ out)
{
    __shared__ float rows[3][66][3];
    int by = blockIdx.x; int b = by >> 6; int y = by & 63;
    int t = threadIdx.x;
    for (int i = t; i < 3 * 66 * 3; i += 256) {
        int r = i / 198; int rem = i - r * 198;
        int xi = rem / 3; int c = rem - xi * 3;
        int yy = y - 1 + r, xx = xi - 1;
        float v = 0.f;
        if (yy >= 0 && yy < 64 && xx >= 0 && xx < 64)
            v = in[(((b * 64 + yy) * 64 + xx) * 3) + c];
        rows[r][xi][c] = v;
    }
    __syncthreads();
    int o4 = (t & 15) * 4; int xg = t >> 4;
    float acc[4][4];
    #pragma unroll
    for (int oi = 0; oi < 4; oi++) {
        float bv = bias[o4 + oi];
        #pragma unroll
        for (int xi = 0; xi < 4; xi++) acc[oi][xi] = bv;
    }
    for (int k = 0; k < 9; k++) {
        int dy = k / 3, dx = k - 3 * (k / 3);
        for (int c = 0; c < 3; c++) {
            float4 w = *reinterpret_cast<const float4*>(&wt[(k * 3 + c) * 64 + o4]);
            #pragma unroll
            for (int xi = 0; xi < 4; xi++) {
                float iv = rows[dy][xg * 4 + xi + dx][c];
                acc[0][xi] = fmaf(w.x, iv, acc[0][xi]);
                acc[1][xi] = fmaf(w.y, iv, acc[1][xi]);
                acc[2][xi] = fmaf(w.z, iv, acc[2][xi]);
                acc[3][xi] = fmaf(w.w, iv, acc[3][xi]);
            }
        }
    }
    #pragma unroll
    for (int xi = 0; xi < 4; xi++) {
        int x = xg * 4 + xi;
        ush4 v;
        v.x = f2bf(fmaxf(acc[0][xi], 0.f));
        v.y = f2bf(fmaxf(acc[1][xi], 0.f));
        v.z = f2bf(fmaxf(acc[2][xi], 0.f));
        v.w = f2bf(fmaxf(acc[3][xi], 0.f));
        *reinterpret_cast<ush4*>(&out[((size_t)(by * 64 + x)) * 64 + o4]) = v;
    }
}

// ---------------------------------------------------------------------------
// MFMA 3x3 conv 64->64 (MODE 0: bf16 NHWC out + bias + optional ReLU;
// MODE 1: f32 [px][36] offs out + bias). Block: 2 rows = 128 px, 4 waves.
// wm: bf16 [9 tap][8 kg][64 o][8 e]; per tap 8KB streamed dbuf.
// ---------------------------------------------------------------------------
template <int MODE, bool RELU>
__global__ __launch_bounds__(256) void conv_mfma_k(const u16* __restrict__ in,
                                                   const u16* __restrict__ wm,
                                                   const float* __restrict__ bias,
                                                   u16* __restrict__ outH,
                                                   float* __restrict__ outF)
{
    __shared__ __attribute__((aligned(16))) char lds_h[4 * 66 * 128];   // 33.8 KB
    __shared__ __attribute__((aligned(16))) u16 wtap[2][8][64][8];      // 16 KB

    int t = threadIdx.x;
    int b = blockIdx.x >> 5; int y0 = (blockIdx.x & 31) * 2;
    int pix0 = b * 4096 + y0 * 64;
    int wid = t >> 6, lane = t & 63;
    int lrow = lane & 31, lhi = lane >> 5;
    int px = wid * 32 + lrow;          // wave-local output pixel column
    int ry_l = px >> 6, xc = px & 63;

    // stage 4 input rows (y0-1 .. y0+2), 66 cols, swizzled
    for (int i = t; i < 4 * 66 * 8; i += 256) {
        int r = i / 528; int rem = i - r * 528;
        int xi = rem >> 3; int g = rem & 7;
        int yy = y0 - 1 + r, xx = xi - 1;
        short8 v = {0,0,0,0,0,0,0,0};
        if (yy >= 0 && yy < 64 && xx >= 0 && xx < 64)
            v = *reinterpret_cast<const short8*>(&in[(size_t)((b * 4096 + yy * 64 + xx)) * 64 + g * 8]);
        int byte = (r * 66 + xi) * 128 + ((g * 16) ^ ((xi & 7) << 4));
        *reinterpret_cast<short8*>(lds_h + byte) = v;
    }
    // stage tap 0 weights
    {
        const char* gb = (const char*)(wm);
        char* lb = (char*)&wtap[0][0][0][0];
        #pragma unroll
        for (int i = 0; i < 2; i++) {
            int off = i * 4096 + wid * 1024;
            __builtin_amdgcn_global_load_lds(
                (const __attribute__((address_space(1))) void*)(gb + off + lane * 16),
                (__attribute__((address_space(3))) void*)(lb + off), 16, 0, 0);
        }
    }
    __syncthreads();

    f32x16 acc[2];
    #pragma unroll
    for (int fo = 0; fo < 2; fo++)
        #pragma unroll
        for (int r = 0; r < 16; r++) acc[fo][r] = 0.f;

    for (int tap = 0; tap < 9; tap++) {
        int cur = tap & 1, nxt = cur ^ 1;
        if (tap < 8) {
            const char* gb = (const char*)(wm + (size_t)(tap + 1) * 4096);
            char* lb = (char*)&wtap[nxt][0][0][0];
            #pragma unroll
            for (int i = 0; i < 2; i++) {
                int off = i * 4096 + wid * 1024;
                __builtin_amdgcn_global_load_lds(
                    (const __attribute__((address_space(1))) void*)(gb + off + lane * 16),
                    (__attribute__((address_space(3))) void*)(lb + off), 16, 0, 0);
            }
        }
        int dy = tap / 3, dx = tap - 3 * (tap / 3);
        int ry = ry_l + dy;
        int xi = xc + dx;
        int rowbyte = (ry * 66 + xi) * 128;
        int swz = (xi & 7) << 4;
        #pragma unroll
        for (int ks = 0; ks < 4; ks++) {
            int kg = ks * 2 + lhi;
            short8 a0 = *reinterpret_cast<const short8*>(&wtap[cur][kg][lrow][0]);
            short8 a1 = *reinterpret_cast<const short8*>(&wtap[cur][kg][32 + lrow][0]);
            short8 b0 = *reinterpret_cast<const short8*>(lds_h + rowbyte + ((kg * 16) ^ swz));
            acc[0] = __builtin_amdgcn_mfma_f32_32x32x16_bf16(a0, b0, acc[0], 0, 0, 0);
            acc[1] = __builtin_amdgcn_mfma_f32_32x32x16_bf16(a1, b0, acc[1], 0, 0, 0);
        }
        if (tap < 8) asm volatile("s_waitcnt vmcnt(0)" ::: "memory");
        __builtin_amdgcn_s_barrier();
    }
    __syncthreads();

    if (MODE == 0) {
        // transpose via LDS: ltile[128 px][64 o] bf16, swizzled by (px&7)<<4
        #pragma unroll
        for (int fo = 0; fo < 2; fo++) {
            #pragma unroll
            for (int q = 0; q < 4; q++) {
                int ob = fo * 32 + q * 8 + 4 * lhi;
                #pragma unroll
                for (int h = 0; h < 2; h++) {
                    float v0 = acc[fo][q * 4 + h * 2] + bias[ob + h * 2];
                    float v1 = acc[fo][q * 4 + h * 2 + 1] + bias[ob + h * 2 + 1];
                    if (RELU) { v0 = fmaxf(v0, 0.f); v1 = fmaxf(v1, 0.f); }
                    u32 pk = (u32)f2bf(v0) | ((u32)f2bf(v1) << 16);
                    int byte = px * 128 + (((ob + h * 2) * 2) ^ ((px & 7) << 4));
                    *reinterpret_cast<u32*>(lds_h + byte) = pk;
                }
            }
        }
        __syncthreads();
        for (int i = 0; i < 4; i++) {
            int cid = i * 256 + t;      // 1024 chunks of 16B
            int p = cid >> 3, g = cid & 7;
            short8 v = *reinterpret_cast<const short8*>(lds_h + p * 128 + ((g * 16) ^ ((p & 7) << 4)));
            *reinterpret_cast<short8*>(&outH[(size_t)(pix0 + p) * 64 + g * 8]) = v;
        }
    } else {
        float* ltf = (float*)lds_h;     // [128][40]
        #pragma unroll
        for (int fo = 0; fo < 2; fo++) {
            #pragma unroll
            for (int r = 0; r < 16; r++) {
                int o = fo * 32 + (r & 3) + ((r >> 2) << 3) + (lhi << 2);
                if (o < 36) ltf[px * 40 + o] = acc[fo][r] + bias[o];
            }
        }
        __syncthreads();
        for (int i = t; i < 1152; i += 256) {
            int p = i / 9, q = i - 9 * (i / 9);
            float4 v = *reinterpret_cast<const float4*>(&ltf[p * 40 + q * 4]);
            *reinterpret_cast<float4*>(&outF[(size_t)(pix0 + p) * 36 + q * 4]) = v;
        }
    }
}

// DCNv1 on h (bf16, C=64), fp32 math. Block = 16 px. feat f32 out.
__global__ __launch_bounds__(256) void dconv_small_k(const u16* __restrict__ h,
                                                     const float* __restrict__ offs,
                                                     const float* __restrict__ wdc,
                                                     float* __restrict__ feat)
{
    __shared__ float s[16][580];
    __shared__ float cw[144][4];
    __shared__ int   ca[144][4];
    int t = threadIdx.x;
    int pix0 = blockIdx.x * 16;
    int b = pix0 >> 12;
    if (t < 144) {
        int pl = t / 9, k = t - 9 * (t / 9);
        int pix = pix0 + pl;
        int pib = pix & 4095; int y = pib >> 6, x = pib & 63;
        float offy = offs[(size_t)pix * 36 + 18 + k * 2];
        float offx = offs[(size_t)pix * 36 + 18 + k * 2 + 1];
        float py = (float)(y - 1 + k / 3) + offy;
        float px = (float)(x - 1 + (k - 3 * (k / 3))) + offx;
        float fy = floorf(py), fx = floorf(px);
        int y0 = (int)fy, x0 = (int)fx;
        float dy = py - fy, dx = px - fx;
        float wts[4] = { (1.f - dy) * (1.f - dx), (1.f - dy) * dx,
                         dy * (1.f - dx), dy * dx };
        #pragma unroll
        for (int j = 0; j < 4; j++) {
            int yy = y0 + (j >> 1), xx = x0 + (j & 1);
            bool valid = (yy >= 0 && yy < 64 && xx >= 0 && xx < 64);
            int yc = min(max(yy, 0), 63), xc = min(max(xx, 0), 63);
            ca[t][j] = (b * 4096 + yc * 64 + xc) * 64;
            cw[t][j] = valid ? wts[j] : 0.f;
        }
    }
    __syncthreads();
    for (int i = t; i < 2304; i += 256) {
        int cq = i & 15; int pk = i >> 4;
        float a0 = 0.f, a1 = 0.f, a2 = 0.f, a3 = 0.f;
        #pragma unroll
        for (int j = 0; j < 4; j++) {
            float w = cw[pk][j];
            const u16* p = h + ca[pk][j] + cq * 4;
            uint2 r = *reinterpret_cast<const uint2*>(p);
            a0 = fmaf(w, bf2f((u16)(r.x & 0xffff)), a0);
            a1 = fmaf(w, bf2f((u16)(r.x >> 16)), a1);
            a2 = fmaf(w, bf2f((u16)(r.y & 0xffff)), a2);
            a3 = fmaf(w, bf2f((u16)(r.y >> 16)), a3);
        }
        int p = pk / 9; int k = pk - 9 * p;
        *reinterpret_cast<float4*>(&s[p][k * 64 + cq * 4]) = make_float4(a0, a1, a2, a3);
    }
    __syncthreads();
    int o4 = (t & 15) * 4; int p = t >> 4;
    float acc[4] = {0.f, 0.f, 0.f, 0.f};
    for (int j = 0; j < 576; j += 4) {
        float sv[4];
        *reinterpret_cast<float4*>(sv) = *reinterpret_cast<const float4*>(&s[p][j]);
        #pragma unroll
        for (int jj = 0; jj < 4; jj++) {
            float4 w = *reinterpret_cast<const float4*>(&wdc[(j + jj) * 64 + o4]);
            acc[0] = fmaf(w.x, sv[jj], acc[0]);
            acc[1] = fmaf(w.y, sv[jj], acc[1]);
            acc[2] = fmaf(w.z, sv[jj], acc[2]);
            acc[3] = fmaf(w.w, sv[jj], acc[3]);
        }
    }
    int pix = pix0 + p;
    *reinterpret_cast<float4*>(&feat[(size_t)pix * 64 + o4]) =
        make_float4(acc[0], acc[1], acc[2], acc[3]);
}

__global__ __launch_bounds__(256) void mask_k(const float* __restrict__ feat,
                                              const float* __restrict__ m_w,
                                              const float* __restrict__ m_b,
                                              float* __restrict__ maskb)
{
    int pix = blockIdx.x * 256 + threadIdx.x;
    float f[64];
    const float* fr = feat + (size_t)pix * 64;
    #pragma unroll
    for (int q = 0; q < 16; q++) {
        float4 v = *reinterpret_cast<const float4*>(&fr[q * 4]);
        f[q * 4] = v.x; f[q * 4 + 1] = v.y; f[q * 4 + 2] = v.z; f[q * 4 + 3] = v.w;
    }
    for (int j = 0; j < 9; j++) {
        float a = m_b[j];
        #pragma unroll 8
        for (int c = 0; c < 64; c++) a = fmaf(f[c], m_w[j * 64 + c], a);
        maskb[(size_t)pix * 9 + j] = 1.f / (1.f + expf(-a));
    }
}

// ---------------------------------------------------------------------------
// Modulated DCNv2 (256->256), bf16 MFMA, pipelined.
// 256 blocks x 512 threads; block = 128 px x 256 o; 8 waves = 4(o) x 2(px).
// K = 36 steps of 64 (tap x 64ch). Weights dbuf + counted vmcnt(4).
// ---------------------------------------------------------------------------
__global__ __launch_bounds__(512) void dconv_big_mfma(
    const u16* __restrict__ xT, const float* __restrict__ offs,
    const float* __restrict__ maskb, const u16* __restrict__ wKg,
    const float* __restrict__ bias, float* __restrict__ out)
{
    __shared__ __attribute__((aligned(16))) u16 wtile[2][8][256][8];  // 64 KB
    __shared__ __attribute__((aligned(16))) u16 stile[8][128][8];     // 16 KB
    __shared__ __attribute__((aligned(16))) int   ca[9][128][4];      // 18 KB
    __shared__ __attribute__((aligned(16))) float cw[9][128][4];      // 18 KB

    int t = threadIdx.x;
    int id = blockIdx.x;                      // 256
    int blk = (id & 7) * 32 + (id >> 3);      // XCD swizzle: XCD x -> batch x
    int pix0 = blk * 128;
    int b = pix0 >> 12, pib0 = pix0 & 4095;
    int wid = t >> 6, lane = t & 63;
    int lrow = lane & 31, lhi = lane >> 5;
    int o0 = (wid & 3) << 6;
    int px0 = (wid >> 2) << 6;
    int gpx = t & 127, hq = t >> 7;           // gather mapping

    // prologue: all 9 tap corner tables
    #pragma unroll
    for (int it = 0; it < 9; it++) {
        int i = it * 512 + t;
        int j = i & 3; int px = (i >> 2) & 127; int tap = i >> 9;
        int pix = pix0 + px; int pib = pix & 4095;
        int y = pib >> 6, x = pib & 63;
        float offy = offs[(size_t)pix * 36 + tap * 2];
        float offx = offs[(size_t)pix * 36 + tap * 2 + 1];
        float m = maskb[(size_t)pix * 9 + tap];
        float py = (float)(y - 1 + tap / 3) + offy;
        float pxf = (float)(x - 1 + (tap % 3)) + offx;
        float fy = floorf(py), fx = floorf(pxf);
        int y0 = (int)fy, x0 = (int)fx;
        float dy = py - fy, dx = pxf - fx;
        float wj = ((j >> 1) ? dy : 1.f - dy) * ((j & 1) ? dx : 1.f - dx);
        int yy = y0 + (j >> 1), xx = x0 + (j & 1);
        bool valid = (yy >= 0 && yy < 64 && xx >= 0 && xx < 64);
        int yc = min(max(yy, 0), 63), xc = min(max(xx, 0), 63);
        ca[tap][px][j] = (b * 4096 + yc * 64 + xc) << 8;
        cw[tap][px][j] = valid ? wj * m : 0.f;
    }
    // stage weights for kt=0
    {
        const char* gb = (const char*)wKg;
        char* lb = (char*)&wtile[0][0][0][0];
        #pragma unroll
        for (int i = 0; i < 4; i++) {
            int off = i * 8192 + wid * 1024;
            __builtin_amdgcn_global_load_lds(
                (const __attribute__((address_space(1))) void*)(gb + off + lane * 16),
                (__attribute__((address_space(3))) void*)(lb + off), 16, 0, 0);
        }
    }
    __syncthreads();

    f32x16 acc[2][2];
    #pragma unroll
    for (int fo = 0; fo < 2; fo++)
        #pragma unroll
        for (int fp = 0; fp < 2; fp++)
            #pragma unroll
            for (int r = 0; r < 16; r++) acc[fo][fp][r] = 0.f;

    for (int kt = 0; kt < 36; ++kt) {
        int cur = kt & 1, nxt = cur ^ 1;
        int tap = kt >> 2, chunk = kt & 3;

        // gather: 16 channels for pixel gpx
        int c = (chunk << 6) + (hq << 4);
        int4 cav = *reinterpret_cast<const int4*>(&ca[tap][gpx][0]);
        float4 cwv = *reinterpret_cast<const float4*>(&cw[tap][gpx][0]);
        float va[16];
        #pragma unroll
        for (int e = 0; e < 16; e++) va[e] = 0.f;
        {
            const int cai[4] = {cav.x, cav.y, cav.z, cav.w};
            const float cwi[4] = {cwv.x, cwv.y, cwv.z, cwv.w};
            #pragma unroll
            for (int j = 0; j < 4; j++) {
                float w = cwi[j];
                const u16* p = xT + cai[j] + c;
                short8 r0 = *reinterpret_cast<const short8*>(p);
                short8 r1 = *reinterpret_cast<const short8*>(p + 8);
                #pragma unroll
                for (int e = 0; e < 8; e++) {
                    va[e]     = fmaf(w, bf2f((u16)r0[e]), va[e]);
                    va[8 + e] = fmaf(w, bf2f((u16)r1[e]), va[8 + e]);
                }
            }
        }
        // prefetch next weights
        if (kt < 35) {
            const char* gb = (const char*)(wKg + (size_t)(kt + 1) * 16384);
            char* lb = (char*)&wtile[nxt][0][0][0];
            #pragma unroll
            for (int i = 0; i < 4; i++) {
                int off = i * 8192 + wid * 1024;
                __builtin_amdgcn_global_load_lds(
                    (const __attribute__((address_space(1))) void*)(gb + off + lane * 16),
                    (__attribute__((address_space(3))) void*)(lb + off), 16, 0, 0);
            }
        }
        // write stile
        short8 s0, s1;
        #pragma unroll
        for (int e = 0; e < 8; e++) { s0[e] = (short)f2bf(va[e]); s1[e] = (short)f2bf(va[8 + e]); }
        *reinterpret_cast<short8*>(&stile[hq * 2][gpx][0]) = s0;
        *reinterpret_cast<short8*>(&stile[hq * 2 + 1][gpx][0]) = s1;

        if (kt < 35) asm volatile("s_waitcnt vmcnt(4) lgkmcnt(0)" ::: "memory");
        else         asm volatile("s_waitcnt vmcnt(0) lgkmcnt(0)" ::: "memory");
        __builtin_amdgcn_s_barrier();

        #pragma unroll
        for (int ks = 0; ks < 4; ks++) {
            int kg = ks * 2 + lhi;
            short8 a0 = *reinterpret_cast<const short8*>(&wtile[cur][kg][o0 + lrow][0]);
            short8 a1 = *reinterpret_cast<const short8*>(&wtile[cur][kg][o0 + 32 + lrow][0]);
            short8 b0 = *reinterpret_cast<const short8*>(&stile[kg][px0 + lrow][0]);
            short8 b1 = *reinterpret_cast<const short8*>(&stile[kg][px0 + 32 + lrow][0]);
            acc[0][0] = __builtin_amdgcn_mfma_f32_32x32x16_bf16(a0, b0, acc[0][0], 0, 0, 0);
            acc[0][1] = __builtin_amdgcn_mfma_f32_32x32x16_bf16(a0, b1, acc[0][1], 0, 0, 0);
            acc[1][0] = __builtin_amdgcn_mfma_f32_32x32x16_bf16(a1, b0, acc[1][0], 0, 0, 0);
            acc[1][1] = __builtin_amdgcn_mfma_f32_32x32x16_bf16(a1, b1, acc[1][1], 0, 0, 0);
        }
        asm volatile("s_waitcnt lgkmcnt(0)" ::: "memory");
        __builtin_amdgcn_s_barrier();
    }

    // epilogue: bias + store NCHW f32
    #pragma unroll
    for (int fo = 0; fo < 2; fo++) {
        #pragma unroll
        for (int r = 0; r < 16; r++) {
            int o = o0 + fo * 32 + (r & 3) + ((r >> 2) << 3) + (lhi << 2);
            float bv = bias[o];
            size_t rowoff = ((size_t)(b * 256 + o) << 12) + pib0;
            out[rowoff + px0 + lrow] = acc[fo][0][r] + bv;
            out[rowoff + px0 + 32 + lrow] = acc[fo][1][r] + bv;
        }
    }
}

extern "C" void kernel_launch(void* const* d_in, const int* in_sizes, int n_in,
                              void* d_out, int out_size, void* d_ws, size_t ws_size,
                              hipStream_t stream)
{
    const float* x        = (const float*)d_in[0];
    const float* S        = (const float*)d_in[1];
    const float* sp_w1    = (const float*)d_in[2];
    const float* sp_b1    = (const float*)d_in[3];
    const float* sp_s1    = (const float*)d_in[4];
    const float* sp_o1    = (const float*)d_in[5];
    const float* sp_w2    = (const float*)d_in[6];
    const float* sp_b2    = (const float*)d_in[7];
    const float* sp_s2    = (const float*)d_in[8];
    const float* sp_o2    = (const float*)d_in[9];
    const float* sp_w3    = (const float*)d_in[10];
    const float* sp_b3    = (const float*)d_in[11];
    const float* sp_s3    = (const float*)d_in[12];
    const float* sp_o3    = (const float*)d_in[13];
    const float* off_w    = (const float*)d_in[14];
    const float* off_b    = (const float*)d_in[15];
    const float* dc_off_w = (const float*)d_in[16];
    const float* dc_off_b = (const float*)d_in[17];
    const float* dc_w     = (const float*)d_in[18];
    const float* m_w      = (const float*)d_in[19];
    const float* m_b      = (const float*)d_in[20];
    const float* weight   = (const float*)d_in[21];
    const float* bias     = (const float*)d_in[22];
    float* out = (float*)d_out;
    float* ws  = (float*)d_ws;

    u16*   xTb   = (u16*)(ws + OXT);
    float* Si    = ws + OSI;
    u16*   h1    = (u16*)(ws + OA);
    u16*   h2    = (u16*)(ws + OB);
    u16*   h3    = (u16*)(ws + OC);
    float* featf = ws + OB;            // reuse after h2 dead
    float* offsb = ws + OOFFS;
    float* maskb = ws + OMSK;

    prep_k<<<2888, 256, 0, stream>>>(weight, sp_w1, sp_s1, sp_w2, sp_s2, sp_w3, sp_s3,
                                     off_w, dc_off_w, dc_w,
                                     sp_b1, sp_o1, sp_b2, sp_o2, sp_b3, sp_o3,
                                     off_b, dc_off_b, ws);
    transpose_x_k<<<2048, 256, 0, stream>>>(x, xTb);
    resize_k<<<384, 256, 0, stream>>>(S, Si);
    conv_in_k<<<512, 256, 0, stream>>>(Si, ws + OWSP1, ws + OBSP1, h1);
    conv_mfma_k<0, true><<<256, 256, 0, stream>>>(h1, (const u16*)(ws + OWSP2),
                                                  ws + OBSP2, h2, nullptr);
    conv_mfma_k<0, true><<<256, 256, 0, stream>>>(h2, (const u16*)(ws + OWSP3),
                                                  ws + OBSP3, h3, nullptr);
    conv_mfma_k<1, false><<<256, 256, 0, stream>>>(h3, (const u16*)(ws + OWOFF),
                                                   ws + OBOFF, nullptr, offsb);
    dconv_small_k<<<2048, 256, 0, stream>>>(h3, offsb, ws + OWDC, featf);
    mask_k<<<128, 256, 0, stream>>>(featf, m_w, m_b, maskb);
    dconv_big_mfma<<<256, 512, 0, stream>>>(xTb, offsb, maskb,
                                            (const u16*)(ws + OWT), bias, out);
}

// Round 4
// 224.339 us; speedup vs baseline: 4.3789x; 1.5031x over previous
//
#include <hip/hip_runtime.h>
#include <hip/hip_bf16.h>

typedef unsigned short u16;
typedef unsigned int u32;
typedef __attribute__((ext_vector_type(8))) short short8;
typedef __attribute__((ext_vector_type(4))) unsigned short ush4;
typedef __attribute__((ext_vector_type(16))) float f32x16;

// ---------------------------------------------------------------------------
// ws layout (float units):
//   OXT   xT bf16 [8][64][64][256]
//   OSI   Si f32  [8][64][64][3]
//   OA    h1 bf16 [32768][64]
//   OB    h2 bf16 -> later feat f32 [32768][64]
//   OC    h3 bf16 [32768][64]
//   OOFFS offs f32 [32768][36]
//   OMSK  mask f32 [32768][9]
//   OWT   wKg bf16 [288][256][8]
//   OWSP1 f32 [9][3][64];  OWSP2/OWSP3/OWOFF/OWDC bf16 [9][8][64][8]
// ---------------------------------------------------------------------------
#define OXT   0
#define OSI   (OXT + 8388608)
#define OA    (OSI + 98304)
#define OB    (OA + 2097152)
#define OC    (OB + 2097152)
#define OOFFS (OC + 2097152)
#define OMSK  (OOFFS + 1179648)
#define OWT   (OMSK + 294912)
#define OWSP1 (OWT + 589824)
#define OBSP1 (OWSP1 + 1728)
#define OWSP2 (OBSP1 + 64)
#define OBSP2 (OWSP2 + 36864)
#define OWSP3 (OBSP2 + 64)
#define OBSP3 (OWSP3 + 36864)
#define OWOFF (OBSP3 + 64)
#define OBOFF (OWOFF + 36864)
#define OWDC  (OBOFF + 64)

__device__ __forceinline__ u16 f2bf(float f) {
    __hip_bfloat16 hb = __float2bfloat16(f);
    return __builtin_bit_cast(u16, hb);
}
__device__ __forceinline__ float bf2f(u16 v) {
    return __builtin_bit_cast(float, (u32)v << 16);
}

// ---------------------------------------------------------------------------
__global__ __launch_bounds__(256) void prep_k(
    const float* __restrict__ weight,
    const float* __restrict__ sp_w1, const float* __restrict__ sp_s1,
    const float* __restrict__ sp_w2, const float* __restrict__ sp_s2,
    const float* __restrict__ sp_w3, const float* __restrict__ sp_s3,
    const float* __restrict__ off_w, const float* __restrict__ dc_off_w,
    const float* __restrict__ dc_w,
    const float* __restrict__ sp_b1, const float* __restrict__ sp_o1,
    const float* __restrict__ sp_b2, const float* __restrict__ sp_o2,
    const float* __restrict__ sp_b3, const float* __restrict__ sp_o3,
    const float* __restrict__ off_b, const float* __restrict__ dc_off_b,
    float* __restrict__ ws)
{
    int i = blockIdx.x * 256 + threadIdx.x;
    if (i < 589824) {   // wKg bf16 [kg][o][j], K=kg*8+j = k*256+c
        int j = i & 7; int o = (i >> 3) & 255; int kg = i >> 11;
        int K = kg * 8 + j; int k = K >> 8; int c = K & 255;
        ((u16*)(ws + OWT))[i] = f2bf(weight[o * 2304 + c * 9 + k]);
        return;
    }
    i -= 589824;
    if (i < 1728) {     // wsp1 f32 [9][3][64]
        int o = i & 63; int kc = i >> 6; int c = kc % 3; int k = kc / 3;
        ws[OWSP1 + i] = sp_w1[(o * 3 + c) * 9 + k] * sp_s1[o];
        return;
    }
    i -= 1728;
    if (i < 36864) {    // wm2 bf16 [t][kg][o][e]
        int e = i & 7; int o = (i >> 3) & 63; int kg = (i >> 9) & 7; int tp = i >> 12;
        ((u16*)(ws + OWSP2))[i] = f2bf(sp_w2[(o * 64 + kg * 8 + e) * 9 + tp] * sp_s2[o]);
        return;
    }
    i -= 36864;
    if (i < 36864) {
        int e = i & 7; int o = (i >> 3) & 63; int kg = (i >> 9) & 7; int tp = i >> 12;
        ((u16*)(ws + OWSP3))[i] = f2bf(sp_w3[(o * 64 + kg * 8 + e) * 9 + tp] * sp_s3[o]);
        return;
    }
    i -= 36864;
    if (i < 36864) {    // woff bf16, o<18 off_w, 18..35 dc_off_w, else 0
        int e = i & 7; int o = (i >> 3) & 63; int kg = (i >> 9) & 7; int tp = i >> 12;
        int c = kg * 8 + e;
        float v = 0.f;
        if (o < 18) v = off_w[(o * 64 + c) * 9 + tp];
        else if (o < 36) v = dc_off_w[((o - 18) * 64 + c) * 9 + tp];
        ((u16*)(ws + OWOFF))[i] = f2bf(v);
        return;
    }
    i -= 36864;
    if (i < 36864) {    // wdc bf16 [t][kg][o][e]
        int e = i & 7; int o = (i >> 3) & 63; int kg = (i >> 9) & 7; int tp = i >> 12;
        ((u16*)(ws + OWDC))[i] = f2bf(dc_w[(o * 64 + kg * 8 + e) * 9 + tp]);
        return;
    }
    i -= 36864;
    if (i < 64) { ws[OBSP1 + i] = sp_b1[i] * sp_s1[i] + sp_o1[i]; return; }
    i -= 64;
    if (i < 64) { ws[OBSP2 + i] = sp_b2[i] * sp_s2[i] + sp_o2[i]; return; }
    i -= 64;
    if (i < 64) { ws[OBSP3 + i] = sp_b3[i] * sp_s3[i] + sp_o3[i]; return; }
    i -= 64;
    if (i < 64) { ws[OBOFF + i] = (i < 18) ? off_b[i] : (i < 36 ? dc_off_b[i - 18] : 0.f); return; }
}

// x NCHW f32 -> xT NHWC bf16
__global__ __launch_bounds__(256) void transpose_x_k(const float* __restrict__ x,
                                                     u16* __restrict__ xT)
{
    __shared__ float tile[64][65];
    int blk = blockIdx.x;
    int chunk = blk & 3; int by = blk >> 2;
    int b = by >> 6; int y = by & 63;
    int c0 = chunk * 64;
    int t = threadIdx.x;
    for (int i = t; i < 4096; i += 256) {
        int ci = i >> 6, xi = i & 63;
        tile[ci][xi] = x[((b * 256 + c0 + ci) * 64 + y) * 64 + xi];
    }
    __syncthreads();
    for (int i = t; i < 4096; i += 256) {
        int xi = i >> 6, ci = i & 63;
        xT[((b * 64 + y) * 64 + xi) * 256 + c0 + ci] = f2bf(tile[ci][xi]);
    }
}

__global__ __launch_bounds__(256) void resize_k(const float* __restrict__ S,
                                                float* __restrict__ Si)
{
    int i = blockIdx.x * 256 + threadIdx.x;
    if (i >= 8 * 64 * 64 * 3) return;
    int c = i % 3; int x = (i / 3) & 63; int y = (i / 192) & 63; int b = i / 12288;
    const float sc = 127.0f / 63.0f;
    float sy = y * sc, sx = x * sc;
    float fy = floorf(sy), fx = floorf(sx);
    int y0 = (int)fy, x0 = (int)fx;
    int y1 = min(y0 + 1, 127), x1 = min(x0 + 1, 127);
    float wy = sy - fy, wx = sx - fx;
    const float* Sb = S + (size_t)(b * 3 + c) * 16384;
    float v00 = Sb[y0 * 128 + x0], v01 = Sb[y0 * 128 + x1];
    float v10 = Sb[y1 * 128 + x0], v11 = Sb[y1 * 128 + x1];
    Si[i] = (v00 * (1.f - wy) + v10 * wy) * (1.f - wx)
          + (v01 * (1.f - wy) + v11 * wy) * wx;
}

// conv1: 3->64, fp32 VALU, bf16 NHWC output. One block per (b,y) row.
__global__ __launch_bounds__(256) void conv_in_k(const float* __restrict__ in,
                                                 const float* __restrict__ wt,
                                                 const float* __restrict__ bias,
                                                 u16* __restrict__ out)
{
    __shared__ float rows[3][66][3];
    int by = blockIdx.x; int b = by >> 6; int y = by & 63;
    int t = threadIdx.x;
    for (int i = t; i < 3 * 66 * 3; i += 256) {
        int r = i / 198; int rem = i - r * 198;
        int xi = rem / 3; int c = rem - xi * 3;
        int yy = y - 1 + r, xx = xi - 1;
        float v = 0.f;
        if (yy >= 0 && yy < 64 && xx >= 0 && xx < 64)
            v = in[(((b * 64 + yy) * 64 + xx) * 3) + c];
        rows[r][xi][c] = v;
    }
    __syncthreads();
    int o4 = (t & 15) * 4; int xg = t >> 4;
    float acc[4][4];
    #pragma unroll
    for (int oi = 0; oi < 4; oi++) {
        float bv = bias[o4 + oi];
        #pragma unroll
        for (int xi = 0; xi < 4; xi++) acc[oi][xi] = bv;
    }
    for (int k = 0; k < 9; k++) {
        int dy = k / 3, dx = k - 3 * (k / 3);
        for (int c = 0; c < 3; c++) {
            float4 w = *reinterpret_cast<const float4*>(&wt[(k * 3 + c) * 64 + o4]);
            #pragma unroll
            for (int xi = 0; xi < 4; xi++) {
                float iv = rows[dy][xg * 4 + xi + dx][c];
                acc[0][xi] = fmaf(w.x, iv, acc[0][xi]);
                acc[1][xi] = fmaf(w.y, iv, acc[1][xi]);
                acc[2][xi] = fmaf(w.z, iv, acc[2][xi]);
                acc[3][xi] = fmaf(w.w, iv, acc[3][xi]);
            }
        }
    }
    #pragma unroll
    for (int xi = 0; xi < 4; xi++) {
        int x = xg * 4 + xi;
        ush4 v;
        v.x = f2bf(fmaxf(acc[0][xi], 0.f));
        v.y = f2bf(fmaxf(acc[1][xi], 0.f));
        v.z = f2bf(fmaxf(acc[2][xi], 0.f));
        v.w = f2bf(fmaxf(acc[3][xi], 0.f));
        *reinterpret_cast<ush4*>(&out[((size_t)(by * 64 + x)) * 64 + o4]) = v;
    }
}

// ---------------------------------------------------------------------------
// MFMA 3x3 conv 64->64 (MODE 0: bf16 NHWC out + bias + optional ReLU;
// MODE 1: f32 [px][36] offs out + bias). Block: 2 rows = 128 px, 4 waves.
// ---------------------------------------------------------------------------
template <int MODE, bool RELU>
__global__ __launch_bounds__(256) void conv_mfma_k(const u16* __restrict__ in,
                                                   const u16* __restrict__ wm,
                                                   const float* __restrict__ bias,
                                                   u16* __restrict__ outH,
                                                   float* __restrict__ outF)
{
    __shared__ __attribute__((aligned(16))) char lds_h[4 * 66 * 128];   // 33.8 KB
    __shared__ __attribute__((aligned(16))) u16 wtap[2][8][64][8];      // 16 KB

    int t = threadIdx.x;
    int b = blockIdx.x >> 5; int y0 = (blockIdx.x & 31) * 2;
    int pix0 = b * 4096 + y0 * 64;
    int wid = t >> 6, lane = t & 63;
    int lrow = lane & 31, lhi = lane >> 5;
    int px = wid * 32 + lrow;
    int ry_l = px >> 6, xc = px & 63;

    for (int i = t; i < 4 * 66 * 8; i += 256) {
        int r = i / 528; int rem = i - r * 528;
        int xi = rem >> 3; int g = rem & 7;
        int yy = y0 - 1 + r, xx = xi - 1;
        short8 v = {0,0,0,0,0,0,0,0};
        if (yy >= 0 && yy < 64 && xx >= 0 && xx < 64)
            v = *reinterpret_cast<const short8*>(&in[(size_t)((b * 4096 + yy * 64 + xx)) * 64 + g * 8]);
        int byte = (r * 66 + xi) * 128 + ((g * 16) ^ ((xi & 7) << 4));
        *reinterpret_cast<short8*>(lds_h + byte) = v;
    }
    {
        const char* gb = (const char*)(wm);
        char* lb = (char*)&wtap[0][0][0][0];
        #pragma unroll
        for (int i = 0; i < 2; i++) {
            int off = i * 4096 + wid * 1024;
            __builtin_amdgcn_global_load_lds(
                (const __attribute__((address_space(1))) void*)(gb + off + lane * 16),
                (__attribute__((address_space(3))) void*)(lb + off), 16, 0, 0);
        }
    }
    __syncthreads();

    f32x16 acc[2];
    #pragma unroll
    for (int fo = 0; fo < 2; fo++)
        #pragma unroll
        for (int r = 0; r < 16; r++) acc[fo][r] = 0.f;

    for (int tap = 0; tap < 9; tap++) {
        int cur = tap & 1, nxt = cur ^ 1;
        if (tap < 8) {
            const char* gb = (const char*)(wm + (size_t)(tap + 1) * 4096);
            char* lb = (char*)&wtap[nxt][0][0][0];
            #pragma unroll
            for (int i = 0; i < 2; i++) {
                int off = i * 4096 + wid * 1024;
                __builtin_amdgcn_global_load_lds(
                    (const __attribute__((address_space(1))) void*)(gb + off + lane * 16),
                    (__attribute__((address_space(3))) void*)(lb + off), 16, 0, 0);
            }
        }
        int dy = tap / 3, dx = tap - 3 * (tap / 3);
        int ry = ry_l + dy;
        int xi = xc + dx;
        int rowbyte = (ry * 66 + xi) * 128;
        int swz = (xi & 7) << 4;
        #pragma unroll
        for (int ks = 0; ks < 4; ks++) {
            int kg = ks * 2 + lhi;
            short8 a0 = *reinterpret_cast<const short8*>(&wtap[cur][kg][lrow][0]);
            short8 a1 = *reinterpret_cast<const short8*>(&wtap[cur][kg][32 + lrow][0]);
            short8 b0 = *reinterpret_cast<const short8*>(lds_h + rowbyte + ((kg * 16) ^ swz));
            acc[0] = __builtin_amdgcn_mfma_f32_32x32x16_bf16(a0, b0, acc[0], 0, 0, 0);
            acc[1] = __builtin_amdgcn_mfma_f32_32x32x16_bf16(a1, b0, acc[1], 0, 0, 0);
        }
        if (tap < 8) asm volatile("s_waitcnt vmcnt(0)" ::: "memory");
        __builtin_amdgcn_s_barrier();
    }
    __syncthreads();

    if (MODE == 0) {
        #pragma unroll
        for (int fo = 0; fo < 2; fo++) {
            #pragma unroll
            for (int q = 0; q < 4; q++) {
                int ob = fo * 32 + q * 8 + 4 * lhi;
                #pragma unroll
                for (int h = 0; h < 2; h++) {
                    float v0 = acc[fo][q * 4 + h * 2] + bias[ob + h * 2];
                    float v1 = acc[fo][q * 4 + h * 2 + 1] + bias[ob + h * 2 + 1];
                    if (RELU) { v0 = fmaxf(v0, 0.f); v1 = fmaxf(v1, 0.f); }
                    u32 pk = (u32)f2bf(v0) | ((u32)f2bf(v1) << 16);
                    int byte = px * 128 + (((ob + h * 2) * 2) ^ ((px & 7) << 4));
                    *reinterpret_cast<u32*>(lds_h + byte) = pk;
                }
            }
        }
        __syncthreads();
        for (int i = 0; i < 4; i++) {
            int cid = i * 256 + t;
            int p = cid >> 3, g = cid & 7;
            short8 v = *reinterpret_cast<const short8*>(lds_h + p * 128 + ((g * 16) ^ ((p & 7) << 4)));
            *reinterpret_cast<short8*>(&outH[(size_t)(pix0 + p) * 64 + g * 8]) = v;
        }
    } else {
        float* ltf = (float*)lds_h;
        #pragma unroll
        for (int fo = 0; fo < 2; fo++) {
            #pragma unroll
            for (int r = 0; r < 16; r++) {
                int o = fo * 32 + (r & 3) + ((r >> 2) << 3) + (lhi << 2);
                if (o < 36) ltf[px * 40 + o] = acc[fo][r] + bias[o];
            }
        }
        __syncthreads();
        for (int i = t; i < 1152; i += 256) {
            int p = i / 9, q = i - 9 * (i / 9);
            float4 v = *reinterpret_cast<const float4*>(&ltf[p * 40 + q * 4]);
            *reinterpret_cast<float4*>(&outF[(size_t)(pix0 + p) * 36 + q * 4]) = v;
        }
    }
}

// ---------------------------------------------------------------------------
// DCNv1 on h (bf16, 64->64), bf16 MFMA. 256 blocks x 512 thr; 128px x 64o.
// K = 9 taps x 64ch; per-tap 8KB weights dbuf'd with counted vmcnt(1).
// wdc bf16 [9 tap][8 kg][64 o][8 e]. offs channels 18..35, no mask.
// ---------------------------------------------------------------------------
__global__ __launch_bounds__(512) void dconv_small_mfma(
    const u16* __restrict__ h, const float* __restrict__ offs,
    const u16* __restrict__ wdc, float* __restrict__ feat)
{
    __shared__ __attribute__((aligned(16))) u16 wtile[2][8][64][8];   // 16 KB
    __shared__ __attribute__((aligned(16))) u16 stile[8][128][8];     // 16 KB
    __shared__ __attribute__((aligned(16))) int   ca[9][128][4];      // 18 KB
    __shared__ __attribute__((aligned(16))) float cw[9][128][4];      // 18 KB

    int t = threadIdx.x;
    int id = blockIdx.x;
    int blk = (id & 7) * 32 + (id >> 3);      // XCD swizzle
    int pix0 = blk * 128;
    int b = pix0 >> 12;
    int wid = t >> 6, lane = t & 63;
    int lrow = lane & 31, lhi = lane >> 5;
    int o0 = (wid & 1) << 5;
    int px0 = (wid >> 1) << 5;
    int gpx = t & 127, hq = t >> 7;

    #pragma unroll
    for (int it = 0; it < 9; it++) {
        int i = it * 512 + t;
        int j = i & 3; int px = (i >> 2) & 127; int tap = i >> 9;
        int pix = pix0 + px; int pib = pix & 4095;
        int y = pib >> 6, x = pib & 63;
        float offy = offs[(size_t)pix * 36 + 18 + tap * 2];
        float offx = offs[(size_t)pix * 36 + 18 + tap * 2 + 1];
        float py = (float)(y - 1 + tap / 3) + offy;
        float pxf = (float)(x - 1 + (tap % 3)) + offx;
        float fy = floorf(py), fx = floorf(pxf);
        int y0 = (int)fy, x0 = (int)fx;
        float dy = py - fy, dx = pxf - fx;
        float wj = ((j >> 1) ? dy : 1.f - dy) * ((j & 1) ? dx : 1.f - dx);
        int yy = y0 + (j >> 1), xx = x0 + (j & 1);
        bool valid = (yy >= 0 && yy < 64 && xx >= 0 && xx < 64);
        int yc = min(max(yy, 0), 63), xc = min(max(xx, 0), 63);
        ca[tap][px][j] = (b * 4096 + yc * 64 + xc) << 6;
        cw[tap][px][j] = valid ? wj : 0.f;
    }
    {
        const char* gb = (const char*)wdc;
        char* lb = (char*)&wtile[0][0][0][0];
        __builtin_amdgcn_global_load_lds(
            (const __attribute__((address_space(1))) void*)(gb + wid * 1024 + lane * 16),
            (__attribute__((address_space(3))) void*)(lb + wid * 1024), 16, 0, 0);
    }
    __syncthreads();

    f32x16 acc;
    #pragma unroll
    for (int r = 0; r < 16; r++) acc[r] = 0.f;

    for (int tap = 0; tap < 9; ++tap) {
        int cur = tap & 1, nxt = cur ^ 1;
        // gather 16 channels of pixel gpx
        int c = hq << 4;
        int4 cav = *reinterpret_cast<const int4*>(&ca[tap][gpx][0]);
        float4 cwv = *reinterpret_cast<const float4*>(&cw[tap][gpx][0]);
        float va[16];
        #pragma unroll
        for (int e = 0; e < 16; e++) va[e] = 0.f;
        {
            const int cai[4] = {cav.x, cav.y, cav.z, cav.w};
            const float cwi[4] = {cwv.x, cwv.y, cwv.z, cwv.w};
            #pragma unroll
            for (int j = 0; j < 4; j++) {
                float w = cwi[j];
                const u16* p = h + cai[j] + c;
                short8 r0 = *reinterpret_cast<const short8*>(p);
                short8 r1 = *reinterpret_cast<const short8*>(p + 8);
                #pragma unroll
                for (int e = 0; e < 8; e++) {
                    va[e]     = fmaf(w, bf2f((u16)r0[e]), va[e]);
                    va[8 + e] = fmaf(w, bf2f((u16)r1[e]), va[8 + e]);
                }
            }
        }
        // prefetch next tap weights (1 load/thread)
        if (tap < 8) {
            const char* gb = (const char*)(wdc + (size_t)(tap + 1) * 4096);
            char* lb = (char*)&wtile[nxt][0][0][0];
            __builtin_amdgcn_global_load_lds(
                (const __attribute__((address_space(1))) void*)(gb + wid * 1024 + lane * 16),
                (__attribute__((address_space(3))) void*)(lb + wid * 1024), 16, 0, 0);
        }
        short8 s0, s1;
        #pragma unroll
        for (int e = 0; e < 8; e++) { s0[e] = (short)f2bf(va[e]); s1[e] = (short)f2bf(va[8 + e]); }
        *reinterpret_cast<short8*>(&stile[hq * 2][gpx][0]) = s0;
        *reinterpret_cast<short8*>(&stile[hq * 2 + 1][gpx][0]) = s1;

        if (tap < 8) asm volatile("s_waitcnt vmcnt(1) lgkmcnt(0)" ::: "memory");
        else         asm volatile("s_waitcnt vmcnt(0) lgkmcnt(0)" ::: "memory");
        __builtin_amdgcn_s_barrier();

        #pragma unroll
        for (int ks = 0; ks < 4; ks++) {
            int kg = ks * 2 + lhi;
            short8 a0 = *reinterpret_cast<const short8*>(&wtile[cur][kg][o0 + lrow][0]);
            short8 b0 = *reinterpret_cast<const short8*>(&stile[kg][px0 + lrow][0]);
            acc = __builtin_amdgcn_mfma_f32_32x32x16_bf16(a0, b0, acc, 0, 0, 0);
        }
        asm volatile("s_waitcnt lgkmcnt(0)" ::: "memory");
        __builtin_amdgcn_s_barrier();
    }

    // epilogue: feat f32 NHWC
    int pix = pix0 + px0 + lrow;
    #pragma unroll
    for (int r = 0; r < 16; r++) {
        int o = o0 + (r & 3) + ((r >> 2) << 3) + (lhi << 2);
        feat[(size_t)pix * 64 + o] = acc[r];
    }
}

__global__ __launch_bounds__(256) void mask_k(const float* __restrict__ feat,
                                              const float* __restrict__ m_w,
                                              const float* __restrict__ m_b,
                                              float* __restrict__ maskb)
{
    int pix = blockIdx.x * 256 + threadIdx.x;
    float f[64];
    const float* fr = feat + (size_t)pix * 64;
    #pragma unroll
    for (int q = 0; q < 16; q++) {
        float4 v = *reinterpret_cast<const float4*>(&fr[q * 4]);
        f[q * 4] = v.x; f[q * 4 + 1] = v.y; f[q * 4 + 2] = v.z; f[q * 4 + 3] = v.w;
    }
    for (int j = 0; j < 9; j++) {
        float a = m_b[j];
        #pragma unroll 8
        for (int c = 0; c < 64; c++) a = fmaf(f[c], m_w[j * 64 + c], a);
        maskb[(size_t)pix * 9 + j] = 1.f / (1.f + expf(-a));
    }
}

// ---------------------------------------------------------------------------
// Modulated DCNv2 (256->256), bf16 MFMA, pipelined.
// ---------------------------------------------------------------------------
__global__ __launch_bounds__(512) void dconv_big_mfma(
    const u16* __restrict__ xT, const float* __restrict__ offs,
    const float* __restrict__ maskb, const u16* __restrict__ wKg,
    const float* __restrict__ bias, float* __restrict__ out)
{
    __shared__ __attribute__((aligned(16))) u16 wtile[2][8][256][8];  // 64 KB
    __shared__ __attribute__((aligned(16))) u16 stile[8][128][8];     // 16 KB
    __shared__ __attribute__((aligned(16))) int   ca[9][128][4];      // 18 KB
    __shared__ __attribute__((aligned(16))) float cw[9][128][4];      // 18 KB

    int t = threadIdx.x;
    int id = blockIdx.x;
    int blk = (id & 7) * 32 + (id >> 3);      // XCD swizzle
    int pix0 = blk * 128;
    int b = pix0 >> 12, pib0 = pix0 & 4095;
    int wid = t >> 6, lane = t & 63;
    int lrow = lane & 31, lhi = lane >> 5;
    int o0 = (wid & 3) << 6;
    int px0 = (wid >> 2) << 6;
    int gpx = t & 127, hq = t >> 7;

    #pragma unroll
    for (int it = 0; it < 9; it++) {
        int i = it * 512 + t;
        int j = i & 3; int px = (i >> 2) & 127; int tap = i >> 9;
        int pix = pix0 + px; int pib = pix & 4095;
        int y = pib >> 6, x = pib & 63;
        float offy = offs[(size_t)pix * 36 + tap * 2];
        float offx = offs[(size_t)pix * 36 + tap * 2 + 1];
        float m = maskb[(size_t)pix * 9 + tap];
        float py = (float)(y - 1 + tap / 3) + offy;
        float pxf = (float)(x - 1 + (tap % 3)) + offx;
        float fy = floorf(py), fx = floorf(pxf);
        int y0 = (int)fy, x0 = (int)fx;
        float dy = py - fy, dx = pxf - fx;
        float wj = ((j >> 1) ? dy : 1.f - dy) * ((j & 1) ? dx : 1.f - dx);
        int yy = y0 + (j >> 1), xx = x0 + (j & 1);
        bool valid = (yy >= 0 && yy < 64 && xx >= 0 && xx < 64);
        int yc = min(max(yy, 0), 63), xc = min(max(xx, 0), 63);
        ca[tap][px][j] = (b * 4096 + yc * 64 + xc) << 8;
        cw[tap][px][j] = valid ? wj * m : 0.f;
    }
    {
        const char* gb = (const char*)wKg;
        char* lb = (char*)&wtile[0][0][0][0];
        #pragma unroll
        for (int i = 0; i < 4; i++) {
            int off = i * 8192 + wid * 1024;
            __builtin_amdgcn_global_load_lds(
                (const __attribute__((address_space(1))) void*)(gb + off + lane * 16),
                (__attribute__((address_space(3))) void*)(lb + off), 16, 0, 0);
        }
    }
    __syncthreads();

    f32x16 acc[2][2];
    #pragma unroll
    for (int fo = 0; fo < 2; fo++)
        #pragma unroll
        for (int fp = 0; fp < 2; fp++)
            #pragma unroll
            for (int r = 0; r < 16; r++) acc[fo][fp][r] = 0.f;

    for (int kt = 0; kt < 36; ++kt) {
        int cur = kt & 1, nxt = cur ^ 1;
        int tap = kt >> 2, chunk = kt & 3;

        int c = (chunk << 6) + (hq << 4);
        int4 cav = *reinterpret_cast<const int4*>(&ca[tap][gpx][0]);
        float4 cwv = *reinterpret_cast<const float4*>(&cw[tap][gpx][0]);
        float va[16];
        #pragma unroll
        for (int e = 0; e < 16; e++) va[e] = 0.f;
        {
            const int cai[4] = {cav.x, cav.y, cav.z, cav.w};
            const float cwi[4] = {cwv.x, cwv.y, cwv.z, cwv.w};
            #pragma unroll
            for (int j = 0; j < 4; j++) {
                float w = cwi[j];
                const u16* p = xT + cai[j] + c;
                short8 r0 = *reinterpret_cast<const short8*>(p);
                short8 r1 = *reinterpret_cast<const short8*>(p + 8);
                #pragma unroll
                for (int e = 0; e < 8; e++) {
                    va[e]     = fmaf(w, bf2f((u16)r0[e]), va[e]);
                    va[8 + e] = fmaf(w, bf2f((u16)r1[e]), va[8 + e]);
                }
            }
        }
        if (kt < 35) {
            const char* gb = (const char*)(wKg + (size_t)(kt + 1) * 16384);
            char* lb = (char*)&wtile[nxt][0][0][0];
            #pragma unroll
            for (int i = 0; i < 4; i++) {
                int off = i * 8192 + wid * 1024;
                __builtin_amdgcn_global_load_lds(
                    (const __attribute__((address_space(1))) void*)(gb + off + lane * 16),
                    (__attribute__((address_space(3))) void*)(lb + off), 16, 0, 0);
            }
        }
        short8 s0, s1;
        #pragma unroll
        for (int e = 0; e < 8; e++) { s0[e] = (short)f2bf(va[e]); s1[e] = (short)f2bf(va[8 + e]); }
        *reinterpret_cast<short8*>(&stile[hq * 2][gpx][0]) = s0;
        *reinterpret_cast<short8*>(&stile[hq * 2 + 1][gpx][0]) = s1;

        if (kt < 35) asm volatile("s_waitcnt vmcnt(4) lgkmcnt(0)" ::: "memory");
        else         asm volatile("s_waitcnt vmcnt(0) lgkmcnt(0)" ::: "memory");
        __builtin_amdgcn_s_barrier();

        #pragma unroll
        for (int ks = 0; ks < 4; ks++) {
            int kg = ks * 2 + lhi;
            short8 a0 = *reinterpret_cast<const short8*>(&wtile[cur][kg][o0 + lrow][0]);
            short8 a1 = *reinterpret_cast<const short8*>(&wtile[cur][kg][o0 + 32 + lrow][0]);
            short8 b0 = *reinterpret_cast<const short8*>(&stile[kg][px0 + lrow][0]);
            short8 b1 = *reinterpret_cast<const short8*>(&stile[kg][px0 + 32 + lrow][0]);
            acc[0][0] = __builtin_amdgcn_mfma_f32_32x32x16_bf16(a0, b0, acc[0][0], 0, 0, 0);
            acc[0][1] = __builtin_amdgcn_mfma_f32_32x32x16_bf16(a0, b1, acc[0][1], 0, 0, 0);
            acc[1][0] = __builtin_amdgcn_mfma_f32_32x32x16_bf16(a1, b0, acc[1][0], 0, 0, 0);
            acc[1][1] = __builtin_amdgcn_mfma_f32_32x32x16_bf16(a1, b1, acc[1][1], 0, 0, 0);
        }
        asm volatile("s_waitcnt lgkmcnt(0)" ::: "memory");
        __builtin_amdgcn_s_barrier();
    }

    #pragma unroll
    for (int fo = 0; fo < 2; fo++) {
        #pragma unroll
        for (int r = 0; r < 16; r++) {
            int o = o0 + fo * 32 + (r & 3) + ((r >> 2) << 3) + (lhi << 2);
            float bv = bias[o];
            size_t rowoff = ((size_t)(b * 256 + o) << 12) + pib0;
            out[rowoff + px0 + lrow] = acc[fo][0][r] + bv;
            out[rowoff + px0 + 32 + lrow] = acc[fo][1][r] + bv;
        }
    }
}

extern "C" void kernel_launch(void* const* d_in, const int* in_sizes, int n_in,
                              void* d_out, int out_size, void* d_ws, size_t ws_size,
                              hipStream_t stream)
{
    const float* x        = (const float*)d_in[0];
    const float* S        = (const float*)d_in[1];
    const float* sp_w1    = (const float*)d_in[2];
    const float* sp_b1    = (const float*)d_in[3];
    const float* sp_s1    = (const float*)d_in[4];
    const float* sp_o1    = (const float*)d_in[5];
    const float* sp_w2    = (const float*)d_in[6];
    const float* sp_b2    = (const float*)d_in[7];
    const float* sp_s2    = (const float*)d_in[8];
    const float* sp_o2    = (const float*)d_in[9];
    const float* sp_w3    = (const float*)d_in[10];
    const float* sp_b3    = (const float*)d_in[11];
    const float* sp_s3    = (const float*)d_in[12];
    const float* sp_o3    = (const float*)d_in[13];
    const float* off_w    = (const float*)d_in[14];
    const float* off_b    = (const float*)d_in[15];
    const float* dc_off_w = (const float*)d_in[16];
    const float* dc_off_b = (const float*)d_in[17];
    const float* dc_w     = (const float*)d_in[18];
    const float* m_w      = (const float*)d_in[19];
    const float* m_b      = (const float*)d_in[20];
    const float* weight   = (const float*)d_in[21];
    const float* bias     = (const float*)d_in[22];
    float* out = (float*)d_out;
    float* ws  = (float*)d_ws;

    u16*   xTb   = (u16*)(ws + OXT);
    float* Si    = ws + OSI;
    u16*   h1    = (u16*)(ws + OA);
    u16*   h2    = (u16*)(ws + OB);
    u16*   h3    = (u16*)(ws + OC);
    float* featf = ws + OB;            // reuse after h2 dead
    float* offsb = ws + OOFFS;
    float* maskb = ws + OMSK;

    prep_k<<<2888, 256, 0, stream>>>(weight, sp_w1, sp_s1, sp_w2, sp_s2, sp_w3, sp_s3,
                                     off_w, dc_off_w, dc_w,
                                     sp_b1, sp_o1, sp_b2, sp_o2, sp_b3, sp_o3,
                                     off_b, dc_off_b, ws);
    transpose_x_k<<<2048, 256, 0, stream>>>(x, xTb);
    resize_k<<<384, 256, 0, stream>>>(S, Si);
    conv_in_k<<<512, 256, 0, stream>>>(Si, ws + OWSP1, ws + OBSP1, h1);
    conv_mfma_k<0, true><<<256, 256, 0, stream>>>(h1, (const u16*)(ws + OWSP2),
                                                  ws + OBSP2, h2, nullptr);
    conv_mfma_k<0, true><<<256, 256, 0, stream>>>(h2, (const u16*)(ws + OWSP3),
                                                  ws + OBSP3, h3, nullptr);
    conv_mfma_k<1, false><<<256, 256, 0, stream>>>(h3, (const u16*)(ws + OWOFF),
                                                   ws + OBOFF, nullptr, offsb);
    dconv_small_mfma<<<256, 512, 0, stream>>>(h3, offsb, (const u16*)(ws + OWDC), featf);
    mask_k<<<128, 256, 0, stream>>>(featf, m_w, m_b, maskb);
    dconv_big_mfma<<<256, 512, 0, stream>>>(xTb, offsb, maskb,
                                            (const u16*)(ws + OWT), bias, out);
}

// Round 5
// 193.413 us; speedup vs baseline: 5.0791x; 1.1599x over previous
//
#include <hip/hip_runtime.h>
#include <hip/hip_bf16.h>

typedef unsigned short u16;
typedef unsigned int u32;
typedef __attribute__((ext_vector_type(8))) short short8;
typedef __attribute__((ext_vector_type(4))) unsigned short ush4;
typedef __attribute__((ext_vector_type(16))) float f32x16;

// ---------------------------------------------------------------------------
// ws layout (float units):
//   OXT   xT bf16 [8][64][64][256]
//   OSI   Si f32  [8][64][64][3]
//   OA    h1 bf16 [32768][64]
//   OB    (free)
//   OC    h3 bf16 [32768][64]   (h2 also lives in OB region transiently)
//   OOFFS offs f32 [32768][36]
//   OMSK  mask f32 [32768][9]
//   OWT   wKg bf16 [288][256][8]
//   OWSP1 f32 [9][3][64];  OWSP2/OWSP3/OWOFF/OWDC bf16 [9][8][64][8]
// ---------------------------------------------------------------------------
#define OXT   0
#define OSI   (OXT + 8388608)
#define OA    (OSI + 98304)
#define OB    (OA + 2097152)
#define OC    (OB + 2097152)
#define OOFFS (OC + 2097152)
#define OMSK  (OOFFS + 1179648)
#define OWT   (OMSK + 294912)
#define OWSP1 (OWT + 589824)
#define OBSP1 (OWSP1 + 1728)
#define OWSP2 (OBSP1 + 64)
#define OBSP2 (OWSP2 + 36864)
#define OWSP3 (OBSP2 + 64)
#define OBSP3 (OWSP3 + 36864)
#define OWOFF (OBSP3 + 64)
#define OBOFF (OWOFF + 36864)
#define OWDC  (OBOFF + 64)

__device__ __forceinline__ u16 f2bf(float f) {
    __hip_bfloat16 hb = __float2bfloat16(f);
    return __builtin_bit_cast(u16, hb);
}
__device__ __forceinline__ float bf2f(u16 v) {
    return __builtin_bit_cast(float, (u32)v << 16);
}

// ---------------------------------------------------------------------------
__global__ __launch_bounds__(256) void prep_k(
    const float* __restrict__ weight,
    const float* __restrict__ sp_w1, const float* __restrict__ sp_s1,
    const float* __restrict__ sp_w2, const float* __restrict__ sp_s2,
    const float* __restrict__ sp_w3, const float* __restrict__ sp_s3,
    const float* __restrict__ off_w, const float* __restrict__ dc_off_w,
    const float* __restrict__ dc_w,
    const float* __restrict__ sp_b1, const float* __restrict__ sp_o1,
    const float* __restrict__ sp_b2, const float* __restrict__ sp_o2,
    const float* __restrict__ sp_b3, const float* __restrict__ sp_o3,
    const float* __restrict__ off_b, const float* __restrict__ dc_off_b,
    float* __restrict__ ws)
{
    int i = blockIdx.x * 256 + threadIdx.x;
    if (i < 589824) {   // wKg bf16 [kg][o][j], K=kg*8+j = k*256+c
        int j = i & 7; int o = (i >> 3) & 255; int kg = i >> 11;
        int K = kg * 8 + j; int k = K >> 8; int c = K & 255;
        ((u16*)(ws + OWT))[i] = f2bf(weight[o * 2304 + c * 9 + k]);
        return;
    }
    i -= 589824;
    if (i < 1728) {     // wsp1 f32 [9][3][64]
        int o = i & 63; int kc = i >> 6; int c = kc % 3; int k = kc / 3;
        ws[OWSP1 + i] = sp_w1[(o * 3 + c) * 9 + k] * sp_s1[o];
        return;
    }
    i -= 1728;
    if (i < 36864) {    // wm2 bf16 [t][kg][o][e]
        int e = i & 7; int o = (i >> 3) & 63; int kg = (i >> 9) & 7; int tp = i >> 12;
        ((u16*)(ws + OWSP2))[i] = f2bf(sp_w2[(o * 64 + kg * 8 + e) * 9 + tp] * sp_s2[o]);
        return;
    }
    i -= 36864;
    if (i < 36864) {
        int e = i & 7; int o = (i >> 3) & 63; int kg = (i >> 9) & 7; int tp = i >> 12;
        ((u16*)(ws + OWSP3))[i] = f2bf(sp_w3[(o * 64 + kg * 8 + e) * 9 + tp] * sp_s3[o]);
        return;
    }
    i -= 36864;
    if (i < 36864) {    // woff bf16, o<18 off_w, 18..35 dc_off_w, else 0
        int e = i & 7; int o = (i >> 3) & 63; int kg = (i >> 9) & 7; int tp = i >> 12;
        int c = kg * 8 + e;
        float v = 0.f;
        if (o < 18) v = off_w[(o * 64 + c) * 9 + tp];
        else if (o < 36) v = dc_off_w[((o - 18) * 64 + c) * 9 + tp];
        ((u16*)(ws + OWOFF))[i] = f2bf(v);
        return;
    }
    i -= 36864;
    if (i < 36864) {    // wdc bf16 [t][kg][o][e]
        int e = i & 7; int o = (i >> 3) & 63; int kg = (i >> 9) & 7; int tp = i >> 12;
        ((u16*)(ws + OWDC))[i] = f2bf(dc_w[(o * 64 + kg * 8 + e) * 9 + tp]);
        return;
    }
    i -= 36864;
    if (i < 64) { ws[OBSP1 + i] = sp_b1[i] * sp_s1[i] + sp_o1[i]; return; }
    i -= 64;
    if (i < 64) { ws[OBSP2 + i] = sp_b2[i] * sp_s2[i] + sp_o2[i]; return; }
    i -= 64;
    if (i < 64) { ws[OBSP3 + i] = sp_b3[i] * sp_s3[i] + sp_o3[i]; return; }
    i -= 64;
    if (i < 64) { ws[OBOFF + i] = (i < 18) ? off_b[i] : (i < 36 ? dc_off_b[i - 18] : 0.f); return; }
}

// x NCHW f32 -> xT NHWC bf16
__global__ __launch_bounds__(256) void transpose_x_k(const float* __restrict__ x,
                                                     u16* __restrict__ xT)
{
    __shared__ float tile[64][65];
    int blk = blockIdx.x;
    int chunk = blk & 3; int by = blk >> 2;
    int b = by >> 6; int y = by & 63;
    int c0 = chunk * 64;
    int t = threadIdx.x;
    for (int i = t; i < 4096; i += 256) {
        int ci = i >> 6, xi = i & 63;
        tile[ci][xi] = x[((b * 256 + c0 + ci) * 64 + y) * 64 + xi];
    }
    __syncthreads();
    for (int i = t; i < 4096; i += 256) {
        int xi = i >> 6, ci = i & 63;
        xT[((b * 64 + y) * 64 + xi) * 256 + c0 + ci] = f2bf(tile[ci][xi]);
    }
}

__global__ __launch_bounds__(256) void resize_k(const float* __restrict__ S,
                                                float* __restrict__ Si)
{
    int i = blockIdx.x * 256 + threadIdx.x;
    if (i >= 8 * 64 * 64 * 3) return;
    int c = i % 3; int x = (i / 3) & 63; int y = (i / 192) & 63; int b = i / 12288;
    const float sc = 127.0f / 63.0f;
    float sy = y * sc, sx = x * sc;
    float fy = floorf(sy), fx = floorf(sx);
    int y0 = (int)fy, x0 = (int)fx;
    int y1 = min(y0 + 1, 127), x1 = min(x0 + 1, 127);
    float wy = sy - fy, wx = sx - fx;
    const float* Sb = S + (size_t)(b * 3 + c) * 16384;
    float v00 = Sb[y0 * 128 + x0], v01 = Sb[y0 * 128 + x1];
    float v10 = Sb[y1 * 128 + x0], v11 = Sb[y1 * 128 + x1];
    Si[i] = (v00 * (1.f - wy) + v10 * wy) * (1.f - wx)
          + (v01 * (1.f - wy) + v11 * wy) * wx;
}

// conv1: 3->64, fp32 VALU, bf16 NHWC output. One block per (b,y) row.
__global__ __launch_bounds__(256) void conv_in_k(const float* __restrict__ in,
                                                 const float* __restrict__ wt,
                                                 const float* __restrict__ bias,
                                                 u16* __restrict__ out)
{
    __shared__ float rows[3][66][3];
    int by = blockIdx.x; int b = by >> 6; int y = by & 63;
    int t = threadIdx.x;
    for (int i = t; i < 3 * 66 * 3; i += 256) {
        int r = i / 198; int rem = i - r * 198;
        int xi = rem / 3; int c = rem - xi * 3;
        int yy = y - 1 + r, xx = xi - 1;
        float v = 0.f;
        if (yy >= 0 && yy < 64 && xx >= 0 && xx < 64)
            v = in[(((b * 64 + yy) * 64 + xx) * 3) + c];
        rows[r][xi][c] = v;
    }
    __syncthreads();
    int o4 = (t & 15) * 4; int xg = t >> 4;
    float acc[4][4];
    #pragma unroll
    for (int oi = 0; oi < 4; oi++) {
        float bv = bias[o4 + oi];
        #pragma unroll
        for (int xi = 0; xi < 4; xi++) acc[oi][xi] = bv;
    }
    for (int k = 0; k < 9; k++) {
        int dy = k / 3, dx = k - 3 * (k / 3);
        for (int c = 0; c < 3; c++) {
            float4 w = *reinterpret_cast<const float4*>(&wt[(k * 3 + c) * 64 + o4]);
            #pragma unroll
            for (int xi = 0; xi < 4; xi++) {
                float iv = rows[dy][xg * 4 + xi + dx][c];
                acc[0][xi] = fmaf(w.x, iv, acc[0][xi]);
                acc[1][xi] = fmaf(w.y, iv, acc[1][xi]);
                acc[2][xi] = fmaf(w.z, iv, acc[2][xi]);
                acc[3][xi] = fmaf(w.w, iv, acc[3][xi]);
            }
        }
    }
    #pragma unroll
    for (int xi = 0; xi < 4; xi++) {
        int x = xg * 4 + xi;
        ush4 v;
        v.x = f2bf(fmaxf(acc[0][xi], 0.f));
        v.y = f2bf(fmaxf(acc[1][xi], 0.f));
        v.z = f2bf(fmaxf(acc[2][xi], 0.f));
        v.w = f2bf(fmaxf(acc[3][xi], 0.f));
        *reinterpret_cast<ush4*>(&out[((size_t)(by * 64 + x)) * 64 + o4]) = v;
    }
}

// ---------------------------------------------------------------------------
// MFMA 3x3 conv 64->64. Block: 1 output row (64 px), 4 waves = 2(o) x 2(px).
// Grid 512. LDS: 3 halo rows (25.3 KB) + wtap dbuf (16 KB) = 41.3 KB.
// MODE 0: bf16 NHWC out (+bias,+ReLU); MODE 1: f32 [px][36] offs out (+bias).
// ---------------------------------------------------------------------------
template <int MODE, bool RELU>
__global__ __launch_bounds__(256) void conv_mfma_k(const u16* __restrict__ in,
                                                   const u16* __restrict__ wm,
                                                   const float* __restrict__ bias,
                                                   u16* __restrict__ outH,
                                                   float* __restrict__ outF)
{
    __shared__ __attribute__((aligned(16))) char lds_h[3 * 66 * 128];   // 25344 B
    __shared__ __attribute__((aligned(16))) u16 wtap[2][8][64][8];      // 16384 B

    int t = threadIdx.x;
    int b = blockIdx.x >> 6; int y = blockIdx.x & 63;
    int pix0 = b * 4096 + y * 64;
    int wid = t >> 6, lane = t & 63;
    int lrow = lane & 31, lhi = lane >> 5;
    int o0 = (wid & 1) << 5;
    int px0 = (wid >> 1) << 5;
    int px = px0 + lrow;

    // stage 3 input rows (y-1..y+1), 66 cols, swizzled
    for (int i = t; i < 3 * 66 * 8; i += 256) {
        int r = i / 528; int rem = i - r * 528;
        int xi = rem >> 3; int g = rem & 7;
        int yy = y - 1 + r, xx = xi - 1;
        short8 v = {0,0,0,0,0,0,0,0};
        if (yy >= 0 && yy < 64 && xx >= 0 && xx < 64)
            v = *reinterpret_cast<const short8*>(&in[(size_t)((b * 4096 + yy * 64 + xx)) * 64 + g * 8]);
        int byte = (r * 66 + xi) * 128 + ((g * 16) ^ ((xi & 7) << 4));
        *reinterpret_cast<short8*>(lds_h + byte) = v;
    }
    // stage tap 0 weights
    {
        const char* gb = (const char*)(wm);
        char* lb = (char*)&wtap[0][0][0][0];
        #pragma unroll
        for (int i = 0; i < 2; i++) {
            int off = i * 4096 + wid * 1024;
            __builtin_amdgcn_global_load_lds(
                (const __attribute__((address_space(1))) void*)(gb + off + lane * 16),
                (__attribute__((address_space(3))) void*)(lb + off), 16, 0, 0);
        }
    }
    __syncthreads();

    f32x16 acc;
    #pragma unroll
    for (int r = 0; r < 16; r++) acc[r] = 0.f;

    #pragma unroll
    for (int tap = 0; tap < 9; tap++) {
        int cur = tap & 1, nxt = cur ^ 1;
        if (tap < 8) {
            const char* gb = (const char*)(wm + (size_t)(tap + 1) * 4096);
            char* lb = (char*)&wtap[nxt][0][0][0];
            #pragma unroll
            for (int i = 0; i < 2; i++) {
                int off = i * 4096 + wid * 1024;
                __builtin_amdgcn_global_load_lds(
                    (const __attribute__((address_space(1))) void*)(gb + off + lane * 16),
                    (__attribute__((address_space(3))) void*)(lb + off), 16, 0, 0);
            }
        }
        int dy = tap / 3, dx = tap - 3 * (tap / 3);
        int xi = px + dx;
        int rowbyte = (dy * 66 + xi) * 128;
        int swz = (xi & 7) << 4;
        #pragma unroll
        for (int ks = 0; ks < 4; ks++) {
            int kg = ks * 2 + lhi;
            short8 a0 = *reinterpret_cast<const short8*>(&wtap[cur][kg][o0 + lrow][0]);
            short8 b0 = *reinterpret_cast<const short8*>(lds_h + rowbyte + ((kg * 16) ^ swz));
            acc = __builtin_amdgcn_mfma_f32_32x32x16_bf16(a0, b0, acc, 0, 0, 0);
        }
        if (tap < 8) asm volatile("s_waitcnt vmcnt(0)" ::: "memory");
        __builtin_amdgcn_s_barrier();
    }
    __syncthreads();

    if (MODE == 0) {
        // transpose via LDS: [64 px][64 o] bf16, swizzled
        #pragma unroll
        for (int q = 0; q < 4; q++) {
            int ob = o0 + q * 8 + 4 * lhi;
            #pragma unroll
            for (int h = 0; h < 2; h++) {
                float v0 = acc[q * 4 + h * 2] + bias[ob + h * 2];
                float v1 = acc[q * 4 + h * 2 + 1] + bias[ob + h * 2 + 1];
                if (RELU) { v0 = fmaxf(v0, 0.f); v1 = fmaxf(v1, 0.f); }
                u32 pk = (u32)f2bf(v0) | ((u32)f2bf(v1) << 16);
                int byte = px * 128 + (((ob + h * 2) * 2) ^ ((px & 7) << 4));
                *reinterpret_cast<u32*>(lds_h + byte) = pk;
            }
        }
        __syncthreads();
        #pragma unroll
        for (int i = 0; i < 2; i++) {
            int cid = i * 256 + t;      // 512 chunks of 16B
            int p = cid >> 3, g = cid & 7;
            short8 v = *reinterpret_cast<const short8*>(lds_h + p * 128 + ((g * 16) ^ ((p & 7) << 4)));
            *reinterpret_cast<short8*>(&outH[(size_t)(pix0 + p) * 64 + g * 8]) = v;
        }
    } else {
        float* ltf = (float*)lds_h;     // [64][40]
        #pragma unroll
        for (int r = 0; r < 16; r++) {
            int o = o0 + (r & 3) + ((r >> 2) << 3) + (lhi << 2);
            if (o < 36) ltf[px * 40 + o] = acc[r] + bias[o];
        }
        __syncthreads();
        for (int i = t; i < 576; i += 256) {
            int p = i / 9, q = i - 9 * (i / 9);
            float4 v = *reinterpret_cast<const float4*>(&ltf[p * 40 + q * 4]);
            *reinterpret_cast<float4*>(&outF[(size_t)(pix0 + p) * 36 + q * 4]) = v;
        }
    }
}

// ---------------------------------------------------------------------------
// DCNv1 on h (bf16, 64->64) + fused mask head.
// 256 blocks x 512 thr; 128px x 64o; corners recomputed in regs per tap.
// LDS: wtile dbuf 16KB + stile 16KB (+1KB for feat overlay) = 33.3 KB.
// Epilogue: feat -> LDS -> mask = sigmoid(m_w . feat + m_b) -> maskb.
// ---------------------------------------------------------------------------
__global__ __launch_bounds__(512) void dconv_small_mfma(
    const u16* __restrict__ h, const float* __restrict__ offs,
    const u16* __restrict__ wdc, const float* __restrict__ m_w,
    const float* __restrict__ m_b, float* __restrict__ maskb)
{
    __shared__ __attribute__((aligned(16))) char smem[33280];
    u16 (*wtile)[8][64][8] = (u16 (*)[8][64][8])smem;            // [2][8][64][8] 16KB
    u16 (*stile)[128][8]   = (u16 (*)[128][8])(smem + 16384);    // [8][128][8]  16KB

    int t = threadIdx.x;
    int id = blockIdx.x;
    int blk = (id & 7) * 32 + (id >> 3);      // XCD swizzle
    int pix0 = blk * 128;
    int b = pix0 >> 12;
    int wid = t >> 6, lane = t & 63;
    int lrow = lane & 31, lhi = lane >> 5;
    int o0 = (wid & 1) << 5;
    int px0 = (wid >> 1) << 5;
    int gpx = t & 127, hq = t >> 7;

    {
        const char* gb = (const char*)wdc;
        char* lb = (char*)&wtile[0][0][0][0];
        __builtin_amdgcn_global_load_lds(
            (const __attribute__((address_space(1))) void*)(gb + wid * 1024 + lane * 16),
            (__attribute__((address_space(3))) void*)(lb + wid * 1024), 16, 0, 0);
    }
    __syncthreads();

    f32x16 acc;
    #pragma unroll
    for (int r = 0; r < 16; r++) acc[r] = 0.f;

    int car[4]; float cwr[4];

    for (int tap = 0; tap < 9; ++tap) {
        int cur = tap & 1, nxt = cur ^ 1;
        // recompute corner table for (tap, gpx) in registers
        {
            int pix = pix0 + gpx; int pib = pix & 4095;
            int y = pib >> 6, x = pib & 63;
            float offy = offs[(size_t)pix * 36 + 18 + tap * 2];
            float offx = offs[(size_t)pix * 36 + 18 + tap * 2 + 1];
            float py = (float)(y - 1 + tap / 3) + offy;
            float pxf = (float)(x - 1 + (tap % 3)) + offx;
            float fy = floorf(py), fx = floorf(pxf);
            int y0 = (int)fy, x0 = (int)fx;
            float dyf = py - fy, dxf = pxf - fx;
            #pragma unroll
            for (int j = 0; j < 4; j++) {
                float wj = ((j >> 1) ? dyf : 1.f - dyf) * ((j & 1) ? dxf : 1.f - dxf);
                int yy = y0 + (j >> 1), xx = x0 + (j & 1);
                bool valid = (yy >= 0 && yy < 64 && xx >= 0 && xx < 64);
                int yc = min(max(yy, 0), 63), xc = min(max(xx, 0), 63);
                car[j] = (b * 4096 + yc * 64 + xc) << 6;
                cwr[j] = valid ? wj : 0.f;
            }
        }
        // gather 16 channels of pixel gpx
        int c = hq << 4;
        float va[16];
        #pragma unroll
        for (int e = 0; e < 16; e++) va[e] = 0.f;
        #pragma unroll
        for (int j = 0; j < 4; j++) {
            float w = cwr[j];
            const u16* p = h + car[j] + c;
            short8 r0 = *reinterpret_cast<const short8*>(p);
            short8 r1 = *reinterpret_cast<const short8*>(p + 8);
            #pragma unroll
            for (int e = 0; e < 8; e++) {
                va[e]     = fmaf(w, bf2f((u16)r0[e]), va[e]);
                va[8 + e] = fmaf(w, bf2f((u16)r1[e]), va[8 + e]);
            }
        }
        // prefetch next tap weights (1 load/thread)
        if (tap < 8) {
            const char* gb = (const char*)(wdc + (size_t)(tap + 1) * 4096);
            char* lb = (char*)&wtile[nxt][0][0][0];
            __builtin_amdgcn_global_load_lds(
                (const __attribute__((address_space(1))) void*)(gb + wid * 1024 + lane * 16),
                (__attribute__((address_space(3))) void*)(lb + wid * 1024), 16, 0, 0);
        }
        short8 s0, s1;
        #pragma unroll
        for (int e = 0; e < 8; e++) { s0[e] = (short)f2bf(va[e]); s1[e] = (short)f2bf(va[8 + e]); }
        *reinterpret_cast<short8*>(&stile[hq * 2][gpx][0]) = s0;
        *reinterpret_cast<short8*>(&stile[hq * 2 + 1][gpx][0]) = s1;

        if (tap < 8) asm volatile("s_waitcnt vmcnt(1) lgkmcnt(0)" ::: "memory");
        else         asm volatile("s_waitcnt vmcnt(0) lgkmcnt(0)" ::: "memory");
        __builtin_amdgcn_s_barrier();

        #pragma unroll
        for (int ks = 0; ks < 4; ks++) {
            int kg = ks * 2 + lhi;
            short8 a0 = *reinterpret_cast<const short8*>(&wtile[cur][kg][o0 + lrow][0]);
            short8 b0 = *reinterpret_cast<const short8*>(&stile[kg][px0 + lrow][0]);
            acc = __builtin_amdgcn_mfma_f32_32x32x16_bf16(a0, b0, acc, 0, 0, 0);
        }
        asm volatile("s_waitcnt lgkmcnt(0)" ::: "memory");
        __builtin_amdgcn_s_barrier();
    }

    // epilogue: feat -> LDS [128][65] f32, then fused mask
    __syncthreads();
    float* featl = (float*)smem;
    int pxl = px0 + lrow;
    #pragma unroll
    for (int r = 0; r < 16; r++) {
        int o = o0 + (r & 3) + ((r >> 2) << 3) + (lhi << 2);
        featl[pxl * 65 + o] = acc[r];
    }
    __syncthreads();
    if (t < 256) {
        int p = t >> 1, hh = t & 1;
        int pix = pix0 + p;
        const float* fr = &featl[p * 65];
        int j0 = hh ? 4 : 0, j1 = hh ? 9 : 4;
        for (int j = j0; j < j1; j++) {
            float a = m_b[j];
            #pragma unroll 8
            for (int cc = 0; cc < 64; cc++) a = fmaf(fr[cc], m_w[j * 64 + cc], a);
            maskb[(size_t)pix * 9 + j] = 1.f / (1.f + expf(-a));
        }
    }
}

// ---------------------------------------------------------------------------
// Modulated DCNv2 (256->256), bf16 MFMA, pipelined.
// 256 blocks x 512 thr; 128px x 256o; 8 waves = 4(o) x 2(px).
// LDS = wtile dbuf 64KB + stile 16KB = exactly 80KB -> 2 blocks/CU.
// Corners recomputed in regs once per tap by each gather thread.
// ---------------------------------------------------------------------------
__global__ __launch_bounds__(512) void dconv_big_mfma(
    const u16* __restrict__ xT, const float* __restrict__ offs,
    const float* __restrict__ maskb, const u16* __restrict__ wKg,
    const float* __restrict__ bias, float* __restrict__ out)
{
    __shared__ __attribute__((aligned(16))) u16 wtile[2][8][256][8];  // 64 KB
    __shared__ __attribute__((aligned(16))) u16 stile[8][128][8];     // 16 KB

    int t = threadIdx.x;
    int id = blockIdx.x;
    int blk = (id & 7) * 32 + (id >> 3);      // XCD swizzle
    int pix0 = blk * 128;
    int b = pix0 >> 12, pib0 = pix0 & 4095;
    int wid = t >> 6, lane = t & 63;
    int lrow = lane & 31, lhi = lane >> 5;
    int o0 = (wid & 3) << 6;
    int px0 = (wid >> 2) << 6;
    int gpx = t & 127, hq = t >> 7;

    {
        const char* gb = (const char*)wKg;
        char* lb = (char*)&wtile[0][0][0][0];
        #pragma unroll
        for (int i = 0; i < 4; i++) {
            int off = i * 8192 + wid * 1024;
            __builtin_amdgcn_global_load_lds(
                (const __attribute__((address_space(1))) void*)(gb + off + lane * 16),
                (__attribute__((address_space(3))) void*)(lb + off), 16, 0, 0);
        }
    }
    __syncthreads();

    f32x16 acc[2][2];
    #pragma unroll
    for (int fo = 0; fo < 2; fo++)
        #pragma unroll
        for (int fp = 0; fp < 2; fp++)
            #pragma unroll
            for (int r = 0; r < 16; r++) acc[fo][fp][r] = 0.f;

    int car[4]; float cwr[4];

    for (int kt = 0; kt < 36; ++kt) {
        int cur = kt & 1, nxt = cur ^ 1;
        int tap = kt >> 2, chunk = kt & 3;

        if (chunk == 0) {
            // recompute corner table for (tap, gpx) in registers
            int pix = pix0 + gpx; int pib = pix & 4095;
            int y = pib >> 6, x = pib & 63;
            float offy = offs[(size_t)pix * 36 + tap * 2];
            float offx = offs[(size_t)pix * 36 + tap * 2 + 1];
            float m = maskb[(size_t)pix * 9 + tap];
            float py = (float)(y - 1 + tap / 3) + offy;
            float pxf = (float)(x - 1 + (tap % 3)) + offx;
            float fy = floorf(py), fx = floorf(pxf);
            int y0 = (int)fy, x0 = (int)fx;
            float dyf = py - fy, dxf = pxf - fx;
            #pragma unroll
            for (int j = 0; j < 4; j++) {
                float wj = ((j >> 1) ? dyf : 1.f - dyf) * ((j & 1) ? dxf : 1.f - dxf);
                int yy = y0 + (j >> 1), xx = x0 + (j & 1);
                bool valid = (yy >= 0 && yy < 64 && xx >= 0 && xx < 64);
                int yc = min(max(yy, 0), 63), xc = min(max(xx, 0), 63);
                car[j] = (b * 4096 + yc * 64 + xc) << 8;
                cwr[j] = valid ? wj * m : 0.f;
            }
        }

        // gather 16 channels of pixel gpx
        int c = (chunk << 6) + (hq << 4);
        float va[16];
        #pragma unroll
        for (int e = 0; e < 16; e++) va[e] = 0.f;
        #pragma unroll
        for (int j = 0; j < 4; j++) {
            float w = cwr[j];
            const u16* p = xT + car[j] + c;
            short8 r0 = *reinterpret_cast<const short8*>(p);
            short8 r1 = *reinterpret_cast<const short8*>(p + 8);
            #pragma unroll
            for (int e = 0; e < 8; e++) {
                va[e]     = fmaf(w, bf2f((u16)r0[e]), va[e]);
                va[8 + e] = fmaf(w, bf2f((u16)r1[e]), va[8 + e]);
            }
        }
        // prefetch next K-step weights
        if (kt < 35) {
            const char* gb = (const char*)(wKg + (size_t)(kt + 1) * 16384);
            char* lb = (char*)&wtile[nxt][0][0][0];
            #pragma unroll
            for (int i = 0; i < 4; i++) {
                int off = i * 8192 + wid * 1024;
                __builtin_amdgcn_global_load_lds(
                    (const __attribute__((address_space(1))) void*)(gb + off + lane * 16),
                    (__attribute__((address_space(3))) void*)(lb + off), 16, 0, 0);
            }
        }
        short8 s0, s1;
        #pragma unroll
        for (int e = 0; e < 8; e++) { s0[e] = (short)f2bf(va[e]); s1[e] = (short)f2bf(va[8 + e]); }
        *reinterpret_cast<short8*>(&stile[hq * 2][gpx][0]) = s0;
        *reinterpret_cast<short8*>(&stile[hq * 2 + 1][gpx][0]) = s1;

        if (kt < 35) asm volatile("s_waitcnt vmcnt(4) lgkmcnt(0)" ::: "memory");
        else         asm volatile("s_waitcnt vmcnt(0) lgkmcnt(0)" ::: "memory");
        __builtin_amdgcn_s_barrier();

        #pragma unroll
        for (int ks = 0; ks < 4; ks++) {
            int kg = ks * 2 + lhi;
            short8 a0 = *reinterpret_cast<const short8*>(&wtile[cur][kg][o0 + lrow][0]);
            short8 a1 = *reinterpret_cast<const short8*>(&wtile[cur][kg][o0 + 32 + lrow][0]);
            short8 b0 = *reinterpret_cast<const short8*>(&stile[kg][px0 + lrow][0]);
            short8 b1 = *reinterpret_cast<const short8*>(&stile[kg][px0 + 32 + lrow][0]);
            acc[0][0] = __builtin_amdgcn_mfma_f32_32x32x16_bf16(a0, b0, acc[0][0], 0, 0, 0);
            acc[0][1] = __builtin_amdgcn_mfma_f32_32x32x16_bf16(a0, b1, acc[0][1], 0, 0, 0);
            acc[1][0] = __builtin_amdgcn_mfma_f32_32x32x16_bf16(a1, b0, acc[1][0], 0, 0, 0);
            acc[1][1] = __builtin_amdgcn_mfma_f32_32x32x16_bf16(a1, b1, acc[1][1], 0, 0, 0);
        }
        asm volatile("s_waitcnt lgkmcnt(0)" ::: "memory");
        __builtin_amdgcn_s_barrier();
    }

    #pragma unroll
    for (int fo = 0; fo < 2; fo++) {
        #pragma unroll
        for (int r = 0; r < 16; r++) {
            int o = o0 + fo * 32 + (r & 3) + ((r >> 2) << 3) + (lhi << 2);
            float bv = bias[o];
            size_t rowoff = ((size_t)(b * 256 + o) << 12) + pib0;
            out[rowoff + px0 + lrow] = acc[fo][0][r] + bv;
            out[rowoff + px0 + 32 + lrow] = acc[fo][1][r] + bv;
        }
    }
}

extern "C" void kernel_launch(void* const* d_in, const int* in_sizes, int n_in,
                              void* d_out, int out_size, void* d_ws, size_t ws_size,
                              hipStream_t stream)
{
    const float* x        = (const float*)d_in[0];
    const float* S        = (const float*)d_in[1];
    const float* sp_w1    = (const float*)d_in[2];
    const float* sp_b1    = (const float*)d_in[3];
    const float* sp_s1    = (const float*)d_in[4];
    const float* sp_o1    = (const float*)d_in[5];
    const float* sp_w2    = (const float*)d_in[6];
    const float* sp_b2    = (const float*)d_in[7];
    const float* sp_s2    = (const float*)d_in[8];
    const float* sp_o2    = (const float*)d_in[9];
    const float* sp_w3    = (const float*)d_in[10];
    const float* sp_b3    = (const float*)d_in[11];
    const float* sp_s3    = (const float*)d_in[12];
    const float* sp_o3    = (const float*)d_in[13];
    const float* off_w    = (const float*)d_in[14];
    const float* off_b    = (const float*)d_in[15];
    const float* dc_off_w = (const float*)d_in[16];
    const float* dc_off_b = (const float*)d_in[17];
    const float* dc_w     = (const float*)d_in[18];
    const float* m_w      = (const float*)d_in[19];
    const float* m_b      = (const float*)d_in[20];
    const float* weight   = (const float*)d_in[21];
    const float* bias     = (const float*)d_in[22];
    float* out = (float*)d_out;
    float* ws  = (float*)d_ws;

    u16*   xTb   = (u16*)(ws + OXT);
    float* Si    = ws + OSI;
    u16*   h1    = (u16*)(ws + OA);
    u16*   h2    = (u16*)(ws + OB);
    u16*   h3    = (u16*)(ws + OC);
    float* offsb = ws + OOFFS;
    float* maskb = ws + OMSK;

    prep_k<<<2888, 256, 0, stream>>>(weight, sp_w1, sp_s1, sp_w2, sp_s2, sp_w3, sp_s3,
                                     off_w, dc_off_w, dc_w,
                                     sp_b1, sp_o1, sp_b2, sp_o2, sp_b3, sp_o3,
                                     off_b, dc_off_b, ws);
    transpose_x_k<<<2048, 256, 0, stream>>>(x, xTb);
    resize_k<<<384, 256, 0, stream>>>(S, Si);
    conv_in_k<<<512, 256, 0, stream>>>(Si, ws + OWSP1, ws + OBSP1, h1);
    conv_mfma_k<0, true><<<512, 256, 0, stream>>>(h1, (const u16*)(ws + OWSP2),
                                                  ws + OBSP2, h2, nullptr);
    conv_mfma_k<0, true><<<512, 256, 0, stream>>>(h2, (const u16*)(ws + OWSP3),
                                                  ws + OBSP3, h3, nullptr);
    conv_mfma_k<1, false><<<512, 256, 0, stream>>>(h3, (const u16*)(ws + OWOFF),
                                                   ws + OBOFF, nullptr, offsb);
    dconv_small_mfma<<<256, 512, 0, stream>>>(h3, offsb, (const u16*)(ws + OWDC),
                                              m_w, m_b, maskb);
    dconv_big_mfma<<<256, 512, 0, stream>>>(xTb, offsb, maskb,
                                            (const u16*)(ws + OWT), bias, out);
}

// Round 6
// 149.650 us; speedup vs baseline: 6.5644x; 1.2924x over previous
//
#include <hip/hip_runtime.h>
#include <hip/hip_bf16.h>

typedef unsigned short u16;
typedef unsigned int u32;
typedef __attribute__((ext_vector_type(8))) short short8;
typedef __attribute__((ext_vector_type(4))) unsigned short ush4;
typedef __attribute__((ext_vector_type(16))) float f32x16;

// ---------------------------------------------------------------------------
// ws layout (float units): see prior rounds.
// ---------------------------------------------------------------------------
#define OXT   0
#define OSI   (OXT + 8388608)
#define OA    (OSI + 98304)
#define OB    (OA + 2097152)
#define OC    (OB + 2097152)
#define OOFFS (OC + 2097152)
#define OMSK  (OOFFS + 1179648)
#define OWT   (OMSK + 294912)
#define OWSP1 (OWT + 589824)
#define OBSP1 (OWSP1 + 1728)
#define OWSP2 (OBSP1 + 64)
#define OBSP2 (OWSP2 + 36864)
#define OWSP3 (OBSP2 + 64)
#define OBSP3 (OWSP3 + 36864)
#define OWOFF (OBSP3 + 64)
#define OBOFF (OWOFF + 36864)
#define OWDC  (OBOFF + 64)

__device__ __forceinline__ u16 f2bf(float f) {
    __hip_bfloat16 hb = __float2bfloat16(f);
    return __builtin_bit_cast(u16, hb);
}
__device__ __forceinline__ float bf2f(u16 v) {
    return __builtin_bit_cast(float, (u32)v << 16);
}

// ---------------------------------------------------------------------------
__global__ __launch_bounds__(256) void prep_k(
    const float* __restrict__ weight,
    const float* __restrict__ sp_w1, const float* __restrict__ sp_s1,
    const float* __restrict__ sp_w2, const float* __restrict__ sp_s2,
    const float* __restrict__ sp_w3, const float* __restrict__ sp_s3,
    const float* __restrict__ off_w, const float* __restrict__ dc_off_w,
    const float* __restrict__ dc_w,
    const float* __restrict__ sp_b1, const float* __restrict__ sp_o1,
    const float* __restrict__ sp_b2, const float* __restrict__ sp_o2,
    const float* __restrict__ sp_b3, const float* __restrict__ sp_o3,
    const float* __restrict__ off_b, const float* __restrict__ dc_off_b,
    float* __restrict__ ws)
{
    int i = blockIdx.x * 256 + threadIdx.x;
    if (i < 589824) {   // wKg bf16 [kg][o][j], K=kg*8+j = k*256+c
        int j = i & 7; int o = (i >> 3) & 255; int kg = i >> 11;
        int K = kg * 8 + j; int k = K >> 8; int c = K & 255;
        ((u16*)(ws + OWT))[i] = f2bf(weight[o * 2304 + c * 9 + k]);
        return;
    }
    i -= 589824;
    if (i < 1728) {     // wsp1 f32 [9][3][64]
        int o = i & 63; int kc = i >> 6; int c = kc % 3; int k = kc / 3;
        ws[OWSP1 + i] = sp_w1[(o * 3 + c) * 9 + k] * sp_s1[o];
        return;
    }
    i -= 1728;
    if (i < 36864) {    // wm2 bf16 [t][kg][o][e]
        int e = i & 7; int o = (i >> 3) & 63; int kg = (i >> 9) & 7; int tp = i >> 12;
        ((u16*)(ws + OWSP2))[i] = f2bf(sp_w2[(o * 64 + kg * 8 + e) * 9 + tp] * sp_s2[o]);
        return;
    }
    i -= 36864;
    if (i < 36864) {
        int e = i & 7; int o = (i >> 3) & 63; int kg = (i >> 9) & 7; int tp = i >> 12;
        ((u16*)(ws + OWSP3))[i] = f2bf(sp_w3[(o * 64 + kg * 8 + e) * 9 + tp] * sp_s3[o]);
        return;
    }
    i -= 36864;
    if (i < 36864) {    // woff bf16
        int e = i & 7; int o = (i >> 3) & 63; int kg = (i >> 9) & 7; int tp = i >> 12;
        int c = kg * 8 + e;
        float v = 0.f;
        if (o < 18) v = off_w[(o * 64 + c) * 9 + tp];
        else if (o < 36) v = dc_off_w[((o - 18) * 64 + c) * 9 + tp];
        ((u16*)(ws + OWOFF))[i] = f2bf(v);
        return;
    }
    i -= 36864;
    if (i < 36864) {    // wdc bf16 [t][kg][o][e]
        int e = i & 7; int o = (i >> 3) & 63; int kg = (i >> 9) & 7; int tp = i >> 12;
        ((u16*)(ws + OWDC))[i] = f2bf(dc_w[(o * 64 + kg * 8 + e) * 9 + tp]);
        return;
    }
    i -= 36864;
    if (i < 64) { ws[OBSP1 + i] = sp_b1[i] * sp_s1[i] + sp_o1[i]; return; }
    i -= 64;
    if (i < 64) { ws[OBSP2 + i] = sp_b2[i] * sp_s2[i] + sp_o2[i]; return; }
    i -= 64;
    if (i < 64) { ws[OBSP3 + i] = sp_b3[i] * sp_s3[i] + sp_o3[i]; return; }
    i -= 64;
    if (i < 64) { ws[OBOFF + i] = (i < 18) ? off_b[i] : (i < 36 ? dc_off_b[i - 18] : 0.f); return; }
}

// x NCHW f32 -> xT NHWC bf16
__global__ __launch_bounds__(256) void transpose_x_k(const float* __restrict__ x,
                                                     u16* __restrict__ xT)
{
    __shared__ float tile[64][65];
    int blk = blockIdx.x;
    int chunk = blk & 3; int by = blk >> 2;
    int b = by >> 6; int y = by & 63;
    int c0 = chunk * 64;
    int t = threadIdx.x;
    for (int i = t; i < 4096; i += 256) {
        int ci = i >> 6, xi = i & 63;
        tile[ci][xi] = x[((b * 256 + c0 + ci) * 64 + y) * 64 + xi];
    }
    __syncthreads();
    for (int i = t; i < 4096; i += 256) {
        int xi = i >> 6, ci = i & 63;
        xT[((b * 64 + y) * 64 + xi) * 256 + c0 + ci] = f2bf(tile[ci][xi]);
    }
}

__global__ __launch_bounds__(256) void resize_k(const float* __restrict__ S,
                                                float* __restrict__ Si)
{
    int i = blockIdx.x * 256 + threadIdx.x;
    if (i >= 8 * 64 * 64 * 3) return;
    int c = i % 3; int x = (i / 3) & 63; int y = (i / 192) & 63; int b = i / 12288;
    const float sc = 127.0f / 63.0f;
    float sy = y * sc, sx = x * sc;
    float fy = floorf(sy), fx = floorf(sx);
    int y0 = (int)fy, x0 = (int)fx;
    int y1 = min(y0 + 1, 127), x1 = min(x0 + 1, 127);
    float wy = sy - fy, wx = sx - fx;
    const float* Sb = S + (size_t)(b * 3 + c) * 16384;
    float v00 = Sb[y0 * 128 + x0], v01 = Sb[y0 * 128 + x1];
    float v10 = Sb[y1 * 128 + x0], v11 = Sb[y1 * 128 + x1];
    Si[i] = (v00 * (1.f - wy) + v10 * wy) * (1.f - wx)
          + (v01 * (1.f - wy) + v11 * wy) * wx;
}

// conv1: 3->64, fp32 VALU, bf16 NHWC output. One block per (b,y) row.
__global__ __launch_bounds__(256) void conv_in_k(const float* __restrict__ in,
                                                 const float* __restrict__ wt,
                                                 const float* __restrict__ bias,
                                                 u16* __restrict__ out)
{
    __shared__ float rows[3][66][3];
    int by = blockIdx.x; int b = by >> 6; int y = by & 63;
    int t = threadIdx.x;
    for (int i = t; i < 3 * 66 * 3; i += 256) {
        int r = i / 198; int rem = i - r * 198;
        int xi = rem / 3; int c = rem - xi * 3;
        int yy = y - 1 + r, xx = xi - 1;
        float v = 0.f;
        if (yy >= 0 && yy < 64 && xx >= 0 && xx < 64)
            v = in[(((b * 64 + yy) * 64 + xx) * 3) + c];
        rows[r][xi][c] = v;
    }
    __syncthreads();
    int o4 = (t & 15) * 4; int xg = t >> 4;
    float acc[4][4];
    #pragma unroll
    for (int oi = 0; oi < 4; oi++) {
        float bv = bias[o4 + oi];
        #pragma unroll
        for (int xi = 0; xi < 4; xi++) acc[oi][xi] = bv;
    }
    for (int k = 0; k < 9; k++) {
        int dy = k / 3, dx = k - 3 * (k / 3);
        for (int c = 0; c < 3; c++) {
            float4 w = *reinterpret_cast<const float4*>(&wt[(k * 3 + c) * 64 + o4]);
            #pragma unroll
            for (int xi = 0; xi < 4; xi++) {
                float iv = rows[dy][xg * 4 + xi + dx][c];
                acc[0][xi] = fmaf(w.x, iv, acc[0][xi]);
                acc[1][xi] = fmaf(w.y, iv, acc[1][xi]);
                acc[2][xi] = fmaf(w.z, iv, acc[2][xi]);
                acc[3][xi] = fmaf(w.w, iv, acc[3][xi]);
            }
        }
    }
    #pragma unroll
    for (int xi = 0; xi < 4; xi++) {
        int x = xg * 4 + xi;
        ush4 v;
        v.x = f2bf(fmaxf(acc[0][xi], 0.f));
        v.y = f2bf(fmaxf(acc[1][xi], 0.f));
        v.z = f2bf(fmaxf(acc[2][xi], 0.f));
        v.w = f2bf(fmaxf(acc[3][xi], 0.f));
        *reinterpret_cast<ush4*>(&out[((size_t)(by * 64 + x)) * 64 + o4]) = v;
    }
}

// ---------------------------------------------------------------------------
// MFMA 3x3 conv 64->64. Block: 1 output row (64 px), 4 waves = 2(o) x 2(px).
// ---------------------------------------------------------------------------
template <int MODE, bool RELU>
__global__ __launch_bounds__(256) void conv_mfma_k(const u16* __restrict__ in,
                                                   const u16* __restrict__ wm,
                                                   const float* __restrict__ bias,
                                                   u16* __restrict__ outH,
                                                   float* __restrict__ outF)
{
    __shared__ __attribute__((aligned(16))) char lds_h[3 * 66 * 128];   // 25344 B
    __shared__ __attribute__((aligned(16))) u16 wtap[2][8][64][8];      // 16384 B

    int t = threadIdx.x;
    int b = blockIdx.x >> 6; int y = blockIdx.x & 63;
    int pix0 = b * 4096 + y * 64;
    int wid = t >> 6, lane = t & 63;
    int lrow = lane & 31, lhi = lane >> 5;
    int o0 = (wid & 1) << 5;
    int px0 = (wid >> 1) << 5;
    int px = px0 + lrow;

    for (int i = t; i < 3 * 66 * 8; i += 256) {
        int r = i / 528; int rem = i - r * 528;
        int xi = rem >> 3; int g = rem & 7;
        int yy = y - 1 + r, xx = xi - 1;
        short8 v = {0,0,0,0,0,0,0,0};
        if (yy >= 0 && yy < 64 && xx >= 0 && xx < 64)
            v = *reinterpret_cast<const short8*>(&in[(size_t)((b * 4096 + yy * 64 + xx)) * 64 + g * 8]);
        int byte = (r * 66 + xi) * 128 + ((g * 16) ^ ((xi & 7) << 4));
        *reinterpret_cast<short8*>(lds_h + byte) = v;
    }
    {
        const char* gb = (const char*)(wm);
        char* lb = (char*)&wtap[0][0][0][0];
        #pragma unroll
        for (int i = 0; i < 2; i++) {
            int off = i * 4096 + wid * 1024;
            __builtin_amdgcn_global_load_lds(
                (const __attribute__((address_space(1))) void*)(gb + off + lane * 16),
                (__attribute__((address_space(3))) void*)(lb + off), 16, 0, 0);
        }
    }
    __syncthreads();

    f32x16 acc;
    #pragma unroll
    for (int r = 0; r < 16; r++) acc[r] = 0.f;

    #pragma unroll
    for (int tap = 0; tap < 9; tap++) {
        int cur = tap & 1, nxt = cur ^ 1;
        if (tap < 8) {
            const char* gb = (const char*)(wm + (size_t)(tap + 1) * 4096);
            char* lb = (char*)&wtap[nxt][0][0][0];
            #pragma unroll
            for (int i = 0; i < 2; i++) {
                int off = i * 4096 + wid * 1024;
                __builtin_amdgcn_global_load_lds(
                    (const __attribute__((address_space(1))) void*)(gb + off + lane * 16),
                    (__attribute__((address_space(3))) void*)(lb + off), 16, 0, 0);
            }
        }
        int dy = tap / 3, dx = tap - 3 * (tap / 3);
        int xi = px + dx;
        int rowbyte = (dy * 66 + xi) * 128;
        int swz = (xi & 7) << 4;
        #pragma unroll
        for (int ks = 0; ks < 4; ks++) {
            int kg = ks * 2 + lhi;
            short8 a0 = *reinterpret_cast<const short8*>(&wtap[cur][kg][o0 + lrow][0]);
            short8 b0 = *reinterpret_cast<const short8*>(lds_h + rowbyte + ((kg * 16) ^ swz));
            acc = __builtin_amdgcn_mfma_f32_32x32x16_bf16(a0, b0, acc, 0, 0, 0);
        }
        if (tap < 8) asm volatile("s_waitcnt vmcnt(0)" ::: "memory");
        __builtin_amdgcn_s_barrier();
    }
    __syncthreads();

    if (MODE == 0) {
        #pragma unroll
        for (int q = 0; q < 4; q++) {
            int ob = o0 + q * 8 + 4 * lhi;
            #pragma unroll
            for (int h = 0; h < 2; h++) {
                float v0 = acc[q * 4 + h * 2] + bias[ob + h * 2];
                float v1 = acc[q * 4 + h * 2 + 1] + bias[ob + h * 2 + 1];
                if (RELU) { v0 = fmaxf(v0, 0.f); v1 = fmaxf(v1, 0.f); }
                u32 pk = (u32)f2bf(v0) | ((u32)f2bf(v1) << 16);
                int byte = px * 128 + (((ob + h * 2) * 2) ^ ((px & 7) << 4));
                *reinterpret_cast<u32*>(lds_h + byte) = pk;
            }
        }
        __syncthreads();
        #pragma unroll
        for (int i = 0; i < 2; i++) {
            int cid = i * 256 + t;
            int p = cid >> 3, g = cid & 7;
            short8 v = *reinterpret_cast<const short8*>(lds_h + p * 128 + ((g * 16) ^ ((p & 7) << 4)));
            *reinterpret_cast<short8*>(&outH[(size_t)(pix0 + p) * 64 + g * 8]) = v;
        }
    } else {
        float* ltf = (float*)lds_h;
        #pragma unroll
        for (int r = 0; r < 16; r++) {
            int o = o0 + (r & 3) + ((r >> 2) << 3) + (lhi << 2);
            if (o < 36) ltf[px * 40 + o] = acc[r] + bias[o];
        }
        __syncthreads();
        for (int i = t; i < 576; i += 256) {
            int p = i / 9, q = i - 9 * (i / 9);
            float4 v = *reinterpret_cast<const float4*>(&ltf[p * 40 + q * 4]);
            *reinterpret_cast<float4*>(&outF[(size_t)(pix0 + p) * 36 + q * 4]) = v;
        }
    }
}

// ---------------------------------------------------------------------------
// DCNv1 on h (bf16, 64->64) + fused mask head.
// 256 blocks x 512 thr; 128px x 64o; channel-major gather (p=t>>2, sub=t&3).
// ---------------------------------------------------------------------------
__global__ __launch_bounds__(512) void dconv_small_mfma(
    const u16* __restrict__ h, const float* __restrict__ offs,
    const u16* __restrict__ wdc, const float* __restrict__ m_w,
    const float* __restrict__ m_b, float* __restrict__ maskb)
{
    __shared__ __attribute__((aligned(16))) char smem[33280];
    u16 (*wtile)[8][64][8] = (u16 (*)[8][64][8])smem;            // [2][8][64][8] 16KB
    u16 (*stile)[128][8]   = (u16 (*)[128][8])(smem + 16384);    // [8][128][8]  16KB

    int t = threadIdx.x;
    int id = blockIdx.x;
    int blk = (id & 7) * 32 + (id >> 3);      // XCD swizzle
    int pix0 = blk * 128;
    int b = pix0 >> 12;
    int wid = t >> 6, lane = t & 63;
    int lrow = lane & 31, lhi = lane >> 5;
    int o0 = (wid & 1) << 5;
    int px0 = (wid >> 1) << 5;
    int gp = t >> 2, gsub = t & 3;            // pixel / 16-ch chunk

    {
        const char* gb = (const char*)wdc;
        char* lb = (char*)&wtile[0][0][0][0];
        __builtin_amdgcn_global_load_lds(
            (const __attribute__((address_space(1))) void*)(gb + wid * 1024 + lane * 16),
            (__attribute__((address_space(3))) void*)(lb + wid * 1024), 16, 0, 0);
    }
    __syncthreads();

    f32x16 acc;
    #pragma unroll
    for (int r = 0; r < 16; r++) acc[r] = 0.f;

    int car[4]; float cwr[4];

    for (int tap = 0; tap < 9; ++tap) {
        int cur = tap & 1, nxt = cur ^ 1;
        // recompute corner table for (tap, gp) in registers
        {
            int pix = pix0 + gp; int pib = pix & 4095;
            int y = pib >> 6, x = pib & 63;
            float offy = offs[(size_t)pix * 36 + 18 + tap * 2];
            float offx = offs[(size_t)pix * 36 + 18 + tap * 2 + 1];
            float py = (float)(y - 1 + tap / 3) + offy;
            float pxf = (float)(x - 1 + (tap % 3)) + offx;
            float fy = floorf(py), fx = floorf(pxf);
            int y0 = (int)fy, x0 = (int)fx;
            float dyf = py - fy, dxf = pxf - fx;
            #pragma unroll
            for (int j = 0; j < 4; j++) {
                float wj = ((j >> 1) ? dyf : 1.f - dyf) * ((j & 1) ? dxf : 1.f - dxf);
                int yy = y0 + (j >> 1), xx = x0 + (j & 1);
                bool valid = (yy >= 0 && yy < 64 && xx >= 0 && xx < 64);
                int yc = min(max(yy, 0), 63), xc = min(max(xx, 0), 63);
                car[j] = (b * 4096 + yc * 64 + xc) << 6;
                cwr[j] = valid ? wj : 0.f;
            }
        }
        // gather 16 channels of pixel gp (channel-major: 4 lanes cover 128B)
        int c = gsub << 4;
        float va[16];
        #pragma unroll
        for (int e = 0; e < 16; e++) va[e] = 0.f;
        #pragma unroll
        for (int j = 0; j < 4; j++) {
            float w = cwr[j];
            const u16* p = h + car[j] + c;
            short8 r0 = *reinterpret_cast<const short8*>(p);
            short8 r1 = *reinterpret_cast<const short8*>(p + 8);
            #pragma unroll
            for (int e = 0; e < 8; e++) {
                va[e]     = fmaf(w, bf2f((u16)r0[e]), va[e]);
                va[8 + e] = fmaf(w, bf2f((u16)r1[e]), va[8 + e]);
            }
        }
        if (tap < 8) {
            const char* gb = (const char*)(wdc + (size_t)(tap + 1) * 4096);
            char* lb = (char*)&wtile[nxt][0][0][0];
            __builtin_amdgcn_global_load_lds(
                (const __attribute__((address_space(1))) void*)(gb + wid * 1024 + lane * 16),
                (__attribute__((address_space(3))) void*)(lb + wid * 1024), 16, 0, 0);
        }
        short8 s0, s1;
        #pragma unroll
        for (int e = 0; e < 8; e++) { s0[e] = (short)f2bf(va[e]); s1[e] = (short)f2bf(va[8 + e]); }
        *reinterpret_cast<short8*>(&stile[gsub * 2][gp][0]) = s0;
        *reinterpret_cast<short8*>(&stile[gsub * 2 + 1][gp][0]) = s1;

        if (tap < 8) asm volatile("s_waitcnt vmcnt(1) lgkmcnt(0)" ::: "memory");
        else         asm volatile("s_waitcnt vmcnt(0) lgkmcnt(0)" ::: "memory");
        __builtin_amdgcn_s_barrier();

        #pragma unroll
        for (int ks = 0; ks < 4; ks++) {
            int kg = ks * 2 + lhi;
            short8 a0 = *reinterpret_cast<const short8*>(&wtile[cur][kg][o0 + lrow][0]);
            short8 b0 = *reinterpret_cast<const short8*>(&stile[kg][px0 + lrow][0]);
            acc = __builtin_amdgcn_mfma_f32_32x32x16_bf16(a0, b0, acc, 0, 0, 0);
        }
        asm volatile("s_waitcnt lgkmcnt(0)" ::: "memory");
        __builtin_amdgcn_s_barrier();
    }

    // epilogue: feat -> LDS [128][65] f32, then fused mask
    __syncthreads();
    float* featl = (float*)smem;
    int pxl = px0 + lrow;
    #pragma unroll
    for (int r = 0; r < 16; r++) {
        int o = o0 + (r & 3) + ((r >> 2) << 3) + (lhi << 2);
        featl[pxl * 65 + o] = acc[r];
    }
    __syncthreads();
    if (t < 256) {
        int p = t >> 1, hh = t & 1;
        int pix = pix0 + p;
        const float* fr = &featl[p * 65];
        int j0 = hh ? 4 : 0, j1 = hh ? 9 : 4;
        for (int j = j0; j < j1; j++) {
            float a = m_b[j];
            #pragma unroll 8
            for (int cc = 0; cc < 64; cc++) a = fmaf(fr[cc], m_w[j * 64 + cc], a);
            maskb[(size_t)pix * 9 + j] = 1.f / (1.f + expf(-a));
        }
    }
}

// ---------------------------------------------------------------------------
// Modulated DCNv2 (256->256), bf16 MFMA, pipelined.
// 512 blocks x 512 thr; block = 64 px x 256 o; 8 waves, each 32o x 64px.
// LDS = wtile dbuf 64KB + stile 8KB = 72KB -> 2 blocks/CU.
// Channel-major gather: thread = (pixel = t>>3, 8ch-chunk = t&7);
// 8 consecutive lanes read 128B contiguous per corner (4x fewer L1 lines).
// ---------------------------------------------------------------------------
__global__ __launch_bounds__(512) void dconv_big_mfma(
    const u16* __restrict__ xT, const float* __restrict__ offs,
    const float* __restrict__ maskb, const u16* __restrict__ wKg,
    const float* __restrict__ bias, float* __restrict__ out)
{
    __shared__ __attribute__((aligned(16))) u16 wtile[2][8][256][8];  // 64 KB
    __shared__ __attribute__((aligned(16))) u16 stile[8][64][8];      // 8 KB

    int t = threadIdx.x;
    int id = blockIdx.x;                       // 512
    int blk = (id & 7) * 64 + (id >> 3);       // XCD swizzle: image b -> XCD b
    int pix0 = blk * 64;
    int b = pix0 >> 12, pib0 = pix0 & 4095;
    int wid = t >> 6, lane = t & 63;
    int lrow = lane & 31, lhi = lane >> 5;
    int o0 = wid << 5;                         // wave tile: 32 o x 64 px
    int gp = t >> 3, gsub = t & 7;             // gather pixel / 8-ch chunk

    {
        const char* gb = (const char*)wKg;
        char* lb = (char*)&wtile[0][0][0][0];
        #pragma unroll
        for (int i = 0; i < 4; i++) {
            int off = i * 8192 + wid * 1024;
            __builtin_amdgcn_global_load_lds(
                (const __attribute__((address_space(1))) void*)(gb + off + lane * 16),
                (__attribute__((address_space(3))) void*)(lb + off), 16, 0, 0);
        }
    }
    __syncthreads();

    f32x16 acc[2];
    #pragma unroll
    for (int fp = 0; fp < 2; fp++)
        #pragma unroll
        for (int r = 0; r < 16; r++) acc[fp][r] = 0.f;

    int car[4]; float cwr[4];

    for (int kt = 0; kt < 36; ++kt) {
        int cur = kt & 1, nxt = cur ^ 1;
        int tap = kt >> 2, chunk = kt & 3;

        if (chunk == 0) {
            int pix = pix0 + gp; int pib = pix & 4095;
            int y = pib >> 6, x = pib & 63;
            float offy = offs[(size_t)pix * 36 + tap * 2];
            float offx = offs[(size_t)pix * 36 + tap * 2 + 1];
            float m = maskb[(size_t)pix * 9 + tap];
            float py = (float)(y - 1 + tap / 3) + offy;
            float pxf = (float)(x - 1 + (tap % 3)) + offx;
            float fy = floorf(py), fx = floorf(pxf);
            int y0 = (int)fy, x0 = (int)fx;
            float dyf = py - fy, dxf = pxf - fx;
            #pragma unroll
            for (int j = 0; j < 4; j++) {
                float wj = ((j >> 1) ? dyf : 1.f - dyf) * ((j & 1) ? dxf : 1.f - dxf);
                int yy = y0 + (j >> 1), xx = x0 + (j & 1);
                bool valid = (yy >= 0 && yy < 64 && xx >= 0 && xx < 64);
                int yc = min(max(yy, 0), 63), xc = min(max(xx, 0), 63);
                car[j] = (b * 4096 + yc * 64 + xc) << 8;
                cwr[j] = valid ? wj * m : 0.f;
            }
        }

        // gather 8 channels of pixel gp (channel-major coalescing)
        int c = (chunk << 6) + (gsub << 3);
        float va[8];
        #pragma unroll
        for (int e = 0; e < 8; e++) va[e] = 0.f;
        #pragma unroll
        for (int j = 0; j < 4; j++) {
            float w = cwr[j];
            short8 r0 = *reinterpret_cast<const short8*>(xT + car[j] + c);
            #pragma unroll
            for (int e = 0; e < 8; e++) va[e] = fmaf(w, bf2f((u16)r0[e]), va[e]);
        }
        // prefetch next K-step weights (stay in flight across barrier)
        if (kt < 35) {
            const char* gb = (const char*)(wKg + (size_t)(kt + 1) * 16384);
            char* lb = (char*)&wtile[nxt][0][0][0];
            #pragma unroll
            for (int i = 0; i < 4; i++) {
                int off = i * 8192 + wid * 1024;
                __builtin_amdgcn_global_load_lds(
                    (const __attribute__((address_space(1))) void*)(gb + off + lane * 16),
                    (__attribute__((address_space(3))) void*)(lb + off), 16, 0, 0);
            }
        }
        short8 s0;
        #pragma unroll
        for (int e = 0; e < 8; e++) s0[e] = (short)f2bf(va[e]);
        *reinterpret_cast<short8*>(&stile[gsub][gp][0]) = s0;

        if (kt < 35) asm volatile("s_waitcnt vmcnt(4) lgkmcnt(0)" ::: "memory");
        else         asm volatile("s_waitcnt vmcnt(0) lgkmcnt(0)" ::: "memory");
        __builtin_amdgcn_s_barrier();

        #pragma unroll
        for (int ks = 0; ks < 4; ks++) {
            int kg = ks * 2 + lhi;
            short8 a0 = *reinterpret_cast<const short8*>(&wtile[cur][kg][o0 + lrow][0]);
            short8 b0 = *reinterpret_cast<const short8*>(&stile[kg][lrow][0]);
            short8 b1 = *reinterpret_cast<const short8*>(&stile[kg][32 + lrow][0]);
            acc[0] = __builtin_amdgcn_mfma_f32_32x32x16_bf16(a0, b0, acc[0], 0, 0, 0);
            acc[1] = __builtin_amdgcn_mfma_f32_32x32x16_bf16(a0, b1, acc[1], 0, 0, 0);
        }
        asm volatile("s_waitcnt lgkmcnt(0)" ::: "memory");
        __builtin_amdgcn_s_barrier();
    }

    // epilogue: bias + store NCHW f32
    #pragma unroll
    for (int fp = 0; fp < 2; fp++) {
        #pragma unroll
        for (int r = 0; r < 16; r++) {
            int o = o0 + (r & 3) + ((r >> 2) << 3) + (lhi << 2);
            size_t rowoff = ((size_t)(b * 256 + o) << 12) + pib0;
            out[rowoff + fp * 32 + lrow] = acc[fp][r] + bias[o];
        }
    }
}

extern "C" void kernel_launch(void* const* d_in, const int* in_sizes, int n_in,
                              void* d_out, int out_size, void* d_ws, size_t ws_size,
                              hipStream_t stream)
{
    const float* x        = (const float*)d_in[0];
    const float* S        = (const float*)d_in[1];
    const float* sp_w1    = (const float*)d_in[2];
    const float* sp_b1    = (const float*)d_in[3];
    const float* sp_s1    = (const float*)d_in[4];
    const float* sp_o1    = (const float*)d_in[5];
    const float* sp_w2    = (const float*)d_in[6];
    const float* sp_b2    = (const float*)d_in[7];
    const float* sp_s2    = (const float*)d_in[8];
    const float* sp_o2    = (const float*)d_in[9];
    const float* sp_w3    = (const float*)d_in[10];
    const float* sp_b3    = (const float*)d_in[11];
    const float* sp_s3    = (const float*)d_in[12];
    const float* sp_o3    = (const float*)d_in[13];
    const float* off_w    = (const float*)d_in[14];
    const float* off_b    = (const float*)d_in[15];
    const float* dc_off_w = (const float*)d_in[16];
    const float* dc_off_b = (const float*)d_in[17];
    const float* dc_w     = (const float*)d_in[18];
    const float* m_w      = (const float*)d_in[19];
    const float* m_b      = (const float*)d_in[20];
    const float* weight   = (const float*)d_in[21];
    const float* bias     = (const float*)d_in[22];
    float* out = (float*)d_out;
    float* ws  = (float*)d_ws;

    u16*   xTb   = (u16*)(ws + OXT);
    float* Si    = ws + OSI;
    u16*   h1    = (u16*)(ws + OA);
    u16*   h2    = (u16*)(ws + OB);
    u16*   h3    = (u16*)(ws + OC);
    float* offsb = ws + OOFFS;
    float* maskb = ws + OMSK;

    prep_k<<<2888, 256, 0, stream>>>(weight, sp_w1, sp_s1, sp_w2, sp_s2, sp_w3, sp_s3,
                                     off_w, dc_off_w, dc_w,
                                     sp_b1, sp_o1, sp_b2, sp_o2, sp_b3, sp_o3,
                                     off_b, dc_off_b, ws);
    transpose_x_k<<<2048, 256, 0, stream>>>(x, xTb);
    resize_k<<<384, 256, 0, stream>>>(S, Si);
    conv_in_k<<<512, 256, 0, stream>>>(Si, ws + OWSP1, ws + OBSP1, h1);
    conv_mfma_k<0, true><<<512, 256, 0, stream>>>(h1, (const u16*)(ws + OWSP2),
                                                  ws + OBSP2, h2, nullptr);
    conv_mfma_k<0, true><<<512, 256, 0, stream>>>(h2, (const u16*)(ws + OWSP3),
                                                  ws + OBSP3, h3, nullptr);
    conv_mfma_k<1, false><<<512, 256, 0, stream>>>(h3, (const u16*)(ws + OWOFF),
                                                   ws + OBOFF, nullptr, offsb);
    dconv_small_mfma<<<256, 512, 0, stream>>>(h3, offsb, (const u16*)(ws + OWDC),
                                              m_w, m_b, maskb);
    dconv_big_mfma<<<512, 512, 0, stream>>>(xTb, offsb, maskb,
                                            (const u16*)(ws + OWT), bias, out);
}

// Round 7
// 147.559 us; speedup vs baseline: 6.6575x; 1.0142x over previous
//
#include <hip/hip_runtime.h>
#include <hip/hip_bf16.h>

typedef unsigned short u16;
typedef unsigned int u32;
typedef __attribute__((ext_vector_type(8))) short short8;
typedef __attribute__((ext_vector_type(4))) unsigned short ush4;
typedef __attribute__((ext_vector_type(16))) float f32x16;

// ---------------------------------------------------------------------------
// ws layout (float units): see prior rounds.
// ---------------------------------------------------------------------------
#define OXT   0
#define OSI   (OXT + 8388608)
#define OA    (OSI + 98304)
#define OB    (OA + 2097152)
#define OC    (OB + 2097152)
#define OOFFS (OC + 2097152)
#define OMSK  (OOFFS + 1179648)
#define OWT   (OMSK + 294912)
#define OWSP1 (OWT + 589824)
#define OBSP1 (OWSP1 + 1728)
#define OWSP2 (OBSP1 + 64)
#define OBSP2 (OWSP2 + 36864)
#define OWSP3 (OBSP2 + 64)
#define OBSP3 (OWSP3 + 36864)
#define OWOFF (OBSP3 + 64)
#define OBOFF (OWOFF + 36864)
#define OWDC  (OBOFF + 64)

__device__ __forceinline__ u16 f2bf(float f) {
    __hip_bfloat16 hb = __float2bfloat16(f);
    return __builtin_bit_cast(u16, hb);
}
__device__ __forceinline__ float bf2f(u16 v) {
    return __builtin_bit_cast(float, (u32)v << 16);
}
// XOR slot swizzle: data (kg, px) lives at row kg, slot = px with low3 ^ kg.
// Makes channel-major gather ds_writes AND MFMA ds_reads bank-conflict-free.
__device__ __forceinline__ int sswz(int kg, int px) {
    return (px & ~7) | ((px ^ kg) & 7);
}

// ---------------------------------------------------------------------------
__global__ __launch_bounds__(256) void prep_k(
    const float* __restrict__ weight,
    const float* __restrict__ sp_w1, const float* __restrict__ sp_s1,
    const float* __restrict__ sp_w2, const float* __restrict__ sp_s2,
    const float* __restrict__ sp_w3, const float* __restrict__ sp_s3,
    const float* __restrict__ off_w, const float* __restrict__ dc_off_w,
    const float* __restrict__ dc_w,
    const float* __restrict__ sp_b1, const float* __restrict__ sp_o1,
    const float* __restrict__ sp_b2, const float* __restrict__ sp_o2,
    const float* __restrict__ sp_b3, const float* __restrict__ sp_o3,
    const float* __restrict__ off_b, const float* __restrict__ dc_off_b,
    float* __restrict__ ws)
{
    int i = blockIdx.x * 256 + threadIdx.x;
    if (i < 589824) {   // wKg bf16 [kg][o][j], K=kg*8+j = k*256+c
        int j = i & 7; int o = (i >> 3) & 255; int kg = i >> 11;
        int K = kg * 8 + j; int k = K >> 8; int c = K & 255;
        ((u16*)(ws + OWT))[i] = f2bf(weight[o * 2304 + c * 9 + k]);
        return;
    }
    i -= 589824;
    if (i < 1728) {     // wsp1 f32 [9][3][64]
        int o = i & 63; int kc = i >> 6; int c = kc % 3; int k = kc / 3;
        ws[OWSP1 + i] = sp_w1[(o * 3 + c) * 9 + k] * sp_s1[o];
        return;
    }
    i -= 1728;
    if (i < 36864) {    // wm2 bf16 [t][kg][o][e]
        int e = i & 7; int o = (i >> 3) & 63; int kg = (i >> 9) & 7; int tp = i >> 12;
        ((u16*)(ws + OWSP2))[i] = f2bf(sp_w2[(o * 64 + kg * 8 + e) * 9 + tp] * sp_s2[o]);
        return;
    }
    i -= 36864;
    if (i < 36864) {
        int e = i & 7; int o = (i >> 3) & 63; int kg = (i >> 9) & 7; int tp = i >> 12;
        ((u16*)(ws + OWSP3))[i] = f2bf(sp_w3[(o * 64 + kg * 8 + e) * 9 + tp] * sp_s3[o]);
        return;
    }
    i -= 36864;
    if (i < 36864) {    // woff bf16
        int e = i & 7; int o = (i >> 3) & 63; int kg = (i >> 9) & 7; int tp = i >> 12;
        int c = kg * 8 + e;
        float v = 0.f;
        if (o < 18) v = off_w[(o * 64 + c) * 9 + tp];
        else if (o < 36) v = dc_off_w[((o - 18) * 64 + c) * 9 + tp];
        ((u16*)(ws + OWOFF))[i] = f2bf(v);
        return;
    }
    i -= 36864;
    if (i < 36864) {    // wdc bf16 [t][kg][o][e]
        int e = i & 7; int o = (i >> 3) & 63; int kg = (i >> 9) & 7; int tp = i >> 12;
        ((u16*)(ws + OWDC))[i] = f2bf(dc_w[(o * 64 + kg * 8 + e) * 9 + tp]);
        return;
    }
    i -= 36864;
    if (i < 64) { ws[OBSP1 + i] = sp_b1[i] * sp_s1[i] + sp_o1[i]; return; }
    i -= 64;
    if (i < 64) { ws[OBSP2 + i] = sp_b2[i] * sp_s2[i] + sp_o2[i]; return; }
    i -= 64;
    if (i < 64) { ws[OBSP3 + i] = sp_b3[i] * sp_s3[i] + sp_o3[i]; return; }
    i -= 64;
    if (i < 64) { ws[OBOFF + i] = (i < 18) ? off_b[i] : (i < 36 ? dc_off_b[i - 18] : 0.f); return; }
}

// x NCHW f32 -> xT NHWC bf16
__global__ __launch_bounds__(256) void transpose_x_k(const float* __restrict__ x,
                                                     u16* __restrict__ xT)
{
    __shared__ float tile[64][65];
    int blk = blockIdx.x;
    int chunk = blk & 3; int by = blk >> 2;
    int b = by >> 6; int y = by & 63;
    int c0 = chunk * 64;
    int t = threadIdx.x;
    for (int i = t; i < 4096; i += 256) {
        int ci = i >> 6, xi = i & 63;
        tile[ci][xi] = x[((b * 256 + c0 + ci) * 64 + y) * 64 + xi];
    }
    __syncthreads();
    for (int i = t; i < 4096; i += 256) {
        int xi = i >> 6, ci = i & 63;
        xT[((b * 64 + y) * 64 + xi) * 256 + c0 + ci] = f2bf(tile[ci][xi]);
    }
}

__global__ __launch_bounds__(256) void resize_k(const float* __restrict__ S,
                                                float* __restrict__ Si)
{
    int i = blockIdx.x * 256 + threadIdx.x;
    if (i >= 8 * 64 * 64 * 3) return;
    int c = i % 3; int x = (i / 3) & 63; int y = (i / 192) & 63; int b = i / 12288;
    const float sc = 127.0f / 63.0f;
    float sy = y * sc, sx = x * sc;
    float fy = floorf(sy), fx = floorf(sx);
    int y0 = (int)fy, x0 = (int)fx;
    int y1 = min(y0 + 1, 127), x1 = min(x0 + 1, 127);
    float wy = sy - fy, wx = sx - fx;
    const float* Sb = S + (size_t)(b * 3 + c) * 16384;
    float v00 = Sb[y0 * 128 + x0], v01 = Sb[y0 * 128 + x1];
    float v10 = Sb[y1 * 128 + x0], v11 = Sb[y1 * 128 + x1];
    Si[i] = (v00 * (1.f - wy) + v10 * wy) * (1.f - wx)
          + (v01 * (1.f - wy) + v11 * wy) * wx;
}

// conv1: 3->64, fp32 VALU, bf16 NHWC output. One block per (b,y) row.
__global__ __launch_bounds__(256) void conv_in_k(const float* __restrict__ in,
                                                 const float* __restrict__ wt,
                                                 const float* __restrict__ bias,
                                                 u16* __restrict__ out)
{
    __shared__ float rows[3][66][3];
    int by = blockIdx.x; int b = by >> 6; int y = by & 63;
    int t = threadIdx.x;
    for (int i = t; i < 3 * 66 * 3; i += 256) {
        int r = i / 198; int rem = i - r * 198;
        int xi = rem / 3; int c = rem - xi * 3;
        int yy = y - 1 + r, xx = xi - 1;
        float v = 0.f;
        if (yy >= 0 && yy < 64 && xx >= 0 && xx < 64)
            v = in[(((b * 64 + yy) * 64 + xx) * 3) + c];
        rows[r][xi][c] = v;
    }
    __syncthreads();
    int o4 = (t & 15) * 4; int xg = t >> 4;
    float acc[4][4];
    #pragma unroll
    for (int oi = 0; oi < 4; oi++) {
        float bv = bias[o4 + oi];
        #pragma unroll
        for (int xi = 0; xi < 4; xi++) acc[oi][xi] = bv;
    }
    for (int k = 0; k < 9; k++) {
        int dy = k / 3, dx = k - 3 * (k / 3);
        for (int c = 0; c < 3; c++) {
            float4 w = *reinterpret_cast<const float4*>(&wt[(k * 3 + c) * 64 + o4]);
            #pragma unroll
            for (int xi = 0; xi < 4; xi++) {
                float iv = rows[dy][xg * 4 + xi + dx][c];
                acc[0][xi] = fmaf(w.x, iv, acc[0][xi]);
                acc[1][xi] = fmaf(w.y, iv, acc[1][xi]);
                acc[2][xi] = fmaf(w.z, iv, acc[2][xi]);
                acc[3][xi] = fmaf(w.w, iv, acc[3][xi]);
            }
        }
    }
    #pragma unroll
    for (int xi = 0; xi < 4; xi++) {
        int x = xg * 4 + xi;
        ush4 v;
        v.x = f2bf(fmaxf(acc[0][xi], 0.f));
        v.y = f2bf(fmaxf(acc[1][xi], 0.f));
        v.z = f2bf(fmaxf(acc[2][xi], 0.f));
        v.w = f2bf(fmaxf(acc[3][xi], 0.f));
        *reinterpret_cast<ush4*>(&out[((size_t)(by * 64 + x)) * 64 + o4]) = v;
    }
}

// ---------------------------------------------------------------------------
// MFMA 3x3 conv 64->64. Block: 1 output row (64 px), 4 waves = 2(o) x 2(px).
// ---------------------------------------------------------------------------
template <int MODE, bool RELU>
__global__ __launch_bounds__(256) void conv_mfma_k(const u16* __restrict__ in,
                                                   const u16* __restrict__ wm,
                                                   const float* __restrict__ bias,
                                                   u16* __restrict__ outH,
                                                   float* __restrict__ outF)
{
    __shared__ __attribute__((aligned(16))) char lds_h[3 * 66 * 128];   // 25344 B
    __shared__ __attribute__((aligned(16))) u16 wtap[2][8][64][8];      // 16384 B

    int t = threadIdx.x;
    int b = blockIdx.x >> 6; int y = blockIdx.x & 63;
    int pix0 = b * 4096 + y * 64;
    int wid = t >> 6, lane = t & 63;
    int lrow = lane & 31, lhi = lane >> 5;
    int o0 = (wid & 1) << 5;
    int px0 = (wid >> 1) << 5;
    int px = px0 + lrow;

    for (int i = t; i < 3 * 66 * 8; i += 256) {
        int r = i / 528; int rem = i - r * 528;
        int xi = rem >> 3; int g = rem & 7;
        int yy = y - 1 + r, xx = xi - 1;
        short8 v = {0,0,0,0,0,0,0,0};
        if (yy >= 0 && yy < 64 && xx >= 0 && xx < 64)
            v = *reinterpret_cast<const short8*>(&in[(size_t)((b * 4096 + yy * 64 + xx)) * 64 + g * 8]);
        int byte = (r * 66 + xi) * 128 + ((g * 16) ^ ((xi & 7) << 4));
        *reinterpret_cast<short8*>(lds_h + byte) = v;
    }
    {
        const char* gb = (const char*)(wm);
        char* lb = (char*)&wtap[0][0][0][0];
        #pragma unroll
        for (int i = 0; i < 2; i++) {
            int off = i * 4096 + wid * 1024;
            __builtin_amdgcn_global_load_lds(
                (const __attribute__((address_space(1))) void*)(gb + off + lane * 16),
                (__attribute__((address_space(3))) void*)(lb + off), 16, 0, 0);
        }
    }
    __syncthreads();

    f32x16 acc;
    #pragma unroll
    for (int r = 0; r < 16; r++) acc[r] = 0.f;

    #pragma unroll
    for (int tap = 0; tap < 9; tap++) {
        int cur = tap & 1, nxt = cur ^ 1;
        if (tap < 8) {
            const char* gb = (const char*)(wm + (size_t)(tap + 1) * 4096);
            char* lb = (char*)&wtap[nxt][0][0][0];
            #pragma unroll
            for (int i = 0; i < 2; i++) {
                int off = i * 4096 + wid * 1024;
                __builtin_amdgcn_global_load_lds(
                    (const __attribute__((address_space(1))) void*)(gb + off + lane * 16),
                    (__attribute__((address_space(3))) void*)(lb + off), 16, 0, 0);
            }
        }
        int dy = tap / 3, dx = tap - 3 * (tap / 3);
        int xi = px + dx;
        int rowbyte = (dy * 66 + xi) * 128;
        int swz = (xi & 7) << 4;
        #pragma unroll
        for (int ks = 0; ks < 4; ks++) {
            int kg = ks * 2 + lhi;
            short8 a0 = *reinterpret_cast<const short8*>(&wtap[cur][kg][o0 + lrow][0]);
            short8 b0 = *reinterpret_cast<const short8*>(lds_h + rowbyte + ((kg * 16) ^ swz));
            acc = __builtin_amdgcn_mfma_f32_32x32x16_bf16(a0, b0, acc, 0, 0, 0);
        }
        if (tap < 8) asm volatile("s_waitcnt vmcnt(0)" ::: "memory");
        __builtin_amdgcn_s_barrier();
    }
    __syncthreads();

    if (MODE == 0) {
        #pragma unroll
        for (int q = 0; q < 4; q++) {
            int ob = o0 + q * 8 + 4 * lhi;
            #pragma unroll
            for (int h = 0; h < 2; h++) {
                float v0 = acc[q * 4 + h * 2] + bias[ob + h * 2];
                float v1 = acc[q * 4 + h * 2 + 1] + bias[ob + h * 2 + 1];
                if (RELU) { v0 = fmaxf(v0, 0.f); v1 = fmaxf(v1, 0.f); }
                u32 pk = (u32)f2bf(v0) | ((u32)f2bf(v1) << 16);
                int byte = px * 128 + (((ob + h * 2) * 2) ^ ((px & 7) << 4));
                *reinterpret_cast<u32*>(lds_h + byte) = pk;
            }
        }
        __syncthreads();
        #pragma unroll
        for (int i = 0; i < 2; i++) {
            int cid = i * 256 + t;
            int p = cid >> 3, g = cid & 7;
            short8 v = *reinterpret_cast<const short8*>(lds_h + p * 128 + ((g * 16) ^ ((p & 7) << 4)));
            *reinterpret_cast<short8*>(&outH[(size_t)(pix0 + p) * 64 + g * 8]) = v;
        }
    } else {
        float* ltf = (float*)lds_h;
        #pragma unroll
        for (int r = 0; r < 16; r++) {
            int o = o0 + (r & 3) + ((r >> 2) << 3) + (lhi << 2);
            if (o < 36) ltf[px * 40 + o] = acc[r] + bias[o];
        }
        __syncthreads();
        for (int i = t; i < 576; i += 256) {
            int p = i / 9, q = i - 9 * (i / 9);
            float4 v = *reinterpret_cast<const float4*>(&ltf[p * 40 + q * 4]);
            *reinterpret_cast<float4*>(&outF[(size_t)(pix0 + p) * 36 + q * 4]) = v;
        }
    }
}

// ---------------------------------------------------------------------------
// DCNv1 on h (bf16, 64->64) + fused mask head.
// 256 blocks x 512 thr; 128px x 64o; channel-major gather (p=t>>2, sub=t&3).
// XOR-swizzled dbuf stile + single barrier per tap, post-barrier prefetch.
// LDS: wtile dbuf 16KB + stile dbuf 32KB = 48KB (feat overlay fits).
// ---------------------------------------------------------------------------
__global__ __launch_bounds__(512) void dconv_small_mfma(
    const u16* __restrict__ h, const float* __restrict__ offs,
    const u16* __restrict__ wdc, const float* __restrict__ m_w,
    const float* __restrict__ m_b, float* __restrict__ maskb)
{
    __shared__ __attribute__((aligned(16))) char smem[49152];
    u16 (*wtile)[8][64][8]  = (u16 (*)[8][64][8])smem;            // [2][8][64][8]  16KB
    u16 (*stile)[8][128][8] = (u16 (*)[8][128][8])(smem + 16384); // [2][8][128][8] 32KB

    int t = threadIdx.x;
    int id = blockIdx.x;
    int blk = (id & 7) * 32 + (id >> 3);      // XCD swizzle
    int pix0 = blk * 128;
    int b = pix0 >> 12;
    int wid = t >> 6, lane = t & 63;
    int lrow = lane & 31, lhi = lane >> 5;
    int o0 = (wid & 1) << 5;
    int px0 = (wid >> 1) << 5;
    int gp = t >> 2, gsub = t & 3;            // pixel / 16-ch chunk

    {
        const char* gb = (const char*)wdc;
        char* lb = (char*)&wtile[0][0][0][0];
        __builtin_amdgcn_global_load_lds(
            (const __attribute__((address_space(1))) void*)(gb + wid * 1024 + lane * 16),
            (__attribute__((address_space(3))) void*)(lb + wid * 1024), 16, 0, 0);
    }

    f32x16 acc;
    #pragma unroll
    for (int r = 0; r < 16; r++) acc[r] = 0.f;

    int car[4]; float cwr[4];

    for (int tap = 0; tap < 9; ++tap) {
        int cur = tap & 1, nxt = cur ^ 1;
        // recompute corner table for (tap, gp) in registers
        {
            int pix = pix0 + gp; int pib = pix & 4095;
            int y = pib >> 6, x = pib & 63;
            float offy = offs[(size_t)pix * 36 + 18 + tap * 2];
            float offx = offs[(size_t)pix * 36 + 18 + tap * 2 + 1];
            float py = (float)(y - 1 + tap / 3) + offy;
            float pxf = (float)(x - 1 + (tap % 3)) + offx;
            float fy = floorf(py), fx = floorf(pxf);
            int y0 = (int)fy, x0 = (int)fx;
            float dyf = py - fy, dxf = pxf - fx;
            #pragma unroll
            for (int j = 0; j < 4; j++) {
                float wj = ((j >> 1) ? dyf : 1.f - dyf) * ((j & 1) ? dxf : 1.f - dxf);
                int yy = y0 + (j >> 1), xx = x0 + (j & 1);
                bool valid = (yy >= 0 && yy < 64 && xx >= 0 && xx < 64);
                int yc = min(max(yy, 0), 63), xc = min(max(xx, 0), 63);
                car[j] = (b * 4096 + yc * 64 + xc) << 6;
                cwr[j] = valid ? wj : 0.f;
            }
        }
        // gather 16 channels of pixel gp (channel-major: 4 lanes cover 128B)
        int c = gsub << 4;
        float va[16];
        #pragma unroll
        for (int e = 0; e < 16; e++) va[e] = 0.f;
        #pragma unroll
        for (int j = 0; j < 4; j++) {
            float w = cwr[j];
            const u16* p = h + car[j] + c;
            short8 r0 = *reinterpret_cast<const short8*>(p);
            short8 r1 = *reinterpret_cast<const short8*>(p + 8);
            #pragma unroll
            for (int e = 0; e < 8; e++) {
                va[e]     = fmaf(w, bf2f((u16)r0[e]), va[e]);
                va[8 + e] = fmaf(w, bf2f((u16)r1[e]), va[8 + e]);
            }
        }
        short8 s0, s1;
        #pragma unroll
        for (int e = 0; e < 8; e++) { s0[e] = (short)f2bf(va[e]); s1[e] = (short)f2bf(va[8 + e]); }
        int kg0 = gsub * 2, kg1 = gsub * 2 + 1;
        *reinterpret_cast<short8*>(&stile[cur][kg0][sswz(kg0, gp)][0]) = s0;
        *reinterpret_cast<short8*>(&stile[cur][kg1][sswz(kg1, gp)][0]) = s1;

        asm volatile("s_waitcnt vmcnt(0) lgkmcnt(0)" ::: "memory");
        __builtin_amdgcn_s_barrier();

        #pragma unroll
        for (int ks = 0; ks < 4; ks++) {
            int kg = ks * 2 + lhi;
            short8 a0 = *reinterpret_cast<const short8*>(&wtile[cur][kg][o0 + lrow][0]);
            short8 b0 = *reinterpret_cast<const short8*>(&stile[cur][kg][sswz(kg, px0 + lrow)][0]);
            acc = __builtin_amdgcn_mfma_f32_32x32x16_bf16(a0, b0, acc, 0, 0, 0);
        }
        // post-barrier prefetch of next tap's weights (safe: all reads of the
        // target buffer drained by every wave's pre-barrier lgkmcnt(0))
        if (tap < 8) {
            const char* gb = (const char*)(wdc + (size_t)(tap + 1) * 4096);
            char* lb = (char*)&wtile[nxt][0][0][0];
            __builtin_amdgcn_global_load_lds(
                (const __attribute__((address_space(1))) void*)(gb + wid * 1024 + lane * 16),
                (__attribute__((address_space(3))) void*)(lb + wid * 1024), 16, 0, 0);
        }
    }

    // epilogue: feat -> LDS [128][65] f32, then fused mask
    __syncthreads();
    float* featl = (float*)smem;
    int pxl = px0 + lrow;
    #pragma unroll
    for (int r = 0; r < 16; r++) {
        int o = o0 + (r & 3) + ((r >> 2) << 3) + (lhi << 2);
        featl[pxl * 65 + o] = acc[r];
    }
    __syncthreads();
    if (t < 256) {
        int p = t >> 1, hh = t & 1;
        int pix = pix0 + p;
        const float* fr = &featl[p * 65];
        int j0 = hh ? 4 : 0, j1 = hh ? 9 : 4;
        for (int j = j0; j < j1; j++) {
            float a = m_b[j];
            #pragma unroll 8
            for (int cc = 0; cc < 64; cc++) a = fmaf(fr[cc], m_w[j * 64 + cc], a);
            maskb[(size_t)pix * 9 + j] = 1.f / (1.f + expf(-a));
        }
    }
}

// ---------------------------------------------------------------------------
// Modulated DCNv2 (256->256), bf16 MFMA, pipelined.
// 512 blocks x 512 thr; block = 64 px x 256 o; 8 waves, each 32o x 64px.
// LDS = wtile dbuf 64KB + stile dbuf 16KB = 80KB -> 2 blocks/CU.
// Channel-major gather + XOR-swizzled stile (conflict-free write & read).
// Single barrier per K-step; weight prefetch issued post-barrier.
// ---------------------------------------------------------------------------
__global__ __launch_bounds__(512) void dconv_big_mfma(
    const u16* __restrict__ xT, const float* __restrict__ offs,
    const float* __restrict__ maskb, const u16* __restrict__ wKg,
    const float* __restrict__ bias, float* __restrict__ out)
{
    __shared__ __attribute__((aligned(16))) u16 wtile[2][8][256][8];  // 64 KB
    __shared__ __attribute__((aligned(16))) u16 stile[2][8][64][8];   // 16 KB

    int t = threadIdx.x;
    int id = blockIdx.x;                       // 512
    int blk = (id & 7) * 64 + (id >> 3);       // XCD swizzle: image b -> XCD b
    int pix0 = blk * 64;
    int b = pix0 >> 12, pib0 = pix0 & 4095;
    int wid = t >> 6, lane = t & 63;
    int lrow = lane & 31, lhi = lane >> 5;
    int o0 = wid << 5;                         // wave tile: 32 o x 64 px
    int gp = t >> 3, gsub = t & 7;             // gather pixel / 8-ch chunk

    {
        const char* gb = (const char*)wKg;
        char* lb = (char*)&wtile[0][0][0][0];
        #pragma unroll
        for (int i = 0; i < 4; i++) {
            int off = i * 8192 + wid * 1024;
            __builtin_amdgcn_global_load_lds(
                (const __attribute__((address_space(1))) void*)(gb + off + lane * 16),
                (__attribute__((address_space(3))) void*)(lb + off), 16, 0, 0);
        }
    }

    f32x16 acc[2];
    #pragma unroll
    for (int fp = 0; fp < 2; fp++)
        #pragma unroll
        for (int r = 0; r < 16; r++) acc[fp][r] = 0.f;

    int car[4]; float cwr[4];

    for (int kt = 0; kt < 36; ++kt) {
        int cur = kt & 1, nxt = cur ^ 1;
        int tap = kt >> 2, chunk = kt & 3;

        if (chunk == 0) {
            int pix = pix0 + gp; int pib = pix & 4095;
            int y = pib >> 6, x = pib & 63;
            float offy = offs[(size_t)pix * 36 + tap * 2];
            float offx = offs[(size_t)pix * 36 + tap * 2 + 1];
            float m = maskb[(size_t)pix * 9 + tap];
            float py = (float)(y - 1 + tap / 3) + offy;
            float pxf = (float)(x - 1 + (tap % 3)) + offx;
            float fy = floorf(py), fx = floorf(pxf);
            int y0 = (int)fy, x0 = (int)fx;
            float dyf = py - fy, dxf = pxf - fx;
            #pragma unroll
            for (int j = 0; j < 4; j++) {
                float wj = ((j >> 1) ? dyf : 1.f - dyf) * ((j & 1) ? dxf : 1.f - dxf);
                int yy = y0 + (j >> 1), xx = x0 + (j & 1);
                bool valid = (yy >= 0 && yy < 64 && xx >= 0 && xx < 64);
                int yc = min(max(yy, 0), 63), xc = min(max(xx, 0), 63);
                car[j] = (b * 4096 + yc * 64 + xc) << 8;
                cwr[j] = valid ? wj * m : 0.f;
            }
        }

        // gather 8 channels of pixel gp (channel-major coalescing)
        int c = (chunk << 6) + (gsub << 3);
        float va[8];
        #pragma unroll
        for (int e = 0; e < 8; e++) va[e] = 0.f;
        #pragma unroll
        for (int j = 0; j < 4; j++) {
            float w = cwr[j];
            short8 r0 = *reinterpret_cast<const short8*>(xT + car[j] + c);
            #pragma unroll
            for (int e = 0; e < 8; e++) va[e] = fmaf(w, bf2f((u16)r0[e]), va[e]);
        }
        short8 s0;
        #pragma unroll
        for (int e = 0; e < 8; e++) s0[e] = (short)f2bf(va[e]);
        *reinterpret_cast<short8*>(&stile[cur][gsub][sswz(gsub, gp)][0]) = s0;

        asm volatile("s_waitcnt vmcnt(0) lgkmcnt(0)" ::: "memory");
        __builtin_amdgcn_s_barrier();

        #pragma unroll
        for (int ks = 0; ks < 4; ks++) {
            int kg = ks * 2 + lhi;
            short8 a0 = *reinterpret_cast<const short8*>(&wtile[cur][kg][o0 + lrow][0]);
            short8 b0 = *reinterpret_cast<const short8*>(&stile[cur][kg][sswz(kg, lrow)][0]);
            short8 b1 = *reinterpret_cast<const short8*>(&stile[cur][kg][sswz(kg, 32 + lrow)][0]);
            acc[0] = __builtin_amdgcn_mfma_f32_32x32x16_bf16(a0, b0, acc[0], 0, 0, 0);
            acc[1] = __builtin_amdgcn_mfma_f32_32x32x16_bf16(a0, b1, acc[1], 0, 0, 0);
        }
        // post-barrier prefetch of next K-step weights (safe per barrier proof)
        if (kt < 35) {
            const char* gb = (const char*)(wKg + (size_t)(kt + 1) * 16384);
            char* lb = (char*)&wtile[nxt][0][0][0];
            #pragma unroll
            for (int i = 0; i < 4; i++) {
                int off = i * 8192 + wid * 1024;
                __builtin_amdgcn_global_load_lds(
                    (const __attribute__((address_space(1))) void*)(gb + off + lane * 16),
                    (__attribute__((address_space(3))) void*)(lb + off), 16, 0, 0);
            }
        }
    }

    // epilogue: bias + store NCHW f32
    #pragma unroll
    for (int fp = 0; fp < 2; fp++) {
        #pragma unroll
        for (int r = 0; r < 16; r++) {
            int o = o0 + (r & 3) + ((r >> 2) << 3) + (lhi << 2);
            size_t rowoff = ((size_t)(b * 256 + o) << 12) + pib0;
            out[rowoff + fp * 32 + lrow] = acc[fp][r] + bias[o];
        }
    }
}

extern "C" void kernel_launch(void* const* d_in, const int* in_sizes, int n_in,
                              void* d_out, int out_size, void* d_ws, size_t ws_size,
                              hipStream_t stream)
{
    const float* x        = (const float*)d_in[0];
    const float* S        = (const float*)d_in[1];
    const float* sp_w1    = (const float*)d_in[2];
    const float* sp_b1    = (const float*)d_in[3];
    const float* sp_s1    = (const float*)d_in[4];
    const float* sp_o1    = (const float*)d_in[5];
    const float* sp_w2    = (const float*)d_in[6];
    const float* sp_b2    = (const float*)d_in[7];
    const float* sp_s2    = (const float*)d_in[8];
    const float* sp_o2    = (const float*)d_in[9];
    const float* sp_w3    = (const float*)d_in[10];
    const float* sp_b3    = (const float*)d_in[11];
    const float* sp_s3    = (const float*)d_in[12];
    const float* sp_o3    = (const float*)d_in[13];
    const float* off_w    = (const float*)d_in[14];
    const float* off_b    = (const float*)d_in[15];
    const float* dc_off_w = (const float*)d_in[16];
    const float* dc_off_b = (const float*)d_in[17];
    const float* dc_w     = (const float*)d_in[18];
    const float* m_w      = (const float*)d_in[19];
    const float* m_b      = (const float*)d_in[20];
    const float* weight   = (const float*)d_in[21];
    const float* bias     = (const float*)d_in[22];
    float* out = (float*)d_out;
    float* ws  = (float*)d_ws;

    u16*   xTb   = (u16*)(ws + OXT);
    float* Si    = ws + OSI;
    u16*   h1    = (u16*)(ws + OA);
    u16*   h2    = (u16*)(ws + OB);
    u16*   h3    = (u16*)(ws + OC);
    float* offsb = ws + OOFFS;
    float* maskb = ws + OMSK;

    prep_k<<<2888, 256, 0, stream>>>(weight, sp_w1, sp_s1, sp_w2, sp_s2, sp_w3, sp_s3,
                                     off_w, dc_off_w, dc_w,
                                     sp_b1, sp_o1, sp_b2, sp_o2, sp_b3, sp_o3,
                                     off_b, dc_off_b, ws);
    transpose_x_k<<<2048, 256, 0, stream>>>(x, xTb);
    resize_k<<<384, 256, 0, stream>>>(S, Si);
    conv_in_k<<<512, 256, 0, stream>>>(Si, ws + OWSP1, ws + OBSP1, h1);
    conv_mfma_k<0, true><<<512, 256, 0, stream>>>(h1, (const u16*)(ws + OWSP2),
                                                  ws + OBSP2, h2, nullptr);
    conv_mfma_k<0, true><<<512, 256, 0, stream>>>(h2, (const u16*)(ws + OWSP3),
                                                  ws + OBSP3, h3, nullptr);
    conv_mfma_k<1, false><<<512, 256, 0, stream>>>(h3, (const u16*)(ws + OWOFF),
                                                   ws + OBOFF, nullptr, offsb);
    dconv_small_mfma<<<256, 512, 0, stream>>>(h3, offsb, (const u16*)(ws + OWDC),
                                              m_w, m_b, maskb);
    dconv_big_mfma<<<512, 512, 0, stream>>>(xTb, offsb, maskb,
                                            (const u16*)(ws + OWT), bias, out);
}

// Round 8
// 147.340 us; speedup vs baseline: 6.6673x; 1.0015x over previous
//
#include <hip/hip_runtime.h>
#include <hip/hip_bf16.h>

typedef unsigned short u16;
typedef unsigned int u32;
typedef __attribute__((ext_vector_type(8))) short short8;
typedef __attribute__((ext_vector_type(4))) unsigned short ush4;
typedef __attribute__((ext_vector_type(16))) float f32x16;

// ---------------------------------------------------------------------------
// ws layout (float units): see prior rounds.
// ---------------------------------------------------------------------------
#define OXT   0
#define OSI   (OXT + 8388608)
#define OA    (OSI + 98304)
#define OB    (OA + 2097152)
#define OC    (OB + 2097152)
#define OOFFS (OC + 2097152)
#define OMSK  (OOFFS + 1179648)
#define OWT   (OMSK + 294912)
#define OWSP1 (OWT + 589824)
#define OBSP1 (OWSP1 + 1728)
#define OWSP2 (OBSP1 + 64)
#define OBSP2 (OWSP2 + 36864)
#define OWSP3 (OBSP2 + 64)
#define OBSP3 (OWSP3 + 36864)
#define OWOFF (OBSP3 + 64)
#define OBOFF (OWOFF + 36864)
#define OWDC  (OBOFF + 64)

__device__ __forceinline__ u16 f2bf(float f) {
    __hip_bfloat16 hb = __float2bfloat16(f);
    return __builtin_bit_cast(u16, hb);
}
__device__ __forceinline__ float bf2f(u16 v) {
    return __builtin_bit_cast(float, (u32)v << 16);
}
// XOR slot swizzle: data (kg, px) lives at row kg, slot = px with low3 ^ kg.
// Makes channel-major gather ds_writes AND MFMA ds_reads bank-conflict-free.
__device__ __forceinline__ int sswz(int kg, int px) {
    return (px & ~7) | ((px ^ kg) & 7);
}

// ---------------------------------------------------------------------------
__global__ __launch_bounds__(256) void prep_k(
    const float* __restrict__ weight,
    const float* __restrict__ sp_w1, const float* __restrict__ sp_s1,
    const float* __restrict__ sp_w2, const float* __restrict__ sp_s2,
    const float* __restrict__ sp_w3, const float* __restrict__ sp_s3,
    const float* __restrict__ off_w, const float* __restrict__ dc_off_w,
    const float* __restrict__ dc_w,
    const float* __restrict__ sp_b1, const float* __restrict__ sp_o1,
    const float* __restrict__ sp_b2, const float* __restrict__ sp_o2,
    const float* __restrict__ sp_b3, const float* __restrict__ sp_o3,
    const float* __restrict__ off_b, const float* __restrict__ dc_off_b,
    float* __restrict__ ws)
{
    int i = blockIdx.x * 256 + threadIdx.x;
    if (i < 589824) {   // wKg bf16 [kg][o][j], K=kg*8+j = k*256+c
        int j = i & 7; int o = (i >> 3) & 255; int kg = i >> 11;
        int K = kg * 8 + j; int k = K >> 8; int c = K & 255;
        ((u16*)(ws + OWT))[i] = f2bf(weight[o * 2304 + c * 9 + k]);
        return;
    }
    i -= 589824;
    if (i < 1728) {     // wsp1 f32 [9][3][64]
        int o = i & 63; int kc = i >> 6; int c = kc % 3; int k = kc / 3;
        ws[OWSP1 + i] = sp_w1[(o * 3 + c) * 9 + k] * sp_s1[o];
        return;
    }
    i -= 1728;
    if (i < 36864) {    // wm2 bf16 [t][kg][o][e]
        int e = i & 7; int o = (i >> 3) & 63; int kg = (i >> 9) & 7; int tp = i >> 12;
        ((u16*)(ws + OWSP2))[i] = f2bf(sp_w2[(o * 64 + kg * 8 + e) * 9 + tp] * sp_s2[o]);
        return;
    }
    i -= 36864;
    if (i < 36864) {
        int e = i & 7; int o = (i >> 3) & 63; int kg = (i >> 9) & 7; int tp = i >> 12;
        ((u16*)(ws + OWSP3))[i] = f2bf(sp_w3[(o * 64 + kg * 8 + e) * 9 + tp] * sp_s3[o]);
        return;
    }
    i -= 36864;
    if (i < 36864) {    // woff bf16
        int e = i & 7; int o = (i >> 3) & 63; int kg = (i >> 9) & 7; int tp = i >> 12;
        int c = kg * 8 + e;
        float v = 0.f;
        if (o < 18) v = off_w[(o * 64 + c) * 9 + tp];
        else if (o < 36) v = dc_off_w[((o - 18) * 64 + c) * 9 + tp];
        ((u16*)(ws + OWOFF))[i] = f2bf(v);
        return;
    }
    i -= 36864;
    if (i < 36864) {    // wdc bf16 [t][kg][o][e]
        int e = i & 7; int o = (i >> 3) & 63; int kg = (i >> 9) & 7; int tp = i >> 12;
        ((u16*)(ws + OWDC))[i] = f2bf(dc_w[(o * 64 + kg * 8 + e) * 9 + tp]);
        return;
    }
    i -= 36864;
    if (i < 64) { ws[OBSP1 + i] = sp_b1[i] * sp_s1[i] + sp_o1[i]; return; }
    i -= 64;
    if (i < 64) { ws[OBSP2 + i] = sp_b2[i] * sp_s2[i] + sp_o2[i]; return; }
    i -= 64;
    if (i < 64) { ws[OBSP3 + i] = sp_b3[i] * sp_s3[i] + sp_o3[i]; return; }
    i -= 64;
    if (i < 64) { ws[OBOFF + i] = (i < 18) ? off_b[i] : (i < 36 ? dc_off_b[i - 18] : 0.f); return; }
}

// x NCHW f32 -> xT NHWC bf16
__global__ __launch_bounds__(256) void transpose_x_k(const float* __restrict__ x,
                                                     u16* __restrict__ xT)
{
    __shared__ float tile[64][65];
    int blk = blockIdx.x;
    int chunk = blk & 3; int by = blk >> 2;
    int b = by >> 6; int y = by & 63;
    int c0 = chunk * 64;
    int t = threadIdx.x;
    for (int i = t; i < 4096; i += 256) {
        int ci = i >> 6, xi = i & 63;
        tile[ci][xi] = x[((b * 256 + c0 + ci) * 64 + y) * 64 + xi];
    }
    __syncthreads();
    for (int i = t; i < 4096; i += 256) {
        int xi = i >> 6, ci = i & 63;
        xT[((b * 64 + y) * 64 + xi) * 256 + c0 + ci] = f2bf(tile[ci][xi]);
    }
}

__global__ __launch_bounds__(256) void resize_k(const float* __restrict__ S,
                                                float* __restrict__ Si)
{
    int i = blockIdx.x * 256 + threadIdx.x;
    if (i >= 8 * 64 * 64 * 3) return;
    int c = i % 3; int x = (i / 3) & 63; int y = (i / 192) & 63; int b = i / 12288;
    const float sc = 127.0f / 63.0f;
    float sy = y * sc, sx = x * sc;
    float fy = floorf(sy), fx = floorf(sx);
    int y0 = (int)fy, x0 = (int)fx;
    int y1 = min(y0 + 1, 127), x1 = min(x0 + 1, 127);
    float wy = sy - fy, wx = sx - fx;
    const float* Sb = S + (size_t)(b * 3 + c) * 16384;
    float v00 = Sb[y0 * 128 + x0], v01 = Sb[y0 * 128 + x1];
    float v10 = Sb[y1 * 128 + x0], v11 = Sb[y1 * 128 + x1];
    Si[i] = (v00 * (1.f - wy) + v10 * wy) * (1.f - wx)
          + (v01 * (1.f - wy) + v11 * wy) * wx;
}

// conv1: 3->64, fp32 VALU, bf16 NHWC output. One block per (b,y) row.
__global__ __launch_bounds__(256) void conv_in_k(const float* __restrict__ in,
                                                 const float* __restrict__ wt,
                                                 const float* __restrict__ bias,
                                                 u16* __restrict__ out)
{
    __shared__ float rows[3][66][3];
    int by = blockIdx.x; int b = by >> 6; int y = by & 63;
    int t = threadIdx.x;
    for (int i = t; i < 3 * 66 * 3; i += 256) {
        int r = i / 198; int rem = i - r * 198;
        int xi = rem / 3; int c = rem - xi * 3;
        int yy = y - 1 + r, xx = xi - 1;
        float v = 0.f;
        if (yy >= 0 && yy < 64 && xx >= 0 && xx < 64)
            v = in[(((b * 64 + yy) * 64 + xx) * 3) + c];
        rows[r][xi][c] = v;
    }
    __syncthreads();
    int o4 = (t & 15) * 4; int xg = t >> 4;
    float acc[4][4];
    #pragma unroll
    for (int oi = 0; oi < 4; oi++) {
        float bv = bias[o4 + oi];
        #pragma unroll
        for (int xi = 0; xi < 4; xi++) acc[oi][xi] = bv;
    }
    for (int k = 0; k < 9; k++) {
        int dy = k / 3, dx = k - 3 * (k / 3);
        for (int c = 0; c < 3; c++) {
            float4 w = *reinterpret_cast<const float4*>(&wt[(k * 3 + c) * 64 + o4]);
            #pragma unroll
            for (int xi = 0; xi < 4; xi++) {
                float iv = rows[dy][xg * 4 + xi + dx][c];
                acc[0][xi] = fmaf(w.x, iv, acc[0][xi]);
                acc[1][xi] = fmaf(w.y, iv, acc[1][xi]);
                acc[2][xi] = fmaf(w.z, iv, acc[2][xi]);
                acc[3][xi] = fmaf(w.w, iv, acc[3][xi]);
            }
        }
    }
    #pragma unroll
    for (int xi = 0; xi < 4; xi++) {
        int x = xg * 4 + xi;
        ush4 v;
        v.x = f2bf(fmaxf(acc[0][xi], 0.f));
        v.y = f2bf(fmaxf(acc[1][xi], 0.f));
        v.z = f2bf(fmaxf(acc[2][xi], 0.f));
        v.w = f2bf(fmaxf(acc[3][xi], 0.f));
        *reinterpret_cast<ush4*>(&out[((size_t)(by * 64 + x)) * 64 + o4]) = v;
    }
}

// ---------------------------------------------------------------------------
// MFMA 3x3 conv 64->64. Block: 1 output row (64 px), 4 waves = 2(o) x 2(px).
// ---------------------------------------------------------------------------
template <int MODE, bool RELU>
__global__ __launch_bounds__(256) void conv_mfma_k(const u16* __restrict__ in,
                                                   const u16* __restrict__ wm,
                                                   const float* __restrict__ bias,
                                                   u16* __restrict__ outH,
                                                   float* __restrict__ outF)
{
    __shared__ __attribute__((aligned(16))) char lds_h[3 * 66 * 128];   // 25344 B
    __shared__ __attribute__((aligned(16))) u16 wtap[2][8][64][8];      // 16384 B

    int t = threadIdx.x;
    int b = blockIdx.x >> 6; int y = blockIdx.x & 63;
    int pix0 = b * 4096 + y * 64;
    int wid = t >> 6, lane = t & 63;
    int lrow = lane & 31, lhi = lane >> 5;
    int o0 = (wid & 1) << 5;
    int px0 = (wid >> 1) << 5;
    int px = px0 + lrow;

    for (int i = t; i < 3 * 66 * 8; i += 256) {
        int r = i / 528; int rem = i - r * 528;
        int xi = rem >> 3; int g = rem & 7;
        int yy = y - 1 + r, xx = xi - 1;
        short8 v = {0,0,0,0,0,0,0,0};
        if (yy >= 0 && yy < 64 && xx >= 0 && xx < 64)
            v = *reinterpret_cast<const short8*>(&in[(size_t)((b * 4096 + yy * 64 + xx)) * 64 + g * 8]);
        int byte = (r * 66 + xi) * 128 + ((g * 16) ^ ((xi & 7) << 4));
        *reinterpret_cast<short8*>(lds_h + byte) = v;
    }
    {
        const char* gb = (const char*)(wm);
        char* lb = (char*)&wtap[0][0][0][0];
        #pragma unroll
        for (int i = 0; i < 2; i++) {
            int off = i * 4096 + wid * 1024;
            __builtin_amdgcn_global_load_lds(
                (const __attribute__((address_space(1))) void*)(gb + off + lane * 16),
                (__attribute__((address_space(3))) void*)(lb + off), 16, 0, 0);
        }
    }
    __syncthreads();

    f32x16 acc;
    #pragma unroll
    for (int r = 0; r < 16; r++) acc[r] = 0.f;

    #pragma unroll
    for (int tap = 0; tap < 9; tap++) {
        int cur = tap & 1, nxt = cur ^ 1;
        if (tap < 8) {
            const char* gb = (const char*)(wm + (size_t)(tap + 1) * 4096);
            char* lb = (char*)&wtap[nxt][0][0][0];
            #pragma unroll
            for (int i = 0; i < 2; i++) {
                int off = i * 4096 + wid * 1024;
                __builtin_amdgcn_global_load_lds(
                    (const __attribute__((address_space(1))) void*)(gb + off + lane * 16),
                    (__attribute__((address_space(3))) void*)(lb + off), 16, 0, 0);
            }
        }
        int dy = tap / 3, dx = tap - 3 * (tap / 3);
        int xi = px + dx;
        int rowbyte = (dy * 66 + xi) * 128;
        int swz = (xi & 7) << 4;
        #pragma unroll
        for (int ks = 0; ks < 4; ks++) {
            int kg = ks * 2 + lhi;
            short8 a0 = *reinterpret_cast<const short8*>(&wtap[cur][kg][o0 + lrow][0]);
            short8 b0 = *reinterpret_cast<const short8*>(lds_h + rowbyte + ((kg * 16) ^ swz));
            acc = __builtin_amdgcn_mfma_f32_32x32x16_bf16(a0, b0, acc, 0, 0, 0);
        }
        if (tap < 8) asm volatile("s_waitcnt vmcnt(0)" ::: "memory");
        __builtin_amdgcn_s_barrier();
    }
    __syncthreads();

    if (MODE == 0) {
        #pragma unroll
        for (int q = 0; q < 4; q++) {
            int ob = o0 + q * 8 + 4 * lhi;
            #pragma unroll
            for (int h = 0; h < 2; h++) {
                float v0 = acc[q * 4 + h * 2] + bias[ob + h * 2];
                float v1 = acc[q * 4 + h * 2 + 1] + bias[ob + h * 2 + 1];
                if (RELU) { v0 = fmaxf(v0, 0.f); v1 = fmaxf(v1, 0.f); }
                u32 pk = (u32)f2bf(v0) | ((u32)f2bf(v1) << 16);
                int byte = px * 128 + (((ob + h * 2) * 2) ^ ((px & 7) << 4));
                *reinterpret_cast<u32*>(lds_h + byte) = pk;
            }
        }
        __syncthreads();
        #pragma unroll
        for (int i = 0; i < 2; i++) {
            int cid = i * 256 + t;
            int p = cid >> 3, g = cid & 7;
            short8 v = *reinterpret_cast<const short8*>(lds_h + p * 128 + ((g * 16) ^ ((p & 7) << 4)));
            *reinterpret_cast<short8*>(&outH[(size_t)(pix0 + p) * 64 + g * 8]) = v;
        }
    } else {
        float* ltf = (float*)lds_h;
        #pragma unroll
        for (int r = 0; r < 16; r++) {
            int o = o0 + (r & 3) + ((r >> 2) << 3) + (lhi << 2);
            if (o < 36) ltf[px * 40 + o] = acc[r] + bias[o];
        }
        __syncthreads();
        for (int i = t; i < 576; i += 256) {
            int p = i / 9, q = i - 9 * (i / 9);
            float4 v = *reinterpret_cast<const float4*>(&ltf[p * 40 + q * 4]);
            *reinterpret_cast<float4*>(&outF[(size_t)(pix0 + p) * 36 + q * 4]) = v;
        }
    }
}

// ---------------------------------------------------------------------------
// DCNv1 on h (bf16, 64->64) + fused mask head.
// 256 blocks x 512 thr; 128px x 64o; channel-major gather (p=t>>2, sub=t&3).
// XOR-swizzled dbuf stile + single barrier per tap, post-barrier prefetch.
// LDS: wtile dbuf 16KB + stile dbuf 32KB = 48KB (feat overlay fits).
// ---------------------------------------------------------------------------
__global__ __launch_bounds__(512) void dconv_small_mfma(
    const u16* __restrict__ h, const float* __restrict__ offs,
    const u16* __restrict__ wdc, const float* __restrict__ m_w,
    const float* __restrict__ m_b, float* __restrict__ maskb)
{
    __shared__ __attribute__((aligned(16))) char smem[49152];
    u16 (*wtile)[8][64][8]  = (u16 (*)[8][64][8])smem;            // [2][8][64][8]  16KB
    u16 (*stile)[8][128][8] = (u16 (*)[8][128][8])(smem + 16384); // [2][8][128][8] 32KB

    int t = threadIdx.x;
    int id = blockIdx.x;
    int blk = (id & 7) * 32 + (id >> 3);      // XCD swizzle
    int pix0 = blk * 128;
    int b = pix0 >> 12;
    int wid = t >> 6, lane = t & 63;
    int lrow = lane & 31, lhi = lane >> 5;
    int o0 = (wid & 1) << 5;
    int px0 = (wid >> 1) << 5;
    int gp = t >> 2, gsub = t & 3;            // pixel / 16-ch chunk

    {
        const char* gb = (const char*)wdc;
        char* lb = (char*)&wtile[0][0][0][0];
        __builtin_amdgcn_global_load_lds(
            (const __attribute__((address_space(1))) void*)(gb + wid * 1024 + lane * 16),
            (__attribute__((address_space(3))) void*)(lb + wid * 1024), 16, 0, 0);
    }

    f32x16 acc;
    #pragma unroll
    for (int r = 0; r < 16; r++) acc[r] = 0.f;

    int car[4]; float cwr[4];

    for (int tap = 0; tap < 9; ++tap) {
        int cur = tap & 1, nxt = cur ^ 1;
        // recompute corner table for (tap, gp) in registers
        {
            int pix = pix0 + gp; int pib = pix & 4095;
            int y = pib >> 6, x = pib & 63;
            float offy = offs[(size_t)pix * 36 + 18 + tap * 2];
            float offx = offs[(size_t)pix * 36 + 18 + tap * 2 + 1];
            float py = (float)(y - 1 + tap / 3) + offy;
            float pxf = (float)(x - 1 + (tap % 3)) + offx;
            float fy = floorf(py), fx = floorf(pxf);
            int y0 = (int)fy, x0 = (int)fx;
            float dyf = py - fy, dxf = pxf - fx;
            #pragma unroll
            for (int j = 0; j < 4; j++) {
                float wj = ((j >> 1) ? dyf : 1.f - dyf) * ((j & 1) ? dxf : 1.f - dxf);
                int yy = y0 + (j >> 1), xx = x0 + (j & 1);
                bool valid = (yy >= 0 && yy < 64 && xx >= 0 && xx < 64);
                int yc = min(max(yy, 0), 63), xc = min(max(xx, 0), 63);
                car[j] = (b * 4096 + yc * 64 + xc) << 6;
                cwr[j] = valid ? wj : 0.f;
            }
        }
        // gather 16 channels of pixel gp (channel-major: 4 lanes cover 128B)
        int c = gsub << 4;
        float va[16];
        #pragma unroll
        for (int e = 0; e < 16; e++) va[e] = 0.f;
        #pragma unroll
        for (int j = 0; j < 4; j++) {
            float w = cwr[j];
            const u16* p = h + car[j] + c;
            short8 r0 = *reinterpret_cast<const short8*>(p);
            short8 r1 = *reinterpret_cast<const short8*>(p + 8);
            #pragma unroll
            for (int e = 0; e < 8; e++) {
                va[e]     = fmaf(w, bf2f((u16)r0[e]), va[e]);
                va[8 + e] = fmaf(w, bf2f((u16)r1[e]), va[8 + e]);
            }
        }
        short8 s0, s1;
        #pragma unroll
        for (int e = 0; e < 8; e++) { s0[e] = (short)f2bf(va[e]); s1[e] = (short)f2bf(va[8 + e]); }
        int kg0 = gsub * 2, kg1 = gsub * 2 + 1;
        *reinterpret_cast<short8*>(&stile[cur][kg0][sswz(kg0, gp)][0]) = s0;
        *reinterpret_cast<short8*>(&stile[cur][kg1][sswz(kg1, gp)][0]) = s1;

        asm volatile("s_waitcnt vmcnt(0) lgkmcnt(0)" ::: "memory");
        __builtin_amdgcn_s_barrier();

        #pragma unroll
        for (int ks = 0; ks < 4; ks++) {
            int kg = ks * 2 + lhi;
            short8 a0 = *reinterpret_cast<const short8*>(&wtile[cur][kg][o0 + lrow][0]);
            short8 b0 = *reinterpret_cast<const short8*>(&stile[cur][kg][sswz(kg, px0 + lrow)][0]);
            acc = __builtin_amdgcn_mfma_f32_32x32x16_bf16(a0, b0, acc, 0, 0, 0);
        }
        // post-barrier prefetch of next tap's weights (safe: all reads of the
        // target buffer drained by every wave's pre-barrier lgkmcnt(0))
        if (tap < 8) {
            const char* gb = (const char*)(wdc + (size_t)(tap + 1) * 4096);
            char* lb = (char*)&wtile[nxt][0][0][0];
            __builtin_amdgcn_global_load_lds(
                (const __attribute__((address_space(1))) void*)(gb + wid * 1024 + lane * 16),
                (__attribute__((address_space(3))) void*)(lb + wid * 1024), 16, 0, 0);
        }
    }

    // epilogue: feat -> LDS [128][65] f32, then fused mask
    __syncthreads();
    float* featl = (float*)smem;
    int pxl = px0 + lrow;
    #pragma unroll
    for (int r = 0; r < 16; r++) {
        int o = o0 + (r & 3) + ((r >> 2) << 3) + (lhi << 2);
        featl[pxl * 65 + o] = acc[r];
    }
    __syncthreads();
    if (t < 256) {
        int p = t >> 1, hh = t & 1;
        int pix = pix0 + p;
        const float* fr = &featl[p * 65];
        int j0 = hh ? 4 : 0, j1 = hh ? 9 : 4;
        for (int j = j0; j < j1; j++) {
            float a = m_b[j];
            #pragma unroll 8
            for (int cc = 0; cc < 64; cc++) a = fmaf(fr[cc], m_w[j * 64 + cc], a);
            maskb[(size_t)pix * 9 + j] = 1.f / (1.f + expf(-a));
        }
    }
}

// ---------------------------------------------------------------------------
// Modulated DCNv2 (256->256), bf16 MFMA, pipelined.
// 512 blocks x 512 thr; block = 64 px x 256 o; 8 waves, each 32o x 64px.
// LDS = wtile dbuf 64KB + stile dbuf 16KB = 80KB -> 2 blocks/CU.
// Channel-major gather + XOR-swizzled stile (conflict-free write & read).
// Single barrier per K-step; weight prefetch issued post-barrier.
// ---------------------------------------------------------------------------
__global__ __launch_bounds__(512) void dconv_big_mfma(
    const u16* __restrict__ xT, const float* __restrict__ offs,
    const float* __restrict__ maskb, const u16* __restrict__ wKg,
    const float* __restrict__ bias, float* __restrict__ out)
{
    __shared__ __attribute__((aligned(16))) u16 wtile[2][8][256][8];  // 64 KB
    __shared__ __attribute__((aligned(16))) u16 stile[2][8][64][8];   // 16 KB

    int t = threadIdx.x;
    int id = blockIdx.x;                       // 512
    int blk = (id & 7) * 64 + (id >> 3);       // XCD swizzle: image b -> XCD b
    int pix0 = blk * 64;
    int b = pix0 >> 12, pib0 = pix0 & 4095;
    int wid = t >> 6, lane = t & 63;
    int lrow = lane & 31, lhi = lane >> 5;
    int o0 = wid << 5;                         // wave tile: 32 o x 64 px
    int gp = t >> 3, gsub = t & 7;             // gather pixel / 8-ch chunk

    {
        const char* gb = (const char*)wKg;
        char* lb = (char*)&wtile[0][0][0][0];
        #pragma unroll
        for (int i = 0; i < 4; i++) {
            int off = i * 8192 + wid * 1024;
            __builtin_amdgcn_global_load_lds(
                (const __attribute__((address_space(1))) void*)(gb + off + lane * 16),
                (__attribute__((address_space(3))) void*)(lb + off), 16, 0, 0);
        }
    }

    f32x16 acc[2];
    #pragma unroll
    for (int fp = 0; fp < 2; fp++)
        #pragma unroll
        for (int r = 0; r < 16; r++) acc[fp][r] = 0.f;

    int car[4]; float cwr[4];

    for (int kt = 0; kt < 36; ++kt) {
        int cur = kt & 1, nxt = cur ^ 1;
        int tap = kt >> 2, chunk = kt & 3;

        if (chunk == 0) {
            int pix = pix0 + gp; int pib = pix & 4095;
            int y = pib >> 6, x = pib & 63;
            float offy = offs[(size_t)pix * 36 + tap * 2];
            float offx = offs[(size_t)pix * 36 + tap * 2 + 1];
            float m = maskb[(size_t)pix * 9 + tap];
            float py = (float)(y - 1 + tap / 3) + offy;
            float pxf = (float)(x - 1 + (tap % 3)) + offx;
            float fy = floorf(py), fx = floorf(pxf);
            int y0 = (int)fy, x0 = (int)fx;
            float dyf = py - fy, dxf = pxf - fx;
            #pragma unroll
            for (int j = 0; j < 4; j++) {
                float wj = ((j >> 1) ? dyf : 1.f - dyf) * ((j & 1) ? dxf : 1.f - dxf);
                int yy = y0 + (j >> 1), xx = x0 + (j & 1);
                bool valid = (yy >= 0 && yy < 64 && xx >= 0 && xx < 64);
                int yc = min(max(yy, 0), 63), xc = min(max(xx, 0), 63);
                car[j] = (b * 4096 + yc * 64 + xc) << 8;
                cwr[j] = valid ? wj * m : 0.f;
            }
        }

        // gather 8 channels of pixel gp (channel-major coalescing)
        int c = (chunk << 6) + (gsub << 3);
        float va[8];
        #pragma unroll
        for (int e = 0; e < 8; e++) va[e] = 0.f;
        #pragma unroll
        for (int j = 0; j < 4; j++) {
            float w = cwr[j];
            short8 r0 = *reinterpret_cast<const short8*>(xT + car[j] + c);
            #pragma unroll
            for (int e = 0; e < 8; e++) va[e] = fmaf(w, bf2f((u16)r0[e]), va[e]);
        }
        short8 s0;
        #pragma unroll
        for (int e = 0; e < 8; e++) s0[e] = (short)f2bf(va[e]);
        *reinterpret_cast<short8*>(&stile[cur][gsub][sswz(gsub, gp)][0]) = s0;

        asm volatile("s_waitcnt vmcnt(0) lgkmcnt(0)" ::: "memory");
        __builtin_amdgcn_s_barrier();

        #pragma unroll
        for (int ks = 0; ks < 4; ks++) {
            int kg = ks * 2 + lhi;
            short8 a0 = *reinterpret_cast<const short8*>(&wtile[cur][kg][o0 + lrow][0]);
            short8 b0 = *reinterpret_cast<const short8*>(&stile[cur][kg][sswz(kg, lrow)][0]);
            short8 b1 = *reinterpret_cast<const short8*>(&stile[cur][kg][sswz(kg, 32 + lrow)][0]);
            acc[0] = __builtin_amdgcn_mfma_f32_32x32x16_bf16(a0, b0, acc[0], 0, 0, 0);
            acc[1] = __builtin_amdgcn_mfma_f32_32x32x16_bf16(a0, b1, acc[1], 0, 0, 0);
        }
        // post-barrier prefetch of next K-step weights (safe per barrier proof)
        if (kt < 35) {
            const char* gb = (const char*)(wKg + (size_t)(kt + 1) * 16384);
            char* lb = (char*)&wtile[nxt][0][0][0];
            #pragma unroll
            for (int i = 0; i < 4; i++) {
                int off = i * 8192 + wid * 1024;
                __builtin_amdgcn_global_load_lds(
                    (const __attribute__((address_space(1))) void*)(gb + off + lane * 16),
                    (__attribute__((address_space(3))) void*)(lb + off), 16, 0, 0);
            }
        }
    }

    // epilogue: bias + store NCHW f32
    #pragma unroll
    for (int fp = 0; fp < 2; fp++) {
        #pragma unroll
        for (int r = 0; r < 16; r++) {
            int o = o0 + (r & 3) + ((r >> 2) << 3) + (lhi << 2);
            size_t rowoff = ((size_t)(b * 256 + o) << 12) + pib0;
            out[rowoff + fp * 32 + lrow] = acc[fp][r] + bias[o];
        }
    }
}

extern "C" void kernel_launch(void* const* d_in, const int* in_sizes, int n_in,
                              void* d_out, int out_size, void* d_ws, size_t ws_size,
                              hipStream_t stream)
{
    const float* x        = (const float*)d_in[0];
    const float* S        = (const float*)d_in[1];
    const float* sp_w1    = (const float*)d_in[2];
    const float* sp_b1    = (const float*)d_in[3];
    const float* sp_s1    = (const float*)d_in[4];
    const float* sp_o1    = (const float*)d_in[5];
    const float* sp_w2    = (const float*)d_in[6];
    const float* sp_b2    = (const float*)d_in[7];
    const float* sp_s2    = (const float*)d_in[8];
    const float* sp_o2    = (const float*)d_in[9];
    const float* sp_w3    = (const float*)d_in[10];
    const float* sp_b3    = (const float*)d_in[11];
    const float* sp_s3    = (const float*)d_in[12];
    const float* sp_o3    = (const float*)d_in[13];
    const float* off_w    = (const float*)d_in[14];
    const float* off_b    = (const float*)d_in[15];
    const float* dc_off_w = (const float*)d_in[16];
    const float* dc_off_b = (const float*)d_in[17];
    const float* dc_w     = (const float*)d_in[18];
    const float* m_w      = (const float*)d_in[19];
    const float* m_b      = (const float*)d_in[20];
    const float* weight   = (const float*)d_in[21];
    const float* bias     = (const float*)d_in[22];
    float* out = (float*)d_out;
    float* ws  = (float*)d_ws;

    u16*   xTb   = (u16*)(ws + OXT);
    float* Si    = ws + OSI;
    u16*   h1    = (u16*)(ws + OA);
    u16*   h2    = (u16*)(ws + OB);
    u16*   h3    = (u16*)(ws + OC);
    float* offsb = ws + OOFFS;
    float* maskb = ws + OMSK;

    prep_k<<<2888, 256, 0, stream>>>(weight, sp_w1, sp_s1, sp_w2, sp_s2, sp_w3, sp_s3,
                                     off_w, dc_off_w, dc_w,
                                     sp_b1, sp_o1, sp_b2, sp_o2, sp_b3, sp_o3,
                                     off_b, dc_off_b, ws);
    transpose_x_k<<<2048, 256, 0, stream>>>(x, xTb);
    resize_k<<<384, 256, 0, stream>>>(S, Si);
    conv_in_k<<<512, 256, 0, stream>>>(Si, ws + OWSP1, ws + OBSP1, h1);
    conv_mfma_k<0, true><<<512, 256, 0, stream>>>(h1, (const u16*)(ws + OWSP2),
                                                  ws + OBSP2, h2, nullptr);
    conv_mfma_k<0, true><<<512, 256, 0, stream>>>(h2, (const u16*)(ws + OWSP3),
                                                  ws + OBSP3, h3, nullptr);
    conv_mfma_k<1, false><<<512, 256, 0, stream>>>(h3, (const u16*)(ws + OWOFF),
                                                   ws + OBOFF, nullptr, offsb);
    dconv_small_mfma<<<256, 512, 0, stream>>>(h3, offsb, (const u16*)(ws + OWDC),
                                              m_w, m_b, maskb);
    dconv_big_mfma<<<512, 512, 0, stream>>>(xTb, offsb, maskb,
                                            (const u16*)(ws + OWT), bias, out);
}